// Round 10
// baseline (1448.279 us; speedup 1.0000x reference)
//
#include <hip/hip_runtime.h>
#include <hip/hip_bf16.h>

typedef __attribute__((ext_vector_type(8)))  short short8v;
typedef __attribute__((ext_vector_type(16))) float f32x16;
typedef __attribute__((ext_vector_type(4)))  int   int4v;

// ===========================================================================
// enc_full: conv3x3(CIN->36) + BN + LIF + mean, ALL 36 co per thread.
// One thread = one pixel, acc[36] (VGPR-resident under the (256,4) pledge —
// mechanics validated R9: 36 accs -> VGPR 48, no spill). co loop INSIDE the
// ci loop: 9 ds_reads feed 324 FMAs, staged tile reused by all 36 outputs
// (no co-split -> FETCH/3 vs R8). Weight SGPR window = 12-co groups
// sequentially == R8's proven shape (108 dwords; 18-wide failed in R9).
// ===========================================================================
template<int CIN, int CICHUNK, int TXX, int TYY>
__global__ __launch_bounds__(TXX* TYY, 4) void enc_full(
    const float* __restrict__ feat,      // [16, CIN, H, W]
    const float* __restrict__ w,         // [36, CIN, 3, 3]
    const float* __restrict__ bn_s, const float* __restrict__ bn_b,
    const float* __restrict__ thr, const float* __restrict__ beta_raw,
    __hip_bfloat16* __restrict__ avg,    // [16][H][W][40]
    int H, int W, int tiles_x)
{
    const int TPB = TXX * TYY;
    const int HR  = TYY + 2, HC = TXX + 2;
    __shared__ float fs[CICHUNK][HR][HC];

    const int tid = threadIdx.x;
    const int b   = blockIdx.y;
    const int tx0 = (blockIdx.x % tiles_x) * TXX;
    const int ty0 = (blockIdx.x / tiles_x) * TYY;

    const int tx = tid % TXX;
    const int ty = tid / TXX;

    float acc[36];
    #pragma unroll
    for (int j = 0; j < 36; ++j) acc[j] = 0.f;

    const float* fb = feat + (long)b * CIN * H * W;

    for (int cc = 0; cc < CIN; cc += CICHUNK) {
        for (int i = tid; i < CICHUNK * HR * HC; i += TPB) {
            int ci = i / (HR * HC);
            int r  = i % (HR * HC);
            int hy = r / HC, hx = r % HC;
            int gy = ty0 + hy - 1, gx = tx0 + hx - 1;
            float v = 0.f;
            if (gy >= 0 && gy < H && gx >= 0 && gx < W)
                v = fb[((long)(cc + ci) * H + gy) * W + gx];
            fs[ci][hy][hx] = v;
        }
        __syncthreads();

        #pragma unroll 2
        for (int ci = 0; ci < CICHUNK; ++ci) {
            float f0 = fs[ci][ty    ][tx], f1 = fs[ci][ty    ][tx+1], f2 = fs[ci][ty    ][tx+2];
            float f3 = fs[ci][ty + 1][tx], f4 = fs[ci][ty + 1][tx+1], f5 = fs[ci][ty + 1][tx+2];
            float f6 = fs[ci][ty + 2][tx], f7 = fs[ci][ty + 2][tx+1], f8 = fs[ci][ty + 2][tx+2];
            const float* wq = w + (long)(cc + ci) * 9;
            #pragma unroll
            for (int j = 0; j < 36; ++j) {
                const float* ww = wq + (long)j * CIN * 9;  // uniform -> s_load
                acc[j] += f0 * ww[0] + f1 * ww[1] + f2 * ww[2]
                        + f3 * ww[3] + f4 * ww[4] + f5 * ww[5]
                        + f6 * ww[6] + f7 * ww[7] + f8 * ww[8];
            }
        }
        __syncthreads();
    }

    // Epilogue: per-channel scalars loaded inline (uniform), cnt reuses acc regs.
    const int oy = ty0 + ty, ox = tx0 + tx;
    if (oy < H && ox < W) {
        float cnt[36];
        #pragma unroll
        for (int j = 0; j < 36; ++j) {
            float h    = acc[j] * bn_s[j] + bn_b[j];
            float beta = 1.f / (1.f + expf(-beta_raw[j]));
            float t    = thr[j];
            float m = 0.f, c2 = 0.f;
            #pragma unroll
            for (int s = 0; s < 4; ++s) {
                m = beta * m + h;
                if (m > t) { c2 += 1.f; m -= t; }
            }
            cnt[j] = c2 * 0.25f;
        }
        unsigned* dp = (unsigned*)(avg + ((long)(b * H + oy) * W + ox) * 40);
        #pragma unroll
        for (int j2 = 0; j2 < 18; ++j2) {
            __hip_bfloat16 h0 = __float2bfloat16(cnt[2 * j2]);
            __hip_bfloat16 h1 = __float2bfloat16(cnt[2 * j2 + 1]);
            unsigned u0 = *(unsigned short*)&h0;
            unsigned u1 = *(unsigned short*)&h1;
            dp[j2] = u0 | (u1 << 16);
        }
    }
}

// ===========================================================================
// enc_px (R8-exact, no VGPR pledge): used for enc4.
// SHAPE RULES (R5-R8): TPB == 256 (4 waves), TXX pow2, acc <= 24.
// ===========================================================================
template<int CIN, int CICHUNK, int COCHUNK, int TXX, int TYY, int PX>
__global__ __launch_bounds__(TXX* TYY / PX) void enc_px(
    const float* __restrict__ feat,      // [16, CIN, H, W]
    const float* __restrict__ w,         // [36, CIN, 3, 3]
    const float* __restrict__ bn_s, const float* __restrict__ bn_b,
    const float* __restrict__ thr, const float* __restrict__ beta_raw,
    __hip_bfloat16* __restrict__ avg,    // [16][H][W][40]
    int H, int W, int tiles_x)
{
    const int TPB = TXX * TYY / PX;
    const int HR  = TYY + 2, HC = TXX + 2;
    __shared__ float fs[CICHUNK][HR][HC];

    const int tid = threadIdx.x;
    const int b   = blockIdx.y;
    const int co0 = blockIdx.z * COCHUNK;
    const int tx0 = (blockIdx.x % tiles_x) * TXX;
    const int ty0 = (blockIdx.x / tiles_x) * TYY;

    const int tx = tid % TXX;
    const int py = tid / TXX;           // owns rows py*PX..py*PX+PX-1

    float acc[COCHUNK][PX];
    #pragma unroll
    for (int j = 0; j < COCHUNK; ++j)
        #pragma unroll
        for (int p = 0; p < PX; ++p) acc[j][p] = 0.f;

    const float* fb = feat + (long)b * CIN * H * W;

    for (int cc = 0; cc < CIN; cc += CICHUNK) {
        for (int i = tid; i < CICHUNK * HR * HC; i += TPB) {
            int ci = i / (HR * HC);
            int r  = i % (HR * HC);
            int hy = r / HC, hx = r % HC;
            int gy = ty0 + hy - 1, gx = tx0 + hx - 1;
            float v = 0.f;
            if (gy >= 0 && gy < H && gx >= 0 && gx < W)
                v = fb[((long)(cc + ci) * H + gy) * W + gx];
            fs[ci][hy][hx] = v;
        }
        __syncthreads();

        for (int ci = 0; ci < CICHUNK; ++ci) {
            float f[PX + 2][3];
            #pragma unroll
            for (int r = 0; r < PX + 2; ++r) {
                f[r][0] = fs[ci][py * PX + r][tx];
                f[r][1] = fs[ci][py * PX + r][tx + 1];
                f[r][2] = fs[ci][py * PX + r][tx + 2];
            }
            const float* wq = w + (long)(cc + ci) * 9;
            #pragma unroll
            for (int j = 0; j < COCHUNK; ++j) {
                const float* ww = wq + (long)(co0 + j) * CIN * 9;  // uniform -> s_load
                #pragma unroll
                for (int p = 0; p < PX; ++p) {
                    acc[j][p] += f[p    ][0] * ww[0] + f[p    ][1] * ww[1] + f[p    ][2] * ww[2]
                               + f[p + 1][0] * ww[3] + f[p + 1][1] * ww[4] + f[p + 1][2] * ww[5]
                               + f[p + 2][0] * ww[6] + f[p + 2][1] * ww[7] + f[p + 2][2] * ww[8];
                }
            }
        }
        __syncthreads();
    }

    float sc[COCHUNK], sb[COCHUNK], bt[COCHUNK], th[COCHUNK];
    #pragma unroll
    for (int j = 0; j < COCHUNK; ++j) {
        int co = co0 + j;
        sc[j] = bn_s[co]; sb[j] = bn_b[co];
        bt[j] = 1.f / (1.f + expf(-beta_raw[co]));
        th[j] = thr[co];
    }

    #pragma unroll
    for (int p = 0; p < PX; ++p) {
        const int oy = ty0 + py * PX + p, ox = tx0 + tx;
        if (oy < H && ox < W) {
            float cnt[COCHUNK];
            #pragma unroll
            for (int j = 0; j < COCHUNK; ++j) {
                float h = acc[j][p] * sc[j] + sb[j];
                float m = 0.f, c2 = 0.f;
                #pragma unroll
                for (int s = 0; s < 4; ++s) {
                    m = bt[j] * m + h;
                    if (m > th[j]) { c2 += 1.f; m -= th[j]; }
                }
                cnt[j] = c2 * 0.25f;
            }
            unsigned* dp = (unsigned*)(avg + ((long)(b * H + oy) * W + ox) * 40 + co0);
            #pragma unroll
            for (int j2 = 0; j2 < COCHUNK / 2; ++j2) {
                __hip_bfloat16 h0 = __float2bfloat16(cnt[2 * j2]);
                __hip_bfloat16 h1 = __float2bfloat16(cnt[2 * j2 + 1]);
                unsigned u0 = *(unsigned short*)&h0;
                unsigned u1 = *(unsigned short*)&h1;
                dp[j2] = u0 | (u1 << 16);
            }
        }
    }
}

// ===========================================================================
// Original encoder (enc5 ci-split + fallback path).
// ===========================================================================
template<int CIN, int CIPER, int CICHUNK, int COCHUNK, int TDIM, bool PARTIAL, bool CL>
__global__ __launch_bounds__(TDIM* TDIM) void enc_tiled(
    const float* __restrict__ feat,
    const float* __restrict__ w,
    const float* __restrict__ bn_s, const float* __restrict__ bn_b,
    const float* __restrict__ thr, const float* __restrict__ beta_raw,
    __hip_bfloat16* __restrict__ avg,
    float* __restrict__ partial,
    int H, int W, int tiles_x)
{
    const int TPB  = TDIM * TDIM;
    const int HALOD = TDIM + 2;
    const int NCO  = 36 / COCHUNK;
    __shared__ float fs[CICHUNK][HALOD][HALOD];

    const int tile = blockIdx.x;
    const int b    = blockIdx.y;
    const int coc  = blockIdx.z % NCO;
    const int cis  = blockIdx.z / NCO;
    const int co0  = coc * COCHUNK;
    const int tx0  = (tile % tiles_x) * TDIM;
    const int ty0  = (tile / tiles_x) * TDIM;

    const int tx = threadIdx.x % TDIM;
    const int ty = threadIdx.x / TDIM;
    const int ox = tx0 + tx, oy = ty0 + ty;

    float acc[COCHUNK];
    #pragma unroll
    for (int c = 0; c < COCHUNK; ++c) acc[c] = 0.f;

    const float* fb = feat + (long)b * CIN * H * W;
    const int ci_base = cis * CIPER;

    for (int cc = ci_base; cc < ci_base + CIPER; cc += CICHUNK) {
        for (int i = threadIdx.x; i < CICHUNK * HALOD * HALOD; i += TPB) {
            int ci = i / (HALOD * HALOD);
            int r  = i % (HALOD * HALOD);
            int hy = r / HALOD, hx = r % HALOD;
            int gy = ty0 + hy - 1, gx = tx0 + hx - 1;
            float v = 0.f;
            if (gy >= 0 && gy < H && gx >= 0 && gx < W)
                v = fb[((long)(cc + ci) * H + gy) * W + gx];
            fs[ci][hy][hx] = v;
        }
        __syncthreads();

        for (int ci = 0; ci < CICHUNK; ++ci) {
            float f0 = fs[ci][ty    ][tx], f1 = fs[ci][ty    ][tx+1], f2 = fs[ci][ty    ][tx+2];
            float f3 = fs[ci][ty + 1][tx], f4 = fs[ci][ty + 1][tx+1], f5 = fs[ci][ty + 1][tx+2];
            float f6 = fs[ci][ty + 2][tx], f7 = fs[ci][ty + 2][tx+1], f8 = fs[ci][ty + 2][tx+2];
            const float* wq = w + (long)(cc + ci) * 9;
            #pragma unroll
            for (int j = 0; j < COCHUNK; ++j) {
                const float* ww = wq + (long)(co0 + j) * CIN * 9;  // uniform -> s_load
                acc[j] += f0 * ww[0] + f1 * ww[1] + f2 * ww[2]
                        + f3 * ww[3] + f4 * ww[4] + f5 * ww[5]
                        + f6 * ww[6] + f7 * ww[7] + f8 * ww[8];
            }
        }
        __syncthreads();
    }

    if (ox < W && oy < H) {
        if (PARTIAL) {
            #pragma unroll
            for (int j = 0; j < COCHUNK; ++j)
                partial[((((long)cis * 16 + b) * 36 + (co0 + j)) * H + oy) * W + ox] = acc[j];
        } else {
            float cnt[COCHUNK];
            #pragma unroll
            for (int j = 0; j < COCHUNK; ++j) {
                int co = co0 + j;
                float h    = acc[j] * bn_s[co] + bn_b[co];
                float beta = 1.f / (1.f + expf(-beta_raw[co]));
                float t    = thr[co];
                float m = 0.f, c2 = 0.f;
                #pragma unroll
                for (int s = 0; s < 4; ++s) {
                    m = beta * m + h;
                    if (m > t) { c2 += 1.f; m -= t; }
                }
                cnt[j] = c2 * 0.25f;
            }
            if (CL) {
                unsigned* dp = (unsigned*)(avg + ((long)(b * H + oy) * W + ox) * 40 + co0);
                #pragma unroll
                for (int j2 = 0; j2 < COCHUNK / 2; ++j2) {
                    __hip_bfloat16 h0 = __float2bfloat16(cnt[2 * j2]);
                    __hip_bfloat16 h1 = __float2bfloat16(cnt[2 * j2 + 1]);
                    unsigned u0 = *(unsigned short*)&h0;
                    unsigned u1 = *(unsigned short*)&h1;
                    dp[j2] = u0 | (u1 << 16);
                }
            } else {
                #pragma unroll
                for (int j = 0; j < COCHUNK; ++j)
                    avg[(((long)b * 36 + (co0 + j)) * H + oy) * W + ox] = __float2bfloat16(cnt[j]);
            }
        }
    }
}

// ===========================================================================
// Combine ci-split partials + BN + LIF + mean -> bf16 avg (CL or NCHW).
// ===========================================================================
template<int SPLITS, bool CL>
__global__ __launch_bounds__(256) void combine_lif(
    const float* __restrict__ partial,
    const float* __restrict__ bn_s, const float* __restrict__ bn_b,
    const float* __restrict__ thr, const float* __restrict__ beta_raw,
    __hip_bfloat16* __restrict__ avg, int H, int W, int total)
{
    int idx = blockIdx.x * 256 + threadIdx.x;
    if (idx >= total) return;
    int HW = H * W;
    int co = (idx / HW) % 36;
    float h = 0.f;
    #pragma unroll
    for (int s = 0; s < SPLITS; ++s) h += partial[(long)s * total + idx];
    h = h * bn_s[co] + bn_b[co];
    float beta = 1.f / (1.f + expf(-beta_raw[co]));
    float t    = thr[co];
    float m = 0.f, cnt = 0.f;
    #pragma unroll
    for (int s = 0; s < 4; ++s) {
        m = beta * m + h;
        if (m > t) { cnt += 1.f; m -= t; }
    }
    if (CL) {
        int b = idx / (36 * HW);
        int rem = idx % HW;
        int y = rem / W, x = rem % W;
        avg[((long)(b * H + y) * W + x) * 40 + co] = __float2bfloat16(cnt * 0.25f);
    } else {
        avg[idx] = __float2bfloat16(cnt * 0.25f);
    }
}

// ===========================================================================
// Weight prepack for MFMA decoder.
// ===========================================================================
__global__ __launch_bounds__(256) void pack_w(
    const float* __restrict__ w, __hip_bfloat16* __restrict__ ap, int total)
{
    int idx = blockIdx.x * 256 + threadIdx.x;   // one per (cg,s,h,m)
    if (idx >= total) return;
    int m  = idx & 31;
    int h  = (idx >> 5) & 1;
    int s  = (idx >> 6) % 23;
    int cg = idx / (23 * 64);
    int o  = 2 * s + h;
    int co = cg * 32 + m;
    unsigned short v[8];
    #pragma unroll
    for (int j = 0; j < 8; ++j) {
        float x = 0.f;
        if (o < 45) {
            int tap = o / 5, oct = o % 5, ci = oct * 8 + j;
            if (ci < 36) x = w[(long)co * 324 + ci * 9 + tap];
        }
        __hip_bfloat16 hv = __float2bfloat16(x);
        v[j] = *(unsigned short*)&hv;
    }
    *(int4v*)(ap + (long)idx * 8) = *(int4v*)v;
}

// ===========================================================================
// MFMA decoder: conv3x3(36->Cout) + BN + SiLU.
// ===========================================================================
template<int COG>
__global__ __launch_bounds__(256) void dec_mfma(
    const __hip_bfloat16* __restrict__ avg_cl,   // [B][H][W][40]
    const __hip_bfloat16* __restrict__ apack,
    const float* __restrict__ bn_s, const float* __restrict__ bn_b,
    float* __restrict__ out, int Cout, int H, int W, int tiles_x)
{
    __shared__ __hip_bfloat16 tile[12960];       // [18][18][40] = 25920 B

    const int tid    = threadIdx.x;
    const int b      = blockIdx.y;
    const int cgbase = blockIdx.z * COG;
    const int tx0 = (blockIdx.x % tiles_x) * 16;
    const int ty0 = (blockIdx.x / tiles_x) * 16;

    {   // stage halo tile (channel-last), zero-padded, b128 both sides
        const __hip_bfloat16* ab = avg_cl + (long)b * H * W * 40;
        for (int i = tid; i < 1620; i += 256) {
            int row = i / 90, u = i - row * 90;
            int px = u / 5, un = u - px * 5;
            int gy = ty0 + row - 1, gx = tx0 + px - 1;
            int4v v = {0, 0, 0, 0};
            if (gy >= 0 && gy < H && gx >= 0 && gx < W)
                v = *(const int4v*)(ab + ((long)gy * W + gx) * 40 + un * 8);
            *(int4v*)(tile + (row * 18 + px) * 40 + un * 8) = v;
        }
    }
    __syncthreads();

    const int lane = tid & 63;
    const int wv   = tid >> 6;
    const int h    = lane >> 5;
    const int n    = lane & 31;
    const int lx   = n & 15;
    const int ly0  = wv * 4 + (n >> 4);

    const char* tb  = (const char*)tile;
    const int   bb0 = ((ly0 + 1) * 18 + (lx + 1)) * 80;
    const int   bb1 = bb0 + 2 * 18 * 80;

    const char* ap = (const char*)apack + (long)cgbase * 23552 + h * 512 + n * 16;

    f32x16 acc[COG][2];
    #pragma unroll
    for (int cg = 0; cg < COG; ++cg)
        #pragma unroll
        for (int pf = 0; pf < 2; ++pf)
            #pragma unroll
            for (int k = 0; k < 16; ++k) acc[cg][pf][k] = 0.f;

    #pragma unroll
    for (int s = 0; s < 23; ++s) {
        int o0 = 2 * s;     if (o0 > 44) o0 = 44;
        int o1 = 2 * s + 1; if (o1 > 44) o1 = 44;
        const int C0 = ((o0 / 5) / 3 - 1) * 1440 + ((o0 / 5) % 3 - 1) * 80 + (o0 % 5) * 16;
        const int C1 = ((o1 / 5) / 3 - 1) * 1440 + ((o1 / 5) % 3 - 1) * 80 + (o1 % 5) * 16;
        const int offc = h ? C1 : C0;
        short8v bf0 = *(const short8v*)(tb + (bb0 + offc));
        short8v bf1 = *(const short8v*)(tb + (bb1 + offc));
        #pragma unroll
        for (int cg = 0; cg < COG; ++cg) {
            short8v af = *(const short8v*)(ap + cg * 23552 + s * 1024);
            acc[cg][0] = __builtin_amdgcn_mfma_f32_32x32x16_bf16(af, bf0, acc[cg][0], 0, 0, 0);
            acc[cg][1] = __builtin_amdgcn_mfma_f32_32x32x16_bf16(af, bf1, acc[cg][1], 0, 0, 0);
        }
    }

    #pragma unroll
    for (int cg = 0; cg < COG; ++cg) {
        #pragma unroll
        for (int r = 0; r < 16; ++r) {
            const int co = ((cgbase + cg) << 5) + (r & 3) + ((r >> 2) << 3) + (h << 2);
            const float sc = bn_s[co], bc = bn_b[co];
            #pragma unroll
            for (int pf = 0; pf < 2; ++pf) {
                const int ly = ly0 + pf * 2;
                const int gy = ty0 + ly, gx = tx0 + lx;
                float v = acc[cg][pf][r] * sc + bc;
                v = v / (1.f + __expf(-v));
                if (gy < H && gx < W)
                    out[(((long)b * Cout + co) * H + gy) * W + gx] = v;
            }
        }
    }
}

// ===========================================================================
// Fallback decoder (VALU, NCHW avg).
// ===========================================================================
template<int COCHUNK, int TDIM>
__global__ __launch_bounds__(TDIM* TDIM) void dec_tiled(
    const __hip_bfloat16* __restrict__ avg,
    const float* __restrict__ w,
    const float* __restrict__ bn_s, const float* __restrict__ bn_b,
    float* __restrict__ out,
    int Cout, int H, int W, int tiles_x)
{
    const int CIN = 36;
    const int TPB = TDIM * TDIM;
    const int HALOD = TDIM + 2;
    __shared__ float fs[CIN][HALOD][HALOD];

    const int tile = blockIdx.x;
    const int b    = blockIdx.y;
    const int co0  = blockIdx.z * COCHUNK;
    const int tx0  = (tile % tiles_x) * TDIM;
    const int ty0  = (tile / tiles_x) * TDIM;

    const int tx = threadIdx.x % TDIM;
    const int ty = threadIdx.x / TDIM;
    const int ox = tx0 + tx, oy = ty0 + ty;

    const __hip_bfloat16* ab = avg + (long)b * CIN * H * W;

    for (int i = threadIdx.x; i < CIN * HALOD * HALOD; i += TPB) {
        int ci = i / (HALOD * HALOD);
        int r  = i % (HALOD * HALOD);
        int hy = r / HALOD, hx = r % HALOD;
        int gy = ty0 + hy - 1, gx = tx0 + hx - 1;
        float v = 0.f;
        if (gy >= 0 && gy < H && gx >= 0 && gx < W)
            v = __bfloat162float(ab[((long)ci * H + gy) * W + gx]);
        fs[ci][hy][hx] = v;
    }
    __syncthreads();

    float acc[COCHUNK];
    #pragma unroll
    for (int j = 0; j < COCHUNK; ++j) acc[j] = 0.f;

    for (int ci = 0; ci < CIN; ++ci) {
        float f0 = fs[ci][ty    ][tx], f1 = fs[ci][ty    ][tx+1], f2 = fs[ci][ty    ][tx+2];
        float f3 = fs[ci][ty + 1][tx], f4 = fs[ci][ty + 1][tx+1], f5 = fs[ci][ty + 1][tx+2];
        float f6 = fs[ci][ty + 2][tx], f7 = fs[ci][ty + 2][tx+1], f8 = fs[ci][ty + 2][tx+2];
        #pragma unroll
        for (int j = 0; j < COCHUNK; ++j) {
            const float* ww = w + ((long)(co0 + j) * CIN + ci) * 9;
            acc[j] += f0 * ww[0] + f1 * ww[1] + f2 * ww[2]
                    + f3 * ww[3] + f4 * ww[4] + f5 * ww[5]
                    + f6 * ww[6] + f7 * ww[7] + f8 * ww[8];
        }
    }

    if (ox < W && oy < H) {
        #pragma unroll
        for (int j = 0; j < COCHUNK; ++j) {
            int co = co0 + j;
            float v = acc[j] * bn_s[co] + bn_b[co];
            out[(((long)b * Cout + co) * H + oy) * W + ox] = v / (1.f + expf(-v));
        }
    }
}

// ===========================================================================
extern "C" void kernel_launch(void* const* d_in, const int* in_sizes, int n_in,
                              void* d_out, int out_size, void* d_ws, size_t ws_size,
                              hipStream_t stream)
{
    const int B = 16;
    const int C[3] = {64, 128, 256};
    const int S[3] = {160, 80, 40};

    float* out = (float*)d_out;
    long out_off[3]; long off = 0;
    for (int l = 0; l < 3; ++l) { out_off[l] = off; off += (long)B * C[l] * S[l] * S[l]; }

    // ---- new-path workspace layout (bytes) ----
    const long avgcl_bytes[3] = {32768000L, 8192000L, 2048000L};   // B*H*W*40*2
    long avgcl_off[3]; long boff = 0;
    for (int l = 0; l < 3; ++l) { avgcl_off[l] = boff; boff += avgcl_bytes[l]; }
    const long avgcl_total = boff;
    const long ap_bytes[3] = {47104L, 94208L, 188416L};             // (C/32)*23552
    long ap_off[3];
    for (int l = 0; l < 3; ++l) { ap_off[l] = boff; boff += ap_bytes[l]; }
    const long part5_off = boff;
    const long part5_bytes = 4L * B * 36 * 1600 * 4;
    const size_t need_full = (size_t)(part5_off + part5_bytes);
    const size_t need_min  = (size_t)part5_off;

    char* wsb = (char*)d_ws;

    if (ws_size >= need_min) {
        // ================= NEW PATH =================
        const bool split5 = ws_size >= need_full;
        hipMemsetAsync(wsb, 0, avgcl_total, stream);   // zero avg_cl incl. ci-pad

        for (int l = 0; l < 3; ++l) {
            const float* dec_w = (const float*)d_in[9 * l + 6];
            int total = (C[l] / 32) * 23 * 2 * 32;
            pack_w<<<(total + 255) / 256, 256, 0, stream>>>(
                dec_w, (__hip_bfloat16*)(wsb + ap_off[l]), total);
        }

        for (int l = 0; l < 3; ++l) {
            const int base = 9 * l;
            const float* feat     = (const float*)d_in[base + 0];
            const float* enc_w    = (const float*)d_in[base + 1];
            const float* enc_bn_s = (const float*)d_in[base + 2];
            const float* enc_bn_b = (const float*)d_in[base + 3];
            const float* enc_thr  = (const float*)d_in[base + 4];
            const float* enc_beta = (const float*)d_in[base + 5];
            const float* dec_bn_s = (const float*)d_in[base + 7];
            const float* dec_bn_b = (const float*)d_in[base + 8];

            const int Hs = S[l], Wsz = S[l];
            __hip_bfloat16* avg_cl = (__hip_bfloat16*)(wsb + avgcl_off[l]);
            const __hip_bfloat16* ap = (const __hip_bfloat16*)(wsb + ap_off[l]);
            float* r = out + out_off[l];

            if (l == 0) {
                // 160x160: 5x20 tiles of 32x8, 256 thr, 1 px/thread, ALL 36 co
                dim3 eg(100, B);
                enc_full<64, 8, 32, 8><<<eg, 256, 0, stream>>>(
                    feat, enc_w, enc_bn_s, enc_bn_b, enc_thr, enc_beta, avg_cl, Hs, Wsz, 5);
                dim3 dg(100, B, 1);
                dec_mfma<2><<<dg, 256, 0, stream>>>(avg_cl, ap, dec_bn_s, dec_bn_b, r, 64, Hs, Wsz, 10);
            } else if (l == 1) {
                // 80x80: 5x3 tiles of 16x32 (last row masked), 256 thr, 2 px/thread,
                // co-split x3 (proven R8 config).
                dim3 eg(15, B, 3);
                enc_px<128, 8, 12, 16, 32, 2><<<eg, 256, 0, stream>>>(
                    feat, enc_w, enc_bn_s, enc_bn_b, enc_thr, enc_beta, avg_cl, Hs, Wsz, 5);
                dim3 dg(25, B, 1);
                dec_mfma<4><<<dg, 256, 0, stream>>>(avg_cl, ap, dec_bn_s, dec_bn_b, r, 128, Hs, Wsz, 5);
            } else {
                if (split5) {
                    float* partial5 = (float*)(wsb + part5_off);
                    dim3 eg(25, B, 12);   // 4 ci-splits x 3 co-chunks
                    enc_tiled<256, 64, 16, 12, 8, true, true><<<eg, 64, 0, stream>>>(
                        feat, enc_w, enc_bn_s, enc_bn_b, enc_thr, enc_beta, nullptr, partial5, Hs, Wsz, 5);
                    int total = B * 36 * Hs * Wsz;
                    combine_lif<4, true><<<(total + 255) / 256, 256, 0, stream>>>(
                        partial5, enc_bn_s, enc_bn_b, enc_thr, enc_beta, avg_cl, Hs, Wsz, total);
                } else {
                    dim3 eg(25, B, 3);
                    enc_tiled<256, 256, 16, 12, 8, false, true><<<eg, 64, 0, stream>>>(
                        feat, enc_w, enc_bn_s, enc_bn_b, enc_thr, enc_beta, avg_cl, nullptr, Hs, Wsz, 5);
                }
                dim3 dg(9, B, 2);
                dec_mfma<4><<<dg, 256, 0, stream>>>(avg_cl, ap, dec_bn_s, dec_bn_b, r, 256, Hs, Wsz, 3);
            }
        }
    } else {
        // ================= FALLBACK (NCHW, VALU decoder) =================
        __hip_bfloat16* ws = (__hip_bfloat16*)d_ws;
        long avg_off2[3]; long eoff = 0;
        for (int l = 0; l < 3; ++l) { avg_off2[l] = eoff; eoff += (long)B * 36 * S[l] * S[l]; }
        float* partial5 = (float*)(ws + ((eoff + 7) & ~7L));
        const long part5f = 4L * B * 36 * 40 * 40;
        const size_t old_need = (size_t)((eoff + 7) & ~7L) * 2 + part5f * 4;
        const bool split5 = ws_size >= old_need;

        for (int l = 0; l < 3; ++l) {
            const int base = 9 * l;
            const float* feat     = (const float*)d_in[base + 0];
            const float* enc_w    = (const float*)d_in[base + 1];
            const float* enc_bn_s = (const float*)d_in[base + 2];
            const float* enc_bn_b = (const float*)d_in[base + 3];
            const float* enc_thr  = (const float*)d_in[base + 4];
            const float* enc_beta = (const float*)d_in[base + 5];
            const float* dec_w    = (const float*)d_in[base + 6];
            const float* dec_bn_s = (const float*)d_in[base + 7];
            const float* dec_bn_b = (const float*)d_in[base + 8];

            const int Hs = S[l], Wsz = S[l], Cl = C[l];
            __hip_bfloat16* avg = ws + avg_off2[l];
            float* r = out + out_off[l];

            if (l == 0) {
                dim3 eg(100, B, 3);
                enc_tiled<64, 64, 16, 12, 16, false, false><<<eg, 256, 0, stream>>>(
                    feat, enc_w, enc_bn_s, enc_bn_b, enc_thr, enc_beta, avg, nullptr, Hs, Wsz, 10);
                dim3 dg(100, B, 2);
                dec_tiled<32, 16><<<dg, 256, 0, stream>>>(avg, dec_w, dec_bn_s, dec_bn_b, r, Cl, Hs, Wsz, 10);
            } else if (l == 1) {
                dim3 eg(25, B, 3);
                enc_tiled<128, 128, 16, 12, 16, false, false><<<eg, 256, 0, stream>>>(
                    feat, enc_w, enc_bn_s, enc_bn_b, enc_thr, enc_beta, avg, nullptr, Hs, Wsz, 5);
                dim3 dg(25, B, 4);
                dec_tiled<32, 16><<<dg, 256, 0, stream>>>(avg, dec_w, dec_bn_s, dec_bn_b, r, Cl, Hs, Wsz, 5);
            } else {
                if (split5) {
                    dim3 eg(25, B, 12);
                    enc_tiled<256, 64, 16, 12, 8, true, false><<<eg, 64, 0, stream>>>(
                        feat, enc_w, enc_bn_s, enc_bn_b, enc_thr, enc_beta, nullptr, partial5, Hs, Wsz, 5);
                    int total = B * 36 * Hs * Wsz;
                    combine_lif<4, false><<<(total + 255) / 256, 256, 0, stream>>>(
                        partial5, enc_bn_s, enc_bn_b, enc_thr, enc_beta, avg, Hs, Wsz, total);
                } else {
                    dim3 eg(25, B, 3);
                    enc_tiled<256, 256, 16, 12, 8, false, false><<<eg, 64, 0, stream>>>(
                        feat, enc_w, enc_bn_s, enc_bn_b, enc_thr, enc_beta, avg, nullptr, Hs, Wsz, 5);
                }
                dim3 dg(25, B, 16);
                dec_tiled<16, 8><<<dg, 64, 0, stream>>>(avg, dec_w, dec_bn_s, dec_bn_b, r, Cl, Hs, Wsz, 5);
            }
        }
    }
}

// Round 11
// 986.126 us; speedup vs baseline: 1.4687x; 1.4687x over previous
//
#include <hip/hip_runtime.h>
#include <hip/hip_bf16.h>

typedef __attribute__((ext_vector_type(8)))  short short8v;
typedef __attribute__((ext_vector_type(16))) float f32x16;
typedef __attribute__((ext_vector_type(4)))  int   int4v;

// ===========================================================================
// Encoder model (R5-R10 distilled): time ~ FMA_cycles * (1 + k/PX).
//  - FMA : s_load-dword ratio == PX  (weight reuse across a thread's pixels)
//  - s_load window per ci must stay <= 108 dwords (12 co; 18 failed in R9)
//  - acc[COCHUNK][PX] <= 36 requires the __launch_bounds__(256,4) pledge
//    (R9-validated: 36 accs -> VGPR 48, no spill); without pledge limit is 24.
//  - TPB == 256, TXX pow2 (R7: 320-thr/80-wide collapsed VGPR/occupancy).
// enc_px_p: pledged variant (PX=3) for enc3.
// ===========================================================================
template<int CIN, int CICHUNK, int COCHUNK, int TXX, int TYY, int PX>
__global__ __launch_bounds__(TXX* TYY / PX, 4) void enc_px_p(
    const float* __restrict__ feat,      // [16, CIN, H, W]
    const float* __restrict__ w,         // [36, CIN, 3, 3]
    const float* __restrict__ bn_s, const float* __restrict__ bn_b,
    const float* __restrict__ thr, const float* __restrict__ beta_raw,
    __hip_bfloat16* __restrict__ avg,    // [16][H][W][40]
    int H, int W, int tiles_x)
{
    const int TPB = TXX * TYY / PX;
    const int HR  = TYY + 2, HC = TXX + 2;
    __shared__ float fs[CICHUNK][HR][HC];

    const int tid = threadIdx.x;
    const int b   = blockIdx.y;
    const int co0 = blockIdx.z * COCHUNK;
    const int tx0 = (blockIdx.x % tiles_x) * TXX;
    const int ty0 = (blockIdx.x / tiles_x) * TYY;

    const int tx = tid % TXX;
    const int py = tid / TXX;           // owns rows py*PX..py*PX+PX-1

    float acc[COCHUNK][PX];
    #pragma unroll
    for (int j = 0; j < COCHUNK; ++j)
        #pragma unroll
        for (int p = 0; p < PX; ++p) acc[j][p] = 0.f;

    const float* fb = feat + (long)b * CIN * H * W;

    for (int cc = 0; cc < CIN; cc += CICHUNK) {
        for (int i = tid; i < CICHUNK * HR * HC; i += TPB) {
            int ci = i / (HR * HC);
            int r  = i % (HR * HC);
            int hy = r / HC, hx = r % HC;
            int gy = ty0 + hy - 1, gx = tx0 + hx - 1;
            float v = 0.f;
            if (gy >= 0 && gy < H && gx >= 0 && gx < W)
                v = fb[((long)(cc + ci) * H + gy) * W + gx];
            fs[ci][hy][hx] = v;
        }
        __syncthreads();

        for (int ci = 0; ci < CICHUNK; ++ci) {
            float f[PX + 2][3];
            #pragma unroll
            for (int r = 0; r < PX + 2; ++r) {
                f[r][0] = fs[ci][py * PX + r][tx];
                f[r][1] = fs[ci][py * PX + r][tx + 1];
                f[r][2] = fs[ci][py * PX + r][tx + 2];
            }
            const float* wq = w + (long)(cc + ci) * 9;
            #pragma unroll
            for (int j = 0; j < COCHUNK; ++j) {
                const float* ww = wq + (long)(co0 + j) * CIN * 9;  // uniform -> s_load
                #pragma unroll
                for (int p = 0; p < PX; ++p) {
                    acc[j][p] += f[p    ][0] * ww[0] + f[p    ][1] * ww[1] + f[p    ][2] * ww[2]
                               + f[p + 1][0] * ww[3] + f[p + 1][1] * ww[4] + f[p + 1][2] * ww[5]
                               + f[p + 2][0] * ww[6] + f[p + 2][1] * ww[7] + f[p + 2][2] * ww[8];
                }
            }
        }
        __syncthreads();
    }

    float sc[COCHUNK], sb[COCHUNK], bt[COCHUNK], th[COCHUNK];
    #pragma unroll
    for (int j = 0; j < COCHUNK; ++j) {
        int co = co0 + j;
        sc[j] = bn_s[co]; sb[j] = bn_b[co];
        bt[j] = 1.f / (1.f + expf(-beta_raw[co]));
        th[j] = thr[co];
    }

    #pragma unroll
    for (int p = 0; p < PX; ++p) {
        const int oy = ty0 + py * PX + p, ox = tx0 + tx;
        if (oy < H && ox < W) {
            float cnt[COCHUNK];
            #pragma unroll
            for (int j = 0; j < COCHUNK; ++j) {
                float h = acc[j][p] * sc[j] + sb[j];
                float m = 0.f, c2 = 0.f;
                #pragma unroll
                for (int s = 0; s < 4; ++s) {
                    m = bt[j] * m + h;
                    if (m > th[j]) { c2 += 1.f; m -= th[j]; }
                }
                cnt[j] = c2 * 0.25f;
            }
            unsigned* dp = (unsigned*)(avg + ((long)(b * H + oy) * W + ox) * 40 + co0);
            #pragma unroll
            for (int j2 = 0; j2 < COCHUNK / 2; ++j2) {
                __hip_bfloat16 h0 = __float2bfloat16(cnt[2 * j2]);
                __hip_bfloat16 h1 = __float2bfloat16(cnt[2 * j2 + 1]);
                unsigned u0 = *(unsigned short*)&h0;
                unsigned u1 = *(unsigned short*)&h1;
                dp[j2] = u0 | (u1 << 16);
            }
        }
    }
}

// ===========================================================================
// enc_px (R8-exact, no pledge): used for enc4. acc <= 24.
// ===========================================================================
template<int CIN, int CICHUNK, int COCHUNK, int TXX, int TYY, int PX>
__global__ __launch_bounds__(TXX* TYY / PX) void enc_px(
    const float* __restrict__ feat,      // [16, CIN, H, W]
    const float* __restrict__ w,         // [36, CIN, 3, 3]
    const float* __restrict__ bn_s, const float* __restrict__ bn_b,
    const float* __restrict__ thr, const float* __restrict__ beta_raw,
    __hip_bfloat16* __restrict__ avg,    // [16][H][W][40]
    int H, int W, int tiles_x)
{
    const int TPB = TXX * TYY / PX;
    const int HR  = TYY + 2, HC = TXX + 2;
    __shared__ float fs[CICHUNK][HR][HC];

    const int tid = threadIdx.x;
    const int b   = blockIdx.y;
    const int co0 = blockIdx.z * COCHUNK;
    const int tx0 = (blockIdx.x % tiles_x) * TXX;
    const int ty0 = (blockIdx.x / tiles_x) * TYY;

    const int tx = tid % TXX;
    const int py = tid / TXX;           // owns rows py*PX..py*PX+PX-1

    float acc[COCHUNK][PX];
    #pragma unroll
    for (int j = 0; j < COCHUNK; ++j)
        #pragma unroll
        for (int p = 0; p < PX; ++p) acc[j][p] = 0.f;

    const float* fb = feat + (long)b * CIN * H * W;

    for (int cc = 0; cc < CIN; cc += CICHUNK) {
        for (int i = tid; i < CICHUNK * HR * HC; i += TPB) {
            int ci = i / (HR * HC);
            int r  = i % (HR * HC);
            int hy = r / HC, hx = r % HC;
            int gy = ty0 + hy - 1, gx = tx0 + hx - 1;
            float v = 0.f;
            if (gy >= 0 && gy < H && gx >= 0 && gx < W)
                v = fb[((long)(cc + ci) * H + gy) * W + gx];
            fs[ci][hy][hx] = v;
        }
        __syncthreads();

        for (int ci = 0; ci < CICHUNK; ++ci) {
            float f[PX + 2][3];
            #pragma unroll
            for (int r = 0; r < PX + 2; ++r) {
                f[r][0] = fs[ci][py * PX + r][tx];
                f[r][1] = fs[ci][py * PX + r][tx + 1];
                f[r][2] = fs[ci][py * PX + r][tx + 2];
            }
            const float* wq = w + (long)(cc + ci) * 9;
            #pragma unroll
            for (int j = 0; j < COCHUNK; ++j) {
                const float* ww = wq + (long)(co0 + j) * CIN * 9;  // uniform -> s_load
                #pragma unroll
                for (int p = 0; p < PX; ++p) {
                    acc[j][p] += f[p    ][0] * ww[0] + f[p    ][1] * ww[1] + f[p    ][2] * ww[2]
                               + f[p + 1][0] * ww[3] + f[p + 1][1] * ww[4] + f[p + 1][2] * ww[5]
                               + f[p + 2][0] * ww[6] + f[p + 2][1] * ww[7] + f[p + 2][2] * ww[8];
                }
            }
        }
        __syncthreads();
    }

    float sc[COCHUNK], sb[COCHUNK], bt[COCHUNK], th[COCHUNK];
    #pragma unroll
    for (int j = 0; j < COCHUNK; ++j) {
        int co = co0 + j;
        sc[j] = bn_s[co]; sb[j] = bn_b[co];
        bt[j] = 1.f / (1.f + expf(-beta_raw[co]));
        th[j] = thr[co];
    }

    #pragma unroll
    for (int p = 0; p < PX; ++p) {
        const int oy = ty0 + py * PX + p, ox = tx0 + tx;
        if (oy < H && ox < W) {
            float cnt[COCHUNK];
            #pragma unroll
            for (int j = 0; j < COCHUNK; ++j) {
                float h = acc[j][p] * sc[j] + sb[j];
                float m = 0.f, c2 = 0.f;
                #pragma unroll
                for (int s = 0; s < 4; ++s) {
                    m = bt[j] * m + h;
                    if (m > th[j]) { c2 += 1.f; m -= th[j]; }
                }
                cnt[j] = c2 * 0.25f;
            }
            unsigned* dp = (unsigned*)(avg + ((long)(b * H + oy) * W + ox) * 40 + co0);
            #pragma unroll
            for (int j2 = 0; j2 < COCHUNK / 2; ++j2) {
                __hip_bfloat16 h0 = __float2bfloat16(cnt[2 * j2]);
                __hip_bfloat16 h1 = __float2bfloat16(cnt[2 * j2 + 1]);
                unsigned u0 = *(unsigned short*)&h0;
                unsigned u1 = *(unsigned short*)&h1;
                dp[j2] = u0 | (u1 << 16);
            }
        }
    }
}

// ===========================================================================
// Original encoder (enc5 ci-split + fallback path).
// ===========================================================================
template<int CIN, int CIPER, int CICHUNK, int COCHUNK, int TDIM, bool PARTIAL, bool CL>
__global__ __launch_bounds__(TDIM* TDIM) void enc_tiled(
    const float* __restrict__ feat,
    const float* __restrict__ w,
    const float* __restrict__ bn_s, const float* __restrict__ bn_b,
    const float* __restrict__ thr, const float* __restrict__ beta_raw,
    __hip_bfloat16* __restrict__ avg,
    float* __restrict__ partial,
    int H, int W, int tiles_x)
{
    const int TPB  = TDIM * TDIM;
    const int HALOD = TDIM + 2;
    const int NCO  = 36 / COCHUNK;
    __shared__ float fs[CICHUNK][HALOD][HALOD];

    const int tile = blockIdx.x;
    const int b    = blockIdx.y;
    const int coc  = blockIdx.z % NCO;
    const int cis  = blockIdx.z / NCO;
    const int co0  = coc * COCHUNK;
    const int tx0  = (tile % tiles_x) * TDIM;
    const int ty0  = (tile / tiles_x) * TDIM;

    const int tx = threadIdx.x % TDIM;
    const int ty = threadIdx.x / TDIM;
    const int ox = tx0 + tx, oy = ty0 + ty;

    float acc[COCHUNK];
    #pragma unroll
    for (int c = 0; c < COCHUNK; ++c) acc[c] = 0.f;

    const float* fb = feat + (long)b * CIN * H * W;
    const int ci_base = cis * CIPER;

    for (int cc = ci_base; cc < ci_base + CIPER; cc += CICHUNK) {
        for (int i = threadIdx.x; i < CICHUNK * HALOD * HALOD; i += TPB) {
            int ci = i / (HALOD * HALOD);
            int r  = i % (HALOD * HALOD);
            int hy = r / HALOD, hx = r % HALOD;
            int gy = ty0 + hy - 1, gx = tx0 + hx - 1;
            float v = 0.f;
            if (gy >= 0 && gy < H && gx >= 0 && gx < W)
                v = fb[((long)(cc + ci) * H + gy) * W + gx];
            fs[ci][hy][hx] = v;
        }
        __syncthreads();

        for (int ci = 0; ci < CICHUNK; ++ci) {
            float f0 = fs[ci][ty    ][tx], f1 = fs[ci][ty    ][tx+1], f2 = fs[ci][ty    ][tx+2];
            float f3 = fs[ci][ty + 1][tx], f4 = fs[ci][ty + 1][tx+1], f5 = fs[ci][ty + 1][tx+2];
            float f6 = fs[ci][ty + 2][tx], f7 = fs[ci][ty + 2][tx+1], f8 = fs[ci][ty + 2][tx+2];
            const float* wq = w + (long)(cc + ci) * 9;
            #pragma unroll
            for (int j = 0; j < COCHUNK; ++j) {
                const float* ww = wq + (long)(co0 + j) * CIN * 9;  // uniform -> s_load
                acc[j] += f0 * ww[0] + f1 * ww[1] + f2 * ww[2]
                        + f3 * ww[3] + f4 * ww[4] + f5 * ww[5]
                        + f6 * ww[6] + f7 * ww[7] + f8 * ww[8];
            }
        }
        __syncthreads();
    }

    if (ox < W && oy < H) {
        if (PARTIAL) {
            #pragma unroll
            for (int j = 0; j < COCHUNK; ++j)
                partial[((((long)cis * 16 + b) * 36 + (co0 + j)) * H + oy) * W + ox] = acc[j];
        } else {
            float cnt[COCHUNK];
            #pragma unroll
            for (int j = 0; j < COCHUNK; ++j) {
                int co = co0 + j;
                float h    = acc[j] * bn_s[co] + bn_b[co];
                float beta = 1.f / (1.f + expf(-beta_raw[co]));
                float t    = thr[co];
                float m = 0.f, c2 = 0.f;
                #pragma unroll
                for (int s = 0; s < 4; ++s) {
                    m = beta * m + h;
                    if (m > t) { c2 += 1.f; m -= t; }
                }
                cnt[j] = c2 * 0.25f;
            }
            if (CL) {
                unsigned* dp = (unsigned*)(avg + ((long)(b * H + oy) * W + ox) * 40 + co0);
                #pragma unroll
                for (int j2 = 0; j2 < COCHUNK / 2; ++j2) {
                    __hip_bfloat16 h0 = __float2bfloat16(cnt[2 * j2]);
                    __hip_bfloat16 h1 = __float2bfloat16(cnt[2 * j2 + 1]);
                    unsigned u0 = *(unsigned short*)&h0;
                    unsigned u1 = *(unsigned short*)&h1;
                    dp[j2] = u0 | (u1 << 16);
                }
            } else {
                #pragma unroll
                for (int j = 0; j < COCHUNK; ++j)
                    avg[(((long)b * 36 + (co0 + j)) * H + oy) * W + ox] = __float2bfloat16(cnt[j]);
            }
        }
    }
}

// ===========================================================================
// Combine ci-split partials + BN + LIF + mean -> bf16 avg (CL or NCHW).
// ===========================================================================
template<int SPLITS, bool CL>
__global__ __launch_bounds__(256) void combine_lif(
    const float* __restrict__ partial,
    const float* __restrict__ bn_s, const float* __restrict__ bn_b,
    const float* __restrict__ thr, const float* __restrict__ beta_raw,
    __hip_bfloat16* __restrict__ avg, int H, int W, int total)
{
    int idx = blockIdx.x * 256 + threadIdx.x;
    if (idx >= total) return;
    int HW = H * W;
    int co = (idx / HW) % 36;
    float h = 0.f;
    #pragma unroll
    for (int s = 0; s < SPLITS; ++s) h += partial[(long)s * total + idx];
    h = h * bn_s[co] + bn_b[co];
    float beta = 1.f / (1.f + expf(-beta_raw[co]));
    float t    = thr[co];
    float m = 0.f, cnt = 0.f;
    #pragma unroll
    for (int s = 0; s < 4; ++s) {
        m = beta * m + h;
        if (m > t) { cnt += 1.f; m -= t; }
    }
    if (CL) {
        int b = idx / (36 * HW);
        int rem = idx % HW;
        int y = rem / W, x = rem % W;
        avg[((long)(b * H + y) * W + x) * 40 + co] = __float2bfloat16(cnt * 0.25f);
    } else {
        avg[idx] = __float2bfloat16(cnt * 0.25f);
    }
}

// ===========================================================================
// Weight prepack for MFMA decoder.
// ===========================================================================
__global__ __launch_bounds__(256) void pack_w(
    const float* __restrict__ w, __hip_bfloat16* __restrict__ ap, int total)
{
    int idx = blockIdx.x * 256 + threadIdx.x;   // one per (cg,s,h,m)
    if (idx >= total) return;
    int m  = idx & 31;
    int h  = (idx >> 5) & 1;
    int s  = (idx >> 6) % 23;
    int cg = idx / (23 * 64);
    int o  = 2 * s + h;
    int co = cg * 32 + m;
    unsigned short v[8];
    #pragma unroll
    for (int j = 0; j < 8; ++j) {
        float x = 0.f;
        if (o < 45) {
            int tap = o / 5, oct = o % 5, ci = oct * 8 + j;
            if (ci < 36) x = w[(long)co * 324 + ci * 9 + tap];
        }
        __hip_bfloat16 hv = __float2bfloat16(x);
        v[j] = *(unsigned short*)&hv;
    }
    *(int4v*)(ap + (long)idx * 8) = *(int4v*)v;
}

// ===========================================================================
// MFMA decoder: conv3x3(36->Cout) + BN + SiLU.
// ===========================================================================
template<int COG>
__global__ __launch_bounds__(256) void dec_mfma(
    const __hip_bfloat16* __restrict__ avg_cl,   // [B][H][W][40]
    const __hip_bfloat16* __restrict__ apack,
    const float* __restrict__ bn_s, const float* __restrict__ bn_b,
    float* __restrict__ out, int Cout, int H, int W, int tiles_x)
{
    __shared__ __hip_bfloat16 tile[12960];       // [18][18][40] = 25920 B

    const int tid    = threadIdx.x;
    const int b      = blockIdx.y;
    const int cgbase = blockIdx.z * COG;
    const int tx0 = (blockIdx.x % tiles_x) * 16;
    const int ty0 = (blockIdx.x / tiles_x) * 16;

    {   // stage halo tile (channel-last), zero-padded, b128 both sides
        const __hip_bfloat16* ab = avg_cl + (long)b * H * W * 40;
        for (int i = tid; i < 1620; i += 256) {
            int row = i / 90, u = i - row * 90;
            int px = u / 5, un = u - px * 5;
            int gy = ty0 + row - 1, gx = tx0 + px - 1;
            int4v v = {0, 0, 0, 0};
            if (gy >= 0 && gy < H && gx >= 0 && gx < W)
                v = *(const int4v*)(ab + ((long)gy * W + gx) * 40 + un * 8);
            *(int4v*)(tile + (row * 18 + px) * 40 + un * 8) = v;
        }
    }
    __syncthreads();

    const int lane = tid & 63;
    const int wv   = tid >> 6;
    const int h    = lane >> 5;
    const int n    = lane & 31;
    const int lx   = n & 15;
    const int ly0  = wv * 4 + (n >> 4);

    const char* tb  = (const char*)tile;
    const int   bb0 = ((ly0 + 1) * 18 + (lx + 1)) * 80;
    const int   bb1 = bb0 + 2 * 18 * 80;

    const char* ap = (const char*)apack + (long)cgbase * 23552 + h * 512 + n * 16;

    f32x16 acc[COG][2];
    #pragma unroll
    for (int cg = 0; cg < COG; ++cg)
        #pragma unroll
        for (int pf = 0; pf < 2; ++pf)
            #pragma unroll
            for (int k = 0; k < 16; ++k) acc[cg][pf][k] = 0.f;

    #pragma unroll
    for (int s = 0; s < 23; ++s) {
        int o0 = 2 * s;     if (o0 > 44) o0 = 44;
        int o1 = 2 * s + 1; if (o1 > 44) o1 = 44;
        const int C0 = ((o0 / 5) / 3 - 1) * 1440 + ((o0 / 5) % 3 - 1) * 80 + (o0 % 5) * 16;
        const int C1 = ((o1 / 5) / 3 - 1) * 1440 + ((o1 / 5) % 3 - 1) * 80 + (o1 % 5) * 16;
        const int offc = h ? C1 : C0;
        short8v bf0 = *(const short8v*)(tb + (bb0 + offc));
        short8v bf1 = *(const short8v*)(tb + (bb1 + offc));
        #pragma unroll
        for (int cg = 0; cg < COG; ++cg) {
            short8v af = *(const short8v*)(ap + cg * 23552 + s * 1024);
            acc[cg][0] = __builtin_amdgcn_mfma_f32_32x32x16_bf16(af, bf0, acc[cg][0], 0, 0, 0);
            acc[cg][1] = __builtin_amdgcn_mfma_f32_32x32x16_bf16(af, bf1, acc[cg][1], 0, 0, 0);
        }
    }

    #pragma unroll
    for (int cg = 0; cg < COG; ++cg) {
        #pragma unroll
        for (int r = 0; r < 16; ++r) {
            const int co = ((cgbase + cg) << 5) + (r & 3) + ((r >> 2) << 3) + (h << 2);
            const float sc = bn_s[co], bc = bn_b[co];
            #pragma unroll
            for (int pf = 0; pf < 2; ++pf) {
                const int ly = ly0 + pf * 2;
                const int gy = ty0 + ly, gx = tx0 + lx;
                float v = acc[cg][pf][r] * sc + bc;
                v = v / (1.f + __expf(-v));
                if (gy < H && gx < W)
                    out[(((long)b * Cout + co) * H + gy) * W + gx] = v;
            }
        }
    }
}

// ===========================================================================
// Fallback decoder (VALU, NCHW avg).
// ===========================================================================
template<int COCHUNK, int TDIM>
__global__ __launch_bounds__(TDIM* TDIM) void dec_tiled(
    const __hip_bfloat16* __restrict__ avg,
    const float* __restrict__ w,
    const float* __restrict__ bn_s, const float* __restrict__ bn_b,
    float* __restrict__ out,
    int Cout, int H, int W, int tiles_x)
{
    const int CIN = 36;
    const int TPB = TDIM * TDIM;
    const int HALOD = TDIM + 2;
    __shared__ float fs[CIN][HALOD][HALOD];

    const int tile = blockIdx.x;
    const int b    = blockIdx.y;
    const int co0  = blockIdx.z * COCHUNK;
    const int tx0  = (tile % tiles_x) * TDIM;
    const int ty0  = (tile / tiles_x) * TDIM;

    const int tx = threadIdx.x % TDIM;
    const int ty = threadIdx.x / TDIM;
    const int ox = tx0 + tx, oy = ty0 + ty;

    const __hip_bfloat16* ab = avg + (long)b * CIN * H * W;

    for (int i = threadIdx.x; i < CIN * HALOD * HALOD; i += TPB) {
        int ci = i / (HALOD * HALOD);
        int r  = i % (HALOD * HALOD);
        int hy = r / HALOD, hx = r % HALOD;
        int gy = ty0 + hy - 1, gx = tx0 + hx - 1;
        float v = 0.f;
        if (gy >= 0 && gy < H && gx >= 0 && gx < W)
            v = __bfloat162float(ab[((long)ci * H + gy) * W + gx]);
        fs[ci][hy][hx] = v;
    }
    __syncthreads();

    float acc[COCHUNK];
    #pragma unroll
    for (int j = 0; j < COCHUNK; ++j) acc[j] = 0.f;

    for (int ci = 0; ci < CIN; ++ci) {
        float f0 = fs[ci][ty    ][tx], f1 = fs[ci][ty    ][tx+1], f2 = fs[ci][ty    ][tx+2];
        float f3 = fs[ci][ty + 1][tx], f4 = fs[ci][ty + 1][tx+1], f5 = fs[ci][ty + 1][tx+2];
        float f6 = fs[ci][ty + 2][tx], f7 = fs[ci][ty + 2][tx+1], f8 = fs[ci][ty + 2][tx+2];
        #pragma unroll
        for (int j = 0; j < COCHUNK; ++j) {
            const float* ww = w + ((long)(co0 + j) * CIN + ci) * 9;
            acc[j] += f0 * ww[0] + f1 * ww[1] + f2 * ww[2]
                    + f3 * ww[3] + f4 * ww[4] + f5 * ww[5]
                    + f6 * ww[6] + f7 * ww[7] + f8 * ww[8];
        }
    }

    if (ox < W && oy < H) {
        #pragma unroll
        for (int j = 0; j < COCHUNK; ++j) {
            int co = co0 + j;
            float v = acc[j] * bn_s[co] + bn_b[co];
            out[(((long)b * Cout + co) * H + oy) * W + ox] = v / (1.f + expf(-v));
        }
    }
}

// ===========================================================================
extern "C" void kernel_launch(void* const* d_in, const int* in_sizes, int n_in,
                              void* d_out, int out_size, void* d_ws, size_t ws_size,
                              hipStream_t stream)
{
    const int B = 16;
    const int C[3] = {64, 128, 256};
    const int S[3] = {160, 80, 40};

    float* out = (float*)d_out;
    long out_off[3]; long off = 0;
    for (int l = 0; l < 3; ++l) { out_off[l] = off; off += (long)B * C[l] * S[l] * S[l]; }

    // ---- new-path workspace layout (bytes) ----
    const long avgcl_bytes[3] = {32768000L, 8192000L, 2048000L};   // B*H*W*40*2
    long avgcl_off[3]; long boff = 0;
    for (int l = 0; l < 3; ++l) { avgcl_off[l] = boff; boff += avgcl_bytes[l]; }
    const long avgcl_total = boff;
    const long ap_bytes[3] = {47104L, 94208L, 188416L};             // (C/32)*23552
    long ap_off[3];
    for (int l = 0; l < 3; ++l) { ap_off[l] = boff; boff += ap_bytes[l]; }
    const long part5_off = boff;
    const long part5_bytes = 4L * B * 36 * 1600 * 4;
    const size_t need_full = (size_t)(part5_off + part5_bytes);
    const size_t need_min  = (size_t)part5_off;

    char* wsb = (char*)d_ws;

    if (ws_size >= need_min) {
        // ================= NEW PATH =================
        const bool split5 = ws_size >= need_full;
        hipMemsetAsync(wsb, 0, avgcl_total, stream);   // zero avg_cl incl. ci-pad

        for (int l = 0; l < 3; ++l) {
            const float* dec_w = (const float*)d_in[9 * l + 6];
            int total = (C[l] / 32) * 23 * 2 * 32;
            pack_w<<<(total + 255) / 256, 256, 0, stream>>>(
                dec_w, (__hip_bfloat16*)(wsb + ap_off[l]), total);
        }

        for (int l = 0; l < 3; ++l) {
            const int base = 9 * l;
            const float* feat     = (const float*)d_in[base + 0];
            const float* enc_w    = (const float*)d_in[base + 1];
            const float* enc_bn_s = (const float*)d_in[base + 2];
            const float* enc_bn_b = (const float*)d_in[base + 3];
            const float* enc_thr  = (const float*)d_in[base + 4];
            const float* enc_beta = (const float*)d_in[base + 5];
            const float* dec_bn_s = (const float*)d_in[base + 7];
            const float* dec_bn_b = (const float*)d_in[base + 8];

            const int Hs = S[l], Wsz = S[l];
            __hip_bfloat16* avg_cl = (__hip_bfloat16*)(wsb + avgcl_off[l]);
            const __hip_bfloat16* ap = (const __hip_bfloat16*)(wsb + ap_off[l]);
            float* r = out + out_off[l];

            if (l == 0) {
                // 160x160: 5x7 tiles of 32x24 (last row masked), 256 thr,
                // PX=3 (FMA:s_load=3), 12-co window, pledged VGPR budget.
                dim3 eg(35, B, 3);
                enc_px_p<64, 8, 12, 32, 24, 3><<<eg, 256, 0, stream>>>(
                    feat, enc_w, enc_bn_s, enc_bn_b, enc_thr, enc_beta, avg_cl, Hs, Wsz, 5);
                dim3 dg(100, B, 1);
                dec_mfma<2><<<dg, 256, 0, stream>>>(avg_cl, ap, dec_bn_s, dec_bn_b, r, 64, Hs, Wsz, 10);
            } else if (l == 1) {
                // 80x80: 5x3 tiles of 16x32 (last row masked), R8-proven config.
                dim3 eg(15, B, 3);
                enc_px<128, 8, 12, 16, 32, 2><<<eg, 256, 0, stream>>>(
                    feat, enc_w, enc_bn_s, enc_bn_b, enc_thr, enc_beta, avg_cl, Hs, Wsz, 5);
                dim3 dg(25, B, 1);
                dec_mfma<4><<<dg, 256, 0, stream>>>(avg_cl, ap, dec_bn_s, dec_bn_b, r, 128, Hs, Wsz, 5);
            } else {
                if (split5) {
                    float* partial5 = (float*)(wsb + part5_off);
                    dim3 eg(25, B, 12);   // 4 ci-splits x 3 co-chunks
                    enc_tiled<256, 64, 16, 12, 8, true, true><<<eg, 64, 0, stream>>>(
                        feat, enc_w, enc_bn_s, enc_bn_b, enc_thr, enc_beta, nullptr, partial5, Hs, Wsz, 5);
                    int total = B * 36 * Hs * Wsz;
                    combine_lif<4, true><<<(total + 255) / 256, 256, 0, stream>>>(
                        partial5, enc_bn_s, enc_bn_b, enc_thr, enc_beta, avg_cl, Hs, Wsz, total);
                } else {
                    dim3 eg(25, B, 3);
                    enc_tiled<256, 256, 16, 12, 8, false, true><<<eg, 64, 0, stream>>>(
                        feat, enc_w, enc_bn_s, enc_bn_b, enc_thr, enc_beta, avg_cl, nullptr, Hs, Wsz, 5);
                }
                dim3 dg(9, B, 2);
                dec_mfma<4><<<dg, 256, 0, stream>>>(avg_cl, ap, dec_bn_s, dec_bn_b, r, 256, Hs, Wsz, 3);
            }
        }
    } else {
        // ================= FALLBACK (NCHW, VALU decoder) =================
        __hip_bfloat16* ws = (__hip_bfloat16*)d_ws;
        long avg_off2[3]; long eoff = 0;
        for (int l = 0; l < 3; ++l) { avg_off2[l] = eoff; eoff += (long)B * 36 * S[l] * S[l]; }
        float* partial5 = (float*)(ws + ((eoff + 7) & ~7L));
        const long part5f = 4L * B * 36 * 40 * 40;
        const size_t old_need = (size_t)((eoff + 7) & ~7L) * 2 + part5f * 4;
        const bool split5 = ws_size >= old_need;

        for (int l = 0; l < 3; ++l) {
            const int base = 9 * l;
            const float* feat     = (const float*)d_in[base + 0];
            const float* enc_w    = (const float*)d_in[base + 1];
            const float* enc_bn_s = (const float*)d_in[base + 2];
            const float* enc_bn_b = (const float*)d_in[base + 3];
            const float* enc_thr  = (const float*)d_in[base + 4];
            const float* enc_beta = (const float*)d_in[base + 5];
            const float* dec_w    = (const float*)d_in[base + 6];
            const float* dec_bn_s = (const float*)d_in[base + 7];
            const float* dec_bn_b = (const float*)d_in[base + 8];

            const int Hs = S[l], Wsz = S[l], Cl = C[l];
            __hip_bfloat16* avg = ws + avg_off2[l];
            float* r = out + out_off[l];

            if (l == 0) {
                dim3 eg(100, B, 3);
                enc_tiled<64, 64, 16, 12, 16, false, false><<<eg, 256, 0, stream>>>(
                    feat, enc_w, enc_bn_s, enc_bn_b, enc_thr, enc_beta, avg, nullptr, Hs, Wsz, 10);
                dim3 dg(100, B, 2);
                dec_tiled<32, 16><<<dg, 256, 0, stream>>>(avg, dec_w, dec_bn_s, dec_bn_b, r, Cl, Hs, Wsz, 10);
            } else if (l == 1) {
                dim3 eg(25, B, 3);
                enc_tiled<128, 128, 16, 12, 16, false, false><<<eg, 256, 0, stream>>>(
                    feat, enc_w, enc_bn_s, enc_bn_b, enc_thr, enc_beta, avg, nullptr, Hs, Wsz, 5);
                dim3 dg(25, B, 4);
                dec_tiled<32, 16><<<dg, 256, 0, stream>>>(avg, dec_w, dec_bn_s, dec_bn_b, r, Cl, Hs, Wsz, 5);
            } else {
                if (split5) {
                    dim3 eg(25, B, 12);
                    enc_tiled<256, 64, 16, 12, 8, true, false><<<eg, 64, 0, stream>>>(
                        feat, enc_w, enc_bn_s, enc_bn_b, enc_thr, enc_beta, nullptr, partial5, Hs, Wsz, 5);
                    int total = B * 36 * Hs * Wsz;
                    combine_lif<4, false><<<(total + 255) / 256, 256, 0, stream>>>(
                        partial5, enc_bn_s, enc_bn_b, enc_thr, enc_beta, avg, Hs, Wsz, total);
                } else {
                    dim3 eg(25, B, 3);
                    enc_tiled<256, 256, 16, 12, 8, false, false><<<eg, 64, 0, stream>>>(
                        feat, enc_w, enc_bn_s, enc_bn_b, enc_thr, enc_beta, avg, nullptr, Hs, Wsz, 5);
                }
                dim3 dg(25, B, 16);
                dec_tiled<16, 8><<<dg, 64, 0, stream>>>(avg, dec_w, dec_bn_s, dec_bn_b, r, Cl, Hs, Wsz, 5);
            }
        }
    }
}

// Round 12
// 907.040 us; speedup vs baseline: 1.5967x; 1.0872x over previous
//
#include <hip/hip_runtime.h>
#include <hip/hip_bf16.h>

typedef __attribute__((ext_vector_type(8)))  short short8v;
typedef __attribute__((ext_vector_type(16))) float f32x16;
typedef __attribute__((ext_vector_type(4)))  int   int4v;

// ===========================================================================
// Encoder weight prepack for MFMA (split bf16 hi/lo).
// Layout [cg][c][s(tap)][h(loc)][m(32)][j(8)], 16B per (..m): flat = idx*8.
// ci = c*16 + h*8 + j ; value = W[co][ci][tap], co = cg*32+m (0 if co>=36).
// hi = bf16(v), lo = bf16(v - hi).
// ===========================================================================
template<int CIN>
__global__ __launch_bounds__(256) void pack_we(
    const float* __restrict__ w, __hip_bfloat16* __restrict__ whi,
    __hip_bfloat16* __restrict__ wlo, int total)
{
    const int NCHUNK = CIN / 16;
    int idx = blockIdx.x * 256 + threadIdx.x;
    if (idx >= total) return;
    int m  = idx & 31;
    int h  = (idx >> 5) & 1;
    int s  = (idx >> 6) % 9;
    int c  = (idx / 576) % NCHUNK;
    int cg = idx / (576 * NCHUNK);
    int co = cg * 32 + m;
    unsigned short vh[8], vl[8];
    #pragma unroll
    for (int j = 0; j < 8; ++j) {
        int ci = c * 16 + h * 8 + j;
        float x = (co < 36) ? w[(long)co * CIN * 9 + ci * 9 + s] : 0.f;
        __hip_bfloat16 xh = __float2bfloat16(x);
        float rem = x - __bfloat162float(xh);
        __hip_bfloat16 xl = __float2bfloat16(rem);
        vh[j] = *(unsigned short*)&xh;
        vl[j] = *(unsigned short*)&xl;
    }
    *(int4v*)(whi + (long)idx * 8) = *(int4v*)vh;
    *(int4v*)(wlo + (long)idx * 8) = *(int4v*)vl;
}

// ===========================================================================
// MFMA encoder: conv3x3(CIN->36) + BN + LIF(T=4) + mean, split-bf16.
// 16x16 px tile, 4 waves, 2 co-groups of 32 (co>=36 padded-zero, masked).
// Per ci-chunk (16): stage fp32 feat -> LDS bf16 hi/lo [324 px][24 shorts]
// (48B rows: 16B-aligned b128 frag reads, ~4-way banks). K-step s = tap;
// h=lane>>5 selects ci-octet (A-pack h dim). 3 MFMA per term-pair:
// hi*hi + hi*lo + lo*hi (lo*lo ~2^-18 dropped -> h error ~2e-6, fp32-level).
// Fragment scheme identical to dec_mfma (verified in-situ):
//   A: m=lane&31=co, k=h*8+j ; B: n=lane&31=px ; D: co=(r&3)+8(r>>2)+4h.
// ===========================================================================
template<int CIN>
__global__ __launch_bounds__(256) void enc_mfma(
    const float* __restrict__ feat,          // [16, CIN, H, W]
    const __hip_bfloat16* __restrict__ whi,  // packed hi
    const __hip_bfloat16* __restrict__ wlo,  // packed lo
    const float* __restrict__ bn_s, const float* __restrict__ bn_b,
    const float* __restrict__ thr, const float* __restrict__ beta_raw,
    __hip_bfloat16* __restrict__ avg,        // [16][H][W][40]
    int H, int W, int tiles_x)
{
    const int NCHUNK = CIN / 16;
    __shared__ __align__(16) short hi_t[324 * 24];
    __shared__ __align__(16) short lo_t[324 * 24];

    const int tid = threadIdx.x;
    const int b   = blockIdx.y;
    const int tx0 = (blockIdx.x % tiles_x) * 16;
    const int ty0 = (blockIdx.x / tiles_x) * 16;

    const int lane = tid & 63;
    const int wv   = tid >> 6;
    const int h    = lane >> 5;
    const int n    = lane & 31;
    const int lx   = n & 15;
    const int ly0  = wv * 4 + (n >> 4);

    f32x16 acc[2][2];   // [cg][pf]
    #pragma unroll
    for (int cg = 0; cg < 2; ++cg)
        #pragma unroll
        for (int pf = 0; pf < 2; ++pf)
            #pragma unroll
            for (int k = 0; k < 16; ++k) acc[cg][pf][k] = 0.f;

    const float* fb = feat + (long)b * CIN * H * W;
    const char* aph = (const char*)whi + h * 512 + n * 16;
    const char* apl = (const char*)wlo + h * 512 + n * 16;
    const long  cgstride = (long)NCHUNK * 9216;

    for (int c = 0; c < NCHUNK; ++c) {
        // ---- stage chunk: fp32 -> bf16 hi/lo, coalesced reads along x ----
        for (int i = tid; i < 324 * 16; i += 256) {
            int cil = i / 324;          // 0..15
            int p   = i - cil * 324;    // px in 18x18 halo
            int hy = p / 18, hx = p - hy * 18;
            int gy = ty0 + hy - 1, gx = tx0 + hx - 1;
            float v = 0.f;
            if (gy >= 0 && gy < H && gx >= 0 && gx < W)
                v = fb[((long)(c * 16 + cil) * H + gy) * W + gx];
            __hip_bfloat16 vh = __float2bfloat16(v);
            float rem = v - __bfloat162float(vh);
            __hip_bfloat16 vl = __float2bfloat16(rem);
            hi_t[p * 24 + cil] = *(short*)&vh;
            lo_t[p * 24 + cil] = *(short*)&vl;
        }
        __syncthreads();

        const char* ahc = aph + (long)c * 9216;
        const char* alc = apl + (long)c * 9216;
        #pragma unroll
        for (int s = 0; s < 9; ++s) {
            const int dy = s / 3, dx = s % 3;
            const int p0 = (ly0 + dy) * 18 + (lx + dx);   // pf=0
            const int p1 = p0 + 36;                        // pf=1 (+2 rows)
            short8v bh0 = *(const short8v*)((const char*)hi_t + p0 * 48 + h * 16);
            short8v bh1 = *(const short8v*)((const char*)hi_t + p1 * 48 + h * 16);
            short8v bl0 = *(const short8v*)((const char*)lo_t + p0 * 48 + h * 16);
            short8v bl1 = *(const short8v*)((const char*)lo_t + p1 * 48 + h * 16);
            #pragma unroll
            for (int cg = 0; cg < 2; ++cg) {
                short8v af = *(const short8v*)(ahc + cg * cgstride + s * 1024);
                short8v al = *(const short8v*)(alc + cg * cgstride + s * 1024);
                acc[cg][0] = __builtin_amdgcn_mfma_f32_32x32x16_bf16(af, bh0, acc[cg][0], 0, 0, 0);
                acc[cg][0] = __builtin_amdgcn_mfma_f32_32x32x16_bf16(af, bl0, acc[cg][0], 0, 0, 0);
                acc[cg][0] = __builtin_amdgcn_mfma_f32_32x32x16_bf16(al, bh0, acc[cg][0], 0, 0, 0);
                acc[cg][1] = __builtin_amdgcn_mfma_f32_32x32x16_bf16(af, bh1, acc[cg][1], 0, 0, 0);
                acc[cg][1] = __builtin_amdgcn_mfma_f32_32x32x16_bf16(af, bl1, acc[cg][1], 0, 0, 0);
                acc[cg][1] = __builtin_amdgcn_mfma_f32_32x32x16_bf16(al, bh1, acc[cg][1], 0, 0, 0);
            }
        }
        __syncthreads();
    }

    // ---- epilogue: BN + LIF + mean, masked store (co<36, px in range) ----
    #pragma unroll
    for (int cg = 0; cg < 2; ++cg) {
        #pragma unroll
        for (int r = 0; r < 16; ++r) {
            const int co = (cg << 5) + (r & 3) + ((r >> 2) << 3) + (h << 2);
            if (co < 36) {
                const float sc   = bn_s[co], sb = bn_b[co];
                const float beta = 1.f / (1.f + expf(-beta_raw[co]));
                const float t    = thr[co];
                #pragma unroll
                for (int pf = 0; pf < 2; ++pf) {
                    const int gy = ty0 + ly0 + pf * 2, gx = tx0 + lx;
                    float hv = acc[cg][pf][r] * sc + sb;
                    float m = 0.f, c2 = 0.f;
                    #pragma unroll
                    for (int s4 = 0; s4 < 4; ++s4) {
                        m = beta * m + hv;
                        if (m > t) { c2 += 1.f; m -= t; }
                    }
                    if (gy < H && gx < W)
                        avg[((long)(b * H + gy) * W + gx) * 40 + co] =
                            __float2bfloat16(c2 * 0.25f);
                }
            }
        }
    }
}

// ===========================================================================
// enc_px (R8-exact): used for enc4. acc <= 24, TPB 256, TXX pow2.
// ===========================================================================
template<int CIN, int CICHUNK, int COCHUNK, int TXX, int TYY, int PX>
__global__ __launch_bounds__(TXX* TYY / PX) void enc_px(
    const float* __restrict__ feat,
    const float* __restrict__ w,
    const float* __restrict__ bn_s, const float* __restrict__ bn_b,
    const float* __restrict__ thr, const float* __restrict__ beta_raw,
    __hip_bfloat16* __restrict__ avg,
    int H, int W, int tiles_x)
{
    const int TPB = TXX * TYY / PX;
    const int HR  = TYY + 2, HC = TXX + 2;
    __shared__ float fs[CICHUNK][HR][HC];

    const int tid = threadIdx.x;
    const int b   = blockIdx.y;
    const int co0 = blockIdx.z * COCHUNK;
    const int tx0 = (blockIdx.x % tiles_x) * TXX;
    const int ty0 = (blockIdx.x / tiles_x) * TYY;

    const int tx = tid % TXX;
    const int py = tid / TXX;

    float acc[COCHUNK][PX];
    #pragma unroll
    for (int j = 0; j < COCHUNK; ++j)
        #pragma unroll
        for (int p = 0; p < PX; ++p) acc[j][p] = 0.f;

    const float* fb = feat + (long)b * CIN * H * W;

    for (int cc = 0; cc < CIN; cc += CICHUNK) {
        for (int i = tid; i < CICHUNK * HR * HC; i += TPB) {
            int ci = i / (HR * HC);
            int r  = i % (HR * HC);
            int hy = r / HC, hx = r % HC;
            int gy = ty0 + hy - 1, gx = tx0 + hx - 1;
            float v = 0.f;
            if (gy >= 0 && gy < H && gx >= 0 && gx < W)
                v = fb[((long)(cc + ci) * H + gy) * W + gx];
            fs[ci][hy][hx] = v;
        }
        __syncthreads();

        for (int ci = 0; ci < CICHUNK; ++ci) {
            float f[PX + 2][3];
            #pragma unroll
            for (int r = 0; r < PX + 2; ++r) {
                f[r][0] = fs[ci][py * PX + r][tx];
                f[r][1] = fs[ci][py * PX + r][tx + 1];
                f[r][2] = fs[ci][py * PX + r][tx + 2];
            }
            const float* wq = w + (long)(cc + ci) * 9;
            #pragma unroll
            for (int j = 0; j < COCHUNK; ++j) {
                const float* ww = wq + (long)(co0 + j) * CIN * 9;
                #pragma unroll
                for (int p = 0; p < PX; ++p) {
                    acc[j][p] += f[p    ][0] * ww[0] + f[p    ][1] * ww[1] + f[p    ][2] * ww[2]
                               + f[p + 1][0] * ww[3] + f[p + 1][1] * ww[4] + f[p + 1][2] * ww[5]
                               + f[p + 2][0] * ww[6] + f[p + 2][1] * ww[7] + f[p + 2][2] * ww[8];
                }
            }
        }
        __syncthreads();
    }

    float sc[COCHUNK], sb[COCHUNK], bt[COCHUNK], th[COCHUNK];
    #pragma unroll
    for (int j = 0; j < COCHUNK; ++j) {
        int co = co0 + j;
        sc[j] = bn_s[co]; sb[j] = bn_b[co];
        bt[j] = 1.f / (1.f + expf(-beta_raw[co]));
        th[j] = thr[co];
    }

    #pragma unroll
    for (int p = 0; p < PX; ++p) {
        const int oy = ty0 + py * PX + p, ox = tx0 + tx;
        if (oy < H && ox < W) {
            float cnt[COCHUNK];
            #pragma unroll
            for (int j = 0; j < COCHUNK; ++j) {
                float hh = acc[j][p] * sc[j] + sb[j];
                float m = 0.f, c2 = 0.f;
                #pragma unroll
                for (int s = 0; s < 4; ++s) {
                    m = bt[j] * m + hh;
                    if (m > th[j]) { c2 += 1.f; m -= th[j]; }
                }
                cnt[j] = c2 * 0.25f;
            }
            unsigned* dp = (unsigned*)(avg + ((long)(b * H + oy) * W + ox) * 40 + co0);
            #pragma unroll
            for (int j2 = 0; j2 < COCHUNK / 2; ++j2) {
                __hip_bfloat16 h0 = __float2bfloat16(cnt[2 * j2]);
                __hip_bfloat16 h1 = __float2bfloat16(cnt[2 * j2 + 1]);
                unsigned u0 = *(unsigned short*)&h0;
                unsigned u1 = *(unsigned short*)&h1;
                dp[j2] = u0 | (u1 << 16);
            }
        }
    }
}

// ===========================================================================
// Original encoder (enc5 ci-split + fallback path).
// ===========================================================================
template<int CIN, int CIPER, int CICHUNK, int COCHUNK, int TDIM, bool PARTIAL, bool CL>
__global__ __launch_bounds__(TDIM* TDIM) void enc_tiled(
    const float* __restrict__ feat,
    const float* __restrict__ w,
    const float* __restrict__ bn_s, const float* __restrict__ bn_b,
    const float* __restrict__ thr, const float* __restrict__ beta_raw,
    __hip_bfloat16* __restrict__ avg,
    float* __restrict__ partial,
    int H, int W, int tiles_x)
{
    const int TPB  = TDIM * TDIM;
    const int HALOD = TDIM + 2;
    const int NCO  = 36 / COCHUNK;
    __shared__ float fs[CICHUNK][HALOD][HALOD];

    const int tile = blockIdx.x;
    const int b    = blockIdx.y;
    const int coc  = blockIdx.z % NCO;
    const int cis  = blockIdx.z / NCO;
    const int co0  = coc * COCHUNK;
    const int tx0  = (tile % tiles_x) * TDIM;
    const int ty0  = (tile / tiles_x) * TDIM;

    const int tx = threadIdx.x % TDIM;
    const int ty = threadIdx.x / TDIM;
    const int ox = tx0 + tx, oy = ty0 + ty;

    float acc[COCHUNK];
    #pragma unroll
    for (int c = 0; c < COCHUNK; ++c) acc[c] = 0.f;

    const float* fb = feat + (long)b * CIN * H * W;
    const int ci_base = cis * CIPER;

    for (int cc = ci_base; cc < ci_base + CIPER; cc += CICHUNK) {
        for (int i = threadIdx.x; i < CICHUNK * HALOD * HALOD; i += TPB) {
            int ci = i / (HALOD * HALOD);
            int r  = i % (HALOD * HALOD);
            int hy = r / HALOD, hx = r % HALOD;
            int gy = ty0 + hy - 1, gx = tx0 + hx - 1;
            float v = 0.f;
            if (gy >= 0 && gy < H && gx >= 0 && gx < W)
                v = fb[((long)(cc + ci) * H + gy) * W + gx];
            fs[ci][hy][hx] = v;
        }
        __syncthreads();

        for (int ci = 0; ci < CICHUNK; ++ci) {
            float f0 = fs[ci][ty    ][tx], f1 = fs[ci][ty    ][tx+1], f2 = fs[ci][ty    ][tx+2];
            float f3 = fs[ci][ty + 1][tx], f4 = fs[ci][ty + 1][tx+1], f5 = fs[ci][ty + 1][tx+2];
            float f6 = fs[ci][ty + 2][tx], f7 = fs[ci][ty + 2][tx+1], f8 = fs[ci][ty + 2][tx+2];
            const float* wq = w + (long)(cc + ci) * 9;
            #pragma unroll
            for (int j = 0; j < COCHUNK; ++j) {
                const float* ww = wq + (long)(co0 + j) * CIN * 9;
                acc[j] += f0 * ww[0] + f1 * ww[1] + f2 * ww[2]
                        + f3 * ww[3] + f4 * ww[4] + f5 * ww[5]
                        + f6 * ww[6] + f7 * ww[7] + f8 * ww[8];
            }
        }
        __syncthreads();
    }

    if (ox < W && oy < H) {
        if (PARTIAL) {
            #pragma unroll
            for (int j = 0; j < COCHUNK; ++j)
                partial[((((long)cis * 16 + b) * 36 + (co0 + j)) * H + oy) * W + ox] = acc[j];
        } else {
            float cnt[COCHUNK];
            #pragma unroll
            for (int j = 0; j < COCHUNK; ++j) {
                int co = co0 + j;
                float hh   = acc[j] * bn_s[co] + bn_b[co];
                float beta = 1.f / (1.f + expf(-beta_raw[co]));
                float t    = thr[co];
                float m = 0.f, c2 = 0.f;
                #pragma unroll
                for (int s = 0; s < 4; ++s) {
                    m = beta * m + hh;
                    if (m > t) { c2 += 1.f; m -= t; }
                }
                cnt[j] = c2 * 0.25f;
            }
            if (CL) {
                unsigned* dp = (unsigned*)(avg + ((long)(b * H + oy) * W + ox) * 40 + co0);
                #pragma unroll
                for (int j2 = 0; j2 < COCHUNK / 2; ++j2) {
                    __hip_bfloat16 h0 = __float2bfloat16(cnt[2 * j2]);
                    __hip_bfloat16 h1 = __float2bfloat16(cnt[2 * j2 + 1]);
                    unsigned u0 = *(unsigned short*)&h0;
                    unsigned u1 = *(unsigned short*)&h1;
                    dp[j2] = u0 | (u1 << 16);
                }
            } else {
                #pragma unroll
                for (int j = 0; j < COCHUNK; ++j)
                    avg[(((long)b * 36 + (co0 + j)) * H + oy) * W + ox] = __float2bfloat16(cnt[j]);
            }
        }
    }
}

// ===========================================================================
// Combine ci-split partials + BN + LIF + mean -> bf16 avg (CL or NCHW).
// ===========================================================================
template<int SPLITS, bool CL>
__global__ __launch_bounds__(256) void combine_lif(
    const float* __restrict__ partial,
    const float* __restrict__ bn_s, const float* __restrict__ bn_b,
    const float* __restrict__ thr, const float* __restrict__ beta_raw,
    __hip_bfloat16* __restrict__ avg, int H, int W, int total)
{
    int idx = blockIdx.x * 256 + threadIdx.x;
    if (idx >= total) return;
    int HW = H * W;
    int co = (idx / HW) % 36;
    float hh = 0.f;
    #pragma unroll
    for (int s = 0; s < SPLITS; ++s) hh += partial[(long)s * total + idx];
    hh = hh * bn_s[co] + bn_b[co];
    float beta = 1.f / (1.f + expf(-beta_raw[co]));
    float t    = thr[co];
    float m = 0.f, cnt = 0.f;
    #pragma unroll
    for (int s = 0; s < 4; ++s) {
        m = beta * m + hh;
        if (m > t) { cnt += 1.f; m -= t; }
    }
    if (CL) {
        int b = idx / (36 * HW);
        int rem = idx % HW;
        int y = rem / W, x = rem % W;
        avg[((long)(b * H + y) * W + x) * 40 + co] = __float2bfloat16(cnt * 0.25f);
    } else {
        avg[idx] = __float2bfloat16(cnt * 0.25f);
    }
}

// ===========================================================================
// Weight prepack for MFMA decoder.
// ===========================================================================
__global__ __launch_bounds__(256) void pack_w(
    const float* __restrict__ w, __hip_bfloat16* __restrict__ ap, int total)
{
    int idx = blockIdx.x * 256 + threadIdx.x;
    if (idx >= total) return;
    int m  = idx & 31;
    int h  = (idx >> 5) & 1;
    int s  = (idx >> 6) % 23;
    int cg = idx / (23 * 64);
    int o  = 2 * s + h;
    int co = cg * 32 + m;
    unsigned short v[8];
    #pragma unroll
    for (int j = 0; j < 8; ++j) {
        float x = 0.f;
        if (o < 45) {
            int tap = o / 5, oct = o % 5, ci = oct * 8 + j;
            if (ci < 36) x = w[(long)co * 324 + ci * 9 + tap];
        }
        __hip_bfloat16 hv = __float2bfloat16(x);
        v[j] = *(unsigned short*)&hv;
    }
    *(int4v*)(ap + (long)idx * 8) = *(int4v*)v;
}

// ===========================================================================
// MFMA decoder: conv3x3(36->Cout) + BN + SiLU.
// ===========================================================================
template<int COG>
__global__ __launch_bounds__(256) void dec_mfma(
    const __hip_bfloat16* __restrict__ avg_cl,   // [B][H][W][40]
    const __hip_bfloat16* __restrict__ apack,
    const float* __restrict__ bn_s, const float* __restrict__ bn_b,
    float* __restrict__ out, int Cout, int H, int W, int tiles_x)
{
    __shared__ __hip_bfloat16 tile[12960];       // [18][18][40] = 25920 B

    const int tid    = threadIdx.x;
    const int b      = blockIdx.y;
    const int cgbase = blockIdx.z * COG;
    const int tx0 = (blockIdx.x % tiles_x) * 16;
    const int ty0 = (blockIdx.x / tiles_x) * 16;

    {
        const __hip_bfloat16* ab = avg_cl + (long)b * H * W * 40;
        for (int i = tid; i < 1620; i += 256) {
            int row = i / 90, u = i - row * 90;
            int px = u / 5, un = u - px * 5;
            int gy = ty0 + row - 1, gx = tx0 + px - 1;
            int4v v = {0, 0, 0, 0};
            if (gy >= 0 && gy < H && gx >= 0 && gx < W)
                v = *(const int4v*)(ab + ((long)gy * W + gx) * 40 + un * 8);
            *(int4v*)(tile + (row * 18 + px) * 40 + un * 8) = v;
        }
    }
    __syncthreads();

    const int lane = tid & 63;
    const int wv   = tid >> 6;
    const int h    = lane >> 5;
    const int n    = lane & 31;
    const int lx   = n & 15;
    const int ly0  = wv * 4 + (n >> 4);

    const char* tb  = (const char*)tile;
    const int   bb0 = ((ly0 + 1) * 18 + (lx + 1)) * 80;
    const int   bb1 = bb0 + 2 * 18 * 80;

    const char* ap = (const char*)apack + (long)cgbase * 23552 + h * 512 + n * 16;

    f32x16 acc[COG][2];
    #pragma unroll
    for (int cg = 0; cg < COG; ++cg)
        #pragma unroll
        for (int pf = 0; pf < 2; ++pf)
            #pragma unroll
            for (int k = 0; k < 16; ++k) acc[cg][pf][k] = 0.f;

    #pragma unroll
    for (int s = 0; s < 23; ++s) {
        int o0 = 2 * s;     if (o0 > 44) o0 = 44;
        int o1 = 2 * s + 1; if (o1 > 44) o1 = 44;
        const int C0 = ((o0 / 5) / 3 - 1) * 1440 + ((o0 / 5) % 3 - 1) * 80 + (o0 % 5) * 16;
        const int C1 = ((o1 / 5) / 3 - 1) * 1440 + ((o1 / 5) % 3 - 1) * 80 + (o1 % 5) * 16;
        const int offc = h ? C1 : C0;
        short8v bf0 = *(const short8v*)(tb + (bb0 + offc));
        short8v bf1 = *(const short8v*)(tb + (bb1 + offc));
        #pragma unroll
        for (int cg = 0; cg < COG; ++cg) {
            short8v af = *(const short8v*)(ap + cg * 23552 + s * 1024);
            acc[cg][0] = __builtin_amdgcn_mfma_f32_32x32x16_bf16(af, bf0, acc[cg][0], 0, 0, 0);
            acc[cg][1] = __builtin_amdgcn_mfma_f32_32x32x16_bf16(af, bf1, acc[cg][1], 0, 0, 0);
        }
    }

    #pragma unroll
    for (int cg = 0; cg < COG; ++cg) {
        #pragma unroll
        for (int r = 0; r < 16; ++r) {
            const int co = ((cgbase + cg) << 5) + (r & 3) + ((r >> 2) << 3) + (h << 2);
            const float sc = bn_s[co], bc = bn_b[co];
            #pragma unroll
            for (int pf = 0; pf < 2; ++pf) {
                const int ly = ly0 + pf * 2;
                const int gy = ty0 + ly, gx = tx0 + lx;
                float v = acc[cg][pf][r] * sc + bc;
                v = v / (1.f + __expf(-v));
                if (gy < H && gx < W)
                    out[(((long)b * Cout + co) * H + gy) * W + gx] = v;
            }
        }
    }
}

// ===========================================================================
// Fallback decoder (VALU, NCHW avg).
// ===========================================================================
template<int COCHUNK, int TDIM>
__global__ __launch_bounds__(TDIM* TDIM) void dec_tiled(
    const __hip_bfloat16* __restrict__ avg,
    const float* __restrict__ w,
    const float* __restrict__ bn_s, const float* __restrict__ bn_b,
    float* __restrict__ out,
    int Cout, int H, int W, int tiles_x)
{
    const int CIN = 36;
    const int TPB = TDIM * TDIM;
    const int HALOD = TDIM + 2;
    __shared__ float fs[CIN][HALOD][HALOD];

    const int tile = blockIdx.x;
    const int b    = blockIdx.y;
    const int co0  = blockIdx.z * COCHUNK;
    const int tx0  = (tile % tiles_x) * TDIM;
    const int ty0  = (tile / tiles_x) * TDIM;

    const int tx = threadIdx.x % TDIM;
    const int ty = threadIdx.x / TDIM;
    const int ox = tx0 + tx, oy = ty0 + ty;

    const __hip_bfloat16* ab = avg + (long)b * CIN * H * W;

    for (int i = threadIdx.x; i < CIN * HALOD * HALOD; i += TPB) {
        int ci = i / (HALOD * HALOD);
        int r  = i % (HALOD * HALOD);
        int hy = r / HALOD, hx = r % HALOD;
        int gy = ty0 + hy - 1, gx = tx0 + hx - 1;
        float v = 0.f;
        if (gy >= 0 && gy < H && gx >= 0 && gx < W)
            v = __bfloat162float(ab[((long)ci * H + gy) * W + gx]);
        fs[ci][hy][hx] = v;
    }
    __syncthreads();

    float acc[COCHUNK];
    #pragma unroll
    for (int j = 0; j < COCHUNK; ++j) acc[j] = 0.f;

    for (int ci = 0; ci < CIN; ++ci) {
        float f0 = fs[ci][ty    ][tx], f1 = fs[ci][ty    ][tx+1], f2 = fs[ci][ty    ][tx+2];
        float f3 = fs[ci][ty + 1][tx], f4 = fs[ci][ty + 1][tx+1], f5 = fs[ci][ty + 1][tx+2];
        float f6 = fs[ci][ty + 2][tx], f7 = fs[ci][ty + 2][tx+1], f8 = fs[ci][ty + 2][tx+2];
        #pragma unroll
        for (int j = 0; j < COCHUNK; ++j) {
            const float* ww = w + ((long)(co0 + j) * CIN + ci) * 9;
            acc[j] += f0 * ww[0] + f1 * ww[1] + f2 * ww[2]
                    + f3 * ww[3] + f4 * ww[4] + f5 * ww[5]
                    + f6 * ww[6] + f7 * ww[7] + f8 * ww[8];
        }
    }

    if (ox < W && oy < H) {
        #pragma unroll
        for (int j = 0; j < COCHUNK; ++j) {
            int co = co0 + j;
            float v = acc[j] * bn_s[co] + bn_b[co];
            out[(((long)b * Cout + co) * H + oy) * W + ox] = v / (1.f + expf(-v));
        }
    }
}

// ===========================================================================
extern "C" void kernel_launch(void* const* d_in, const int* in_sizes, int n_in,
                              void* d_out, int out_size, void* d_ws, size_t ws_size,
                              hipStream_t stream)
{
    const int B = 16;
    const int C[3] = {64, 128, 256};
    const int S[3] = {160, 80, 40};

    float* out = (float*)d_out;
    long out_off[3]; long off = 0;
    for (int l = 0; l < 3; ++l) { out_off[l] = off; off += (long)B * C[l] * S[l] * S[l]; }

    // ---- new-path workspace layout (bytes) ----
    const long avgcl_bytes[3] = {32768000L, 8192000L, 2048000L};   // B*H*W*40*2
    long avgcl_off[3]; long boff = 0;
    for (int l = 0; l < 3; ++l) { avgcl_off[l] = boff; boff += avgcl_bytes[l]; }
    const long avgcl_total = boff;
    const long ap_bytes[3] = {47104L, 94208L, 188416L};             // (C/32)*23552
    long ap_off[3];
    for (int l = 0; l < 3; ++l) { ap_off[l] = boff; boff += ap_bytes[l]; }
    // enc MFMA weight packs (hi+lo), per level: CIN*1152 bytes each
    const long we_bytes[3] = {73728L, 147456L, 294912L};
    long wehi_off[3], welo_off[3];
    for (int l = 0; l < 3; ++l) { wehi_off[l] = boff; boff += we_bytes[l];
                                  welo_off[l] = boff; boff += we_bytes[l]; }
    const long part5_off = boff;
    const long part5_bytes = 4L * B * 36 * 1600 * 4;
    const size_t need_full = (size_t)(part5_off + part5_bytes);
    const size_t need_min  = (size_t)part5_off;

    char* wsb = (char*)d_ws;

    if (ws_size >= need_min) {
        // ================= NEW PATH =================
        const bool split5 = ws_size >= need_full;
        hipMemsetAsync(wsb, 0, avgcl_total, stream);   // zero avg_cl incl. ci-pad

        for (int l = 0; l < 3; ++l) {
            const float* dec_w = (const float*)d_in[9 * l + 6];
            int total = (C[l] / 32) * 23 * 2 * 32;
            pack_w<<<(total + 255) / 256, 256, 0, stream>>>(
                dec_w, (__hip_bfloat16*)(wsb + ap_off[l]), total);
        }
        {   // enc3 MFMA weight pack: cg2 x chunk4 x 9 x h2 x m32
            const float* enc_w3 = (const float*)d_in[1];
            int total = 2 * (64 / 16) * 9 * 2 * 32;   // 4608
            pack_we<64><<<(total + 255) / 256, 256, 0, stream>>>(
                enc_w3, (__hip_bfloat16*)(wsb + wehi_off[0]),
                (__hip_bfloat16*)(wsb + welo_off[0]), total);
        }

        for (int l = 0; l < 3; ++l) {
            const int base = 9 * l;
            const float* feat     = (const float*)d_in[base + 0];
            const float* enc_w    = (const float*)d_in[base + 1];
            const float* enc_bn_s = (const float*)d_in[base + 2];
            const float* enc_bn_b = (const float*)d_in[base + 3];
            const float* enc_thr  = (const float*)d_in[base + 4];
            const float* enc_beta = (const float*)d_in[base + 5];
            const float* dec_bn_s = (const float*)d_in[base + 7];
            const float* dec_bn_b = (const float*)d_in[base + 8];

            const int Hs = S[l], Wsz = S[l];
            __hip_bfloat16* avg_cl = (__hip_bfloat16*)(wsb + avgcl_off[l]);
            const __hip_bfloat16* ap = (const __hip_bfloat16*)(wsb + ap_off[l]);
            float* r = out + out_off[l];

            if (l == 0) {
                // 160x160: MFMA encoder (split bf16), 10x10 tiles of 16x16
                dim3 eg(100, B);
                enc_mfma<64><<<eg, 256, 0, stream>>>(
                    feat, (const __hip_bfloat16*)(wsb + wehi_off[0]),
                    (const __hip_bfloat16*)(wsb + welo_off[0]),
                    enc_bn_s, enc_bn_b, enc_thr, enc_beta, avg_cl, Hs, Wsz, 10);
                dim3 dg(100, B, 1);
                dec_mfma<2><<<dg, 256, 0, stream>>>(avg_cl, ap, dec_bn_s, dec_bn_b, r, 64, Hs, Wsz, 10);
            } else if (l == 1) {
                // 80x80: R8-proven VALU config.
                dim3 eg(15, B, 3);
                enc_px<128, 8, 12, 16, 32, 2><<<eg, 256, 0, stream>>>(
                    feat, enc_w, enc_bn_s, enc_bn_b, enc_thr, enc_beta, avg_cl, Hs, Wsz, 5);
                dim3 dg(25, B, 1);
                dec_mfma<4><<<dg, 256, 0, stream>>>(avg_cl, ap, dec_bn_s, dec_bn_b, r, 128, Hs, Wsz, 5);
            } else {
                if (split5) {
                    float* partial5 = (float*)(wsb + part5_off);
                    dim3 eg(25, B, 12);
                    enc_tiled<256, 64, 16, 12, 8, true, true><<<eg, 64, 0, stream>>>(
                        feat, enc_w, enc_bn_s, enc_bn_b, enc_thr, enc_beta, nullptr, partial5, Hs, Wsz, 5);
                    int total = B * 36 * Hs * Wsz;
                    combine_lif<4, true><<<(total + 255) / 256, 256, 0, stream>>>(
                        partial5, enc_bn_s, enc_bn_b, enc_thr, enc_beta, avg_cl, Hs, Wsz, total);
                } else {
                    dim3 eg(25, B, 3);
                    enc_tiled<256, 256, 16, 12, 8, false, true><<<eg, 64, 0, stream>>>(
                        feat, enc_w, enc_bn_s, enc_bn_b, enc_thr, enc_beta, avg_cl, nullptr, Hs, Wsz, 5);
                }
                dim3 dg(9, B, 2);
                dec_mfma<4><<<dg, 256, 0, stream>>>(avg_cl, ap, dec_bn_s, dec_bn_b, r, 256, Hs, Wsz, 3);
            }
        }
    } else {
        // ================= FALLBACK (NCHW, VALU decoder) =================
        __hip_bfloat16* ws = (__hip_bfloat16*)d_ws;
        long avg_off2[3]; long eoff = 0;
        for (int l = 0; l < 3; ++l) { avg_off2[l] = eoff; eoff += (long)B * 36 * S[l] * S[l]; }
        float* partial5 = (float*)(ws + ((eoff + 7) & ~7L));
        const long part5f = 4L * B * 36 * 40 * 40;
        const size_t old_need = (size_t)((eoff + 7) & ~7L) * 2 + part5f * 4;
        const bool split5 = ws_size >= old_need;

        for (int l = 0; l < 3; ++l) {
            const int base = 9 * l;
            const float* feat     = (const float*)d_in[base + 0];
            const float* enc_w    = (const float*)d_in[base + 1];
            const float* enc_bn_s = (const float*)d_in[base + 2];
            const float* enc_bn_b = (const float*)d_in[base + 3];
            const float* enc_thr  = (const float*)d_in[base + 4];
            const float* enc_beta = (const float*)d_in[base + 5];
            const float* dec_w    = (const float*)d_in[base + 6];
            const float* dec_bn_s = (const float*)d_in[base + 7];
            const float* dec_bn_b = (const float*)d_in[base + 8];

            const int Hs = S[l], Wsz = S[l], Cl = C[l];
            __hip_bfloat16* avg = ws + avg_off2[l];
            float* r = out + out_off[l];

            if (l == 0) {
                dim3 eg(100, B, 3);
                enc_tiled<64, 64, 16, 12, 16, false, false><<<eg, 256, 0, stream>>>(
                    feat, enc_w, enc_bn_s, enc_bn_b, enc_thr, enc_beta, avg, nullptr, Hs, Wsz, 10);
                dim3 dg(100, B, 2);
                dec_tiled<32, 16><<<dg, 256, 0, stream>>>(avg, dec_w, dec_bn_s, dec_bn_b, r, Cl, Hs, Wsz, 10);
            } else if (l == 1) {
                dim3 eg(25, B, 3);
                enc_tiled<128, 128, 16, 12, 16, false, false><<<eg, 256, 0, stream>>>(
                    feat, enc_w, enc_bn_s, enc_bn_b, enc_thr, enc_beta, avg, nullptr, Hs, Wsz, 5);
                dim3 dg(25, B, 4);
                dec_tiled<32, 16><<<dg, 256, 0, stream>>>(avg, dec_w, dec_bn_s, dec_bn_b, r, Cl, Hs, Wsz, 5);
            } else {
                if (split5) {
                    dim3 eg(25, B, 12);
                    enc_tiled<256, 64, 16, 12, 8, true, false><<<eg, 64, 0, stream>>>(
                        feat, enc_w, enc_bn_s, enc_bn_b, enc_thr, enc_beta, nullptr, partial5, Hs, Wsz, 5);
                    int total = B * 36 * Hs * Wsz;
                    combine_lif<4, false><<<(total + 255) / 256, 256, 0, stream>>>(
                        partial5, enc_bn_s, enc_bn_b, enc_thr, enc_beta, avg, Hs, Wsz, total);
                } else {
                    dim3 eg(25, B, 3);
                    enc_tiled<256, 256, 16, 12, 8, false, false><<<eg, 64, 0, stream>>>(
                        feat, enc_w, enc_bn_s, enc_bn_b, enc_thr, enc_beta, avg, nullptr, Hs, Wsz, 5);
                }
                dim3 dg(25, B, 16);
                dec_tiled<16, 8><<<dg, 64, 0, stream>>>(avg, dec_w, dec_bn_s, dec_bn_b, r, Cl, Hs, Wsz, 5);
            }
        }
    }
}

// Round 13
// 778.429 us; speedup vs baseline: 1.8605x; 1.1652x over previous
//
#include <hip/hip_runtime.h>
#include <hip/hip_bf16.h>

typedef __attribute__((ext_vector_type(8)))  short short8v;
typedef __attribute__((ext_vector_type(16))) float f32x16;
typedef __attribute__((ext_vector_type(4)))  int   int4v;

// ===========================================================================
// Encoder weight prepack for MFMA (split bf16 hi/lo).
// Layout [cg][c][s(tap)][h(loc)][m(32)][j(8)], 16B per (..m): flat = idx*8.
// ci = c*16 + h*8 + j ; value = W[co][ci][tap], co = cg*32+m (0 if co>=36).
// hi = bf16(v), lo = bf16(v - hi).
// ===========================================================================
template<int CIN>
__global__ __launch_bounds__(256) void pack_we(
    const float* __restrict__ w, __hip_bfloat16* __restrict__ whi,
    __hip_bfloat16* __restrict__ wlo, int total)
{
    const int NCHUNK = CIN / 16;
    int idx = blockIdx.x * 256 + threadIdx.x;
    if (idx >= total) return;
    int m  = idx & 31;
    int h  = (idx >> 5) & 1;
    int s  = (idx >> 6) % 9;
    int c  = (idx / 576) % NCHUNK;
    int cg = idx / (576 * NCHUNK);
    int co = cg * 32 + m;
    unsigned short vh[8], vl[8];
    #pragma unroll
    for (int j = 0; j < 8; ++j) {
        int ci = c * 16 + h * 8 + j;
        float x = (co < 36) ? w[(long)co * CIN * 9 + ci * 9 + s] : 0.f;
        __hip_bfloat16 xh = __float2bfloat16(x);
        float rem = x - __bfloat162float(xh);
        __hip_bfloat16 xl = __float2bfloat16(rem);
        vh[j] = *(unsigned short*)&xh;
        vl[j] = *(unsigned short*)&xl;
    }
    *(int4v*)(whi + (long)idx * 8) = *(int4v*)vh;
    *(int4v*)(wlo + (long)idx * 8) = *(int4v*)vl;
}

// ===========================================================================
// MFMA encoder: conv3x3(CIN->36) + BN + LIF(T=4) + mean, split-bf16.
// 16x16 px tile, 4 waves, 2 co-groups of 32 (co>=36 padded-zero, masked).
// In-situ verified at CIN=64 (R12, absmax 0.047 pass). See R12 header.
// ===========================================================================
template<int CIN>
__global__ __launch_bounds__(256) void enc_mfma(
    const float* __restrict__ feat,          // [16, CIN, H, W]
    const __hip_bfloat16* __restrict__ whi,  // packed hi
    const __hip_bfloat16* __restrict__ wlo,  // packed lo
    const float* __restrict__ bn_s, const float* __restrict__ bn_b,
    const float* __restrict__ thr, const float* __restrict__ beta_raw,
    __hip_bfloat16* __restrict__ avg,        // [16][H][W][40]
    int H, int W, int tiles_x)
{
    const int NCHUNK = CIN / 16;
    __shared__ __align__(16) short hi_t[324 * 24];
    __shared__ __align__(16) short lo_t[324 * 24];

    const int tid = threadIdx.x;
    const int b   = blockIdx.y;
    const int tx0 = (blockIdx.x % tiles_x) * 16;
    const int ty0 = (blockIdx.x / tiles_x) * 16;

    const int lane = tid & 63;
    const int wv   = tid >> 6;
    const int h    = lane >> 5;
    const int n    = lane & 31;
    const int lx   = n & 15;
    const int ly0  = wv * 4 + (n >> 4);

    f32x16 acc[2][2];   // [cg][pf]
    #pragma unroll
    for (int cg = 0; cg < 2; ++cg)
        #pragma unroll
        for (int pf = 0; pf < 2; ++pf)
            #pragma unroll
            for (int k = 0; k < 16; ++k) acc[cg][pf][k] = 0.f;

    const float* fb = feat + (long)b * CIN * H * W;
    const char* aph = (const char*)whi + h * 512 + n * 16;
    const char* apl = (const char*)wlo + h * 512 + n * 16;
    const long  cgstride = (long)NCHUNK * 9216;

    for (int c = 0; c < NCHUNK; ++c) {
        // ---- stage chunk: fp32 -> bf16 hi/lo, coalesced reads along x ----
        for (int i = tid; i < 324 * 16; i += 256) {
            int cil = i / 324;          // 0..15
            int p   = i - cil * 324;    // px in 18x18 halo
            int hy = p / 18, hx = p - hy * 18;
            int gy = ty0 + hy - 1, gx = tx0 + hx - 1;
            float v = 0.f;
            if (gy >= 0 && gy < H && gx >= 0 && gx < W)
                v = fb[((long)(c * 16 + cil) * H + gy) * W + gx];
            __hip_bfloat16 vh = __float2bfloat16(v);
            float rem = v - __bfloat162float(vh);
            __hip_bfloat16 vl = __float2bfloat16(rem);
            hi_t[p * 24 + cil] = *(short*)&vh;
            lo_t[p * 24 + cil] = *(short*)&vl;
        }
        __syncthreads();

        const char* ahc = aph + (long)c * 9216;
        const char* alc = apl + (long)c * 9216;
        #pragma unroll
        for (int s = 0; s < 9; ++s) {
            const int dy = s / 3, dx = s % 3;
            const int p0 = (ly0 + dy) * 18 + (lx + dx);   // pf=0
            const int p1 = p0 + 36;                        // pf=1 (+2 rows)
            short8v bh0 = *(const short8v*)((const char*)hi_t + p0 * 48 + h * 16);
            short8v bh1 = *(const short8v*)((const char*)hi_t + p1 * 48 + h * 16);
            short8v bl0 = *(const short8v*)((const char*)lo_t + p0 * 48 + h * 16);
            short8v bl1 = *(const short8v*)((const char*)lo_t + p1 * 48 + h * 16);
            #pragma unroll
            for (int cg = 0; cg < 2; ++cg) {
                short8v af = *(const short8v*)(ahc + cg * cgstride + s * 1024);
                short8v al = *(const short8v*)(alc + cg * cgstride + s * 1024);
                acc[cg][0] = __builtin_amdgcn_mfma_f32_32x32x16_bf16(af, bh0, acc[cg][0], 0, 0, 0);
                acc[cg][0] = __builtin_amdgcn_mfma_f32_32x32x16_bf16(af, bl0, acc[cg][0], 0, 0, 0);
                acc[cg][0] = __builtin_amdgcn_mfma_f32_32x32x16_bf16(al, bh0, acc[cg][0], 0, 0, 0);
                acc[cg][1] = __builtin_amdgcn_mfma_f32_32x32x16_bf16(af, bh1, acc[cg][1], 0, 0, 0);
                acc[cg][1] = __builtin_amdgcn_mfma_f32_32x32x16_bf16(af, bl1, acc[cg][1], 0, 0, 0);
                acc[cg][1] = __builtin_amdgcn_mfma_f32_32x32x16_bf16(al, bh1, acc[cg][1], 0, 0, 0);
            }
        }
        __syncthreads();
    }

    // ---- epilogue: BN + LIF + mean, masked store (co<36, px in range) ----
    #pragma unroll
    for (int cg = 0; cg < 2; ++cg) {
        #pragma unroll
        for (int r = 0; r < 16; ++r) {
            const int co = (cg << 5) + (r & 3) + ((r >> 2) << 3) + (h << 2);
            if (co < 36) {
                const float sc   = bn_s[co], sb = bn_b[co];
                const float beta = 1.f / (1.f + expf(-beta_raw[co]));
                const float t    = thr[co];
                #pragma unroll
                for (int pf = 0; pf < 2; ++pf) {
                    const int gy = ty0 + ly0 + pf * 2, gx = tx0 + lx;
                    float hv = acc[cg][pf][r] * sc + sb;
                    float m = 0.f, c2 = 0.f;
                    #pragma unroll
                    for (int s4 = 0; s4 < 4; ++s4) {
                        m = beta * m + hv;
                        if (m > t) { c2 += 1.f; m -= t; }
                    }
                    if (gy < H && gx < W)
                        avg[((long)(b * H + gy) * W + gx) * 40 + co] =
                            __float2bfloat16(c2 * 0.25f);
                }
            }
        }
    }
}

// ===========================================================================
// Original encoder (enc5 ci-split + fallback path).
// ===========================================================================
template<int CIN, int CIPER, int CICHUNK, int COCHUNK, int TDIM, bool PARTIAL, bool CL>
__global__ __launch_bounds__(TDIM* TDIM) void enc_tiled(
    const float* __restrict__ feat,
    const float* __restrict__ w,
    const float* __restrict__ bn_s, const float* __restrict__ bn_b,
    const float* __restrict__ thr, const float* __restrict__ beta_raw,
    __hip_bfloat16* __restrict__ avg,
    float* __restrict__ partial,
    int H, int W, int tiles_x)
{
    const int TPB  = TDIM * TDIM;
    const int HALOD = TDIM + 2;
    const int NCO  = 36 / COCHUNK;
    __shared__ float fs[CICHUNK][HALOD][HALOD];

    const int tile = blockIdx.x;
    const int b    = blockIdx.y;
    const int coc  = blockIdx.z % NCO;
    const int cis  = blockIdx.z / NCO;
    const int co0  = coc * COCHUNK;
    const int tx0  = (tile % tiles_x) * TDIM;
    const int ty0  = (tile / tiles_x) * TDIM;

    const int tx = threadIdx.x % TDIM;
    const int ty = threadIdx.x / TDIM;
    const int ox = tx0 + tx, oy = ty0 + ty;

    float acc[COCHUNK];
    #pragma unroll
    for (int c = 0; c < COCHUNK; ++c) acc[c] = 0.f;

    const float* fb = feat + (long)b * CIN * H * W;
    const int ci_base = cis * CIPER;

    for (int cc = ci_base; cc < ci_base + CIPER; cc += CICHUNK) {
        for (int i = threadIdx.x; i < CICHUNK * HALOD * HALOD; i += TPB) {
            int ci = i / (HALOD * HALOD);
            int r  = i % (HALOD * HALOD);
            int hy = r / HALOD, hx = r % HALOD;
            int gy = ty0 + hy - 1, gx = tx0 + hx - 1;
            float v = 0.f;
            if (gy >= 0 && gy < H && gx >= 0 && gx < W)
                v = fb[((long)(cc + ci) * H + gy) * W + gx];
            fs[ci][hy][hx] = v;
        }
        __syncthreads();

        for (int ci = 0; ci < CICHUNK; ++ci) {
            float f0 = fs[ci][ty    ][tx], f1 = fs[ci][ty    ][tx+1], f2 = fs[ci][ty    ][tx+2];
            float f3 = fs[ci][ty + 1][tx], f4 = fs[ci][ty + 1][tx+1], f5 = fs[ci][ty + 1][tx+2];
            float f6 = fs[ci][ty + 2][tx], f7 = fs[ci][ty + 2][tx+1], f8 = fs[ci][ty + 2][tx+2];
            const float* wq = w + (long)(cc + ci) * 9;
            #pragma unroll
            for (int j = 0; j < COCHUNK; ++j) {
                const float* ww = wq + (long)(co0 + j) * CIN * 9;
                acc[j] += f0 * ww[0] + f1 * ww[1] + f2 * ww[2]
                        + f3 * ww[3] + f4 * ww[4] + f5 * ww[5]
                        + f6 * ww[6] + f7 * ww[7] + f8 * ww[8];
            }
        }
        __syncthreads();
    }

    if (ox < W && oy < H) {
        if (PARTIAL) {
            #pragma unroll
            for (int j = 0; j < COCHUNK; ++j)
                partial[((((long)cis * 16 + b) * 36 + (co0 + j)) * H + oy) * W + ox] = acc[j];
        } else {
            float cnt[COCHUNK];
            #pragma unroll
            for (int j = 0; j < COCHUNK; ++j) {
                int co = co0 + j;
                float hh   = acc[j] * bn_s[co] + bn_b[co];
                float beta = 1.f / (1.f + expf(-beta_raw[co]));
                float t    = thr[co];
                float m = 0.f, c2 = 0.f;
                #pragma unroll
                for (int s = 0; s < 4; ++s) {
                    m = beta * m + hh;
                    if (m > t) { c2 += 1.f; m -= t; }
                }
                cnt[j] = c2 * 0.25f;
            }
            if (CL) {
                unsigned* dp = (unsigned*)(avg + ((long)(b * H + oy) * W + ox) * 40 + co0);
                #pragma unroll
                for (int j2 = 0; j2 < COCHUNK / 2; ++j2) {
                    __hip_bfloat16 h0 = __float2bfloat16(cnt[2 * j2]);
                    __hip_bfloat16 h1 = __float2bfloat16(cnt[2 * j2 + 1]);
                    unsigned u0 = *(unsigned short*)&h0;
                    unsigned u1 = *(unsigned short*)&h1;
                    dp[j2] = u0 | (u1 << 16);
                }
            } else {
                #pragma unroll
                for (int j = 0; j < COCHUNK; ++j)
                    avg[(((long)b * 36 + (co0 + j)) * H + oy) * W + ox] = __float2bfloat16(cnt[j]);
            }
        }
    }
}

// ===========================================================================
// Combine ci-split partials + BN + LIF + mean -> bf16 avg (CL or NCHW).
// ===========================================================================
template<int SPLITS, bool CL>
__global__ __launch_bounds__(256) void combine_lif(
    const float* __restrict__ partial,
    const float* __restrict__ bn_s, const float* __restrict__ bn_b,
    const float* __restrict__ thr, const float* __restrict__ beta_raw,
    __hip_bfloat16* __restrict__ avg, int H, int W, int total)
{
    int idx = blockIdx.x * 256 + threadIdx.x;
    if (idx >= total) return;
    int HW = H * W;
    int co = (idx / HW) % 36;
    float hh = 0.f;
    #pragma unroll
    for (int s = 0; s < SPLITS; ++s) hh += partial[(long)s * total + idx];
    hh = hh * bn_s[co] + bn_b[co];
    float beta = 1.f / (1.f + expf(-beta_raw[co]));
    float t    = thr[co];
    float m = 0.f, cnt = 0.f;
    #pragma unroll
    for (int s = 0; s < 4; ++s) {
        m = beta * m + hh;
        if (m > t) { cnt += 1.f; m -= t; }
    }
    if (CL) {
        int b = idx / (36 * HW);
        int rem = idx % HW;
        int y = rem / W, x = rem % W;
        avg[((long)(b * H + y) * W + x) * 40 + co] = __float2bfloat16(cnt * 0.25f);
    } else {
        avg[idx] = __float2bfloat16(cnt * 0.25f);
    }
}

// ===========================================================================
// Weight prepack for MFMA decoder.
// ===========================================================================
__global__ __launch_bounds__(256) void pack_w(
    const float* __restrict__ w, __hip_bfloat16* __restrict__ ap, int total)
{
    int idx = blockIdx.x * 256 + threadIdx.x;
    if (idx >= total) return;
    int m  = idx & 31;
    int h  = (idx >> 5) & 1;
    int s  = (idx >> 6) % 23;
    int cg = idx / (23 * 64);
    int o  = 2 * s + h;
    int co = cg * 32 + m;
    unsigned short v[8];
    #pragma unroll
    for (int j = 0; j < 8; ++j) {
        float x = 0.f;
        if (o < 45) {
            int tap = o / 5, oct = o % 5, ci = oct * 8 + j;
            if (ci < 36) x = w[(long)co * 324 + ci * 9 + tap];
        }
        __hip_bfloat16 hv = __float2bfloat16(x);
        v[j] = *(unsigned short*)&hv;
    }
    *(int4v*)(ap + (long)idx * 8) = *(int4v*)v;
}

// ===========================================================================
// MFMA decoder: conv3x3(36->Cout) + BN + SiLU.
// ===========================================================================
template<int COG>
__global__ __launch_bounds__(256) void dec_mfma(
    const __hip_bfloat16* __restrict__ avg_cl,   // [B][H][W][40]
    const __hip_bfloat16* __restrict__ apack,
    const float* __restrict__ bn_s, const float* __restrict__ bn_b,
    float* __restrict__ out, int Cout, int H, int W, int tiles_x)
{
    __shared__ __hip_bfloat16 tile[12960];       // [18][18][40] = 25920 B

    const int tid    = threadIdx.x;
    const int b      = blockIdx.y;
    const int cgbase = blockIdx.z * COG;
    const int tx0 = (blockIdx.x % tiles_x) * 16;
    const int ty0 = (blockIdx.x / tiles_x) * 16;

    {
        const __hip_bfloat16* ab = avg_cl + (long)b * H * W * 40;
        for (int i = tid; i < 1620; i += 256) {
            int row = i / 90, u = i - row * 90;
            int px = u / 5, un = u - px * 5;
            int gy = ty0 + row - 1, gx = tx0 + px - 1;
            int4v v = {0, 0, 0, 0};
            if (gy >= 0 && gy < H && gx >= 0 && gx < W)
                v = *(const int4v*)(ab + ((long)gy * W + gx) * 40 + un * 8);
            *(int4v*)(tile + (row * 18 + px) * 40 + un * 8) = v;
        }
    }
    __syncthreads();

    const int lane = tid & 63;
    const int wv   = tid >> 6;
    const int h    = lane >> 5;
    const int n    = lane & 31;
    const int lx   = n & 15;
    const int ly0  = wv * 4 + (n >> 4);

    const char* tb  = (const char*)tile;
    const int   bb0 = ((ly0 + 1) * 18 + (lx + 1)) * 80;
    const int   bb1 = bb0 + 2 * 18 * 80;

    const char* ap = (const char*)apack + (long)cgbase * 23552 + h * 512 + n * 16;

    f32x16 acc[COG][2];
    #pragma unroll
    for (int cg = 0; cg < COG; ++cg)
        #pragma unroll
        for (int pf = 0; pf < 2; ++pf)
            #pragma unroll
            for (int k = 0; k < 16; ++k) acc[cg][pf][k] = 0.f;

    #pragma unroll
    for (int s = 0; s < 23; ++s) {
        int o0 = 2 * s;     if (o0 > 44) o0 = 44;
        int o1 = 2 * s + 1; if (o1 > 44) o1 = 44;
        const int C0 = ((o0 / 5) / 3 - 1) * 1440 + ((o0 / 5) % 3 - 1) * 80 + (o0 % 5) * 16;
        const int C1 = ((o1 / 5) / 3 - 1) * 1440 + ((o1 / 5) % 3 - 1) * 80 + (o1 % 5) * 16;
        const int offc = h ? C1 : C0;
        short8v bf0 = *(const short8v*)(tb + (bb0 + offc));
        short8v bf1 = *(const short8v*)(tb + (bb1 + offc));
        #pragma unroll
        for (int cg = 0; cg < COG; ++cg) {
            short8v af = *(const short8v*)(ap + cg * 23552 + s * 1024);
            acc[cg][0] = __builtin_amdgcn_mfma_f32_32x32x16_bf16(af, bf0, acc[cg][0], 0, 0, 0);
            acc[cg][1] = __builtin_amdgcn_mfma_f32_32x32x16_bf16(af, bf1, acc[cg][1], 0, 0, 0);
        }
    }

    #pragma unroll
    for (int cg = 0; cg < COG; ++cg) {
        #pragma unroll
        for (int r = 0; r < 16; ++r) {
            const int co = ((cgbase + cg) << 5) + (r & 3) + ((r >> 2) << 3) + (h << 2);
            const float sc = bn_s[co], bc = bn_b[co];
            #pragma unroll
            for (int pf = 0; pf < 2; ++pf) {
                const int ly = ly0 + pf * 2;
                const int gy = ty0 + ly, gx = tx0 + lx;
                float v = acc[cg][pf][r] * sc + bc;
                v = v / (1.f + __expf(-v));
                if (gy < H && gx < W)
                    out[(((long)b * Cout + co) * H + gy) * W + gx] = v;
            }
        }
    }
}

// ===========================================================================
// Fallback decoder (VALU, NCHW avg).
// ===========================================================================
template<int COCHUNK, int TDIM>
__global__ __launch_bounds__(TDIM* TDIM) void dec_tiled(
    const __hip_bfloat16* __restrict__ avg,
    const float* __restrict__ w,
    const float* __restrict__ bn_s, const float* __restrict__ bn_b,
    float* __restrict__ out,
    int Cout, int H, int W, int tiles_x)
{
    const int CIN = 36;
    const int TPB = TDIM * TDIM;
    const int HALOD = TDIM + 2;
    __shared__ float fs[CIN][HALOD][HALOD];

    const int tile = blockIdx.x;
    const int b    = blockIdx.y;
    const int co0  = blockIdx.z * COCHUNK;
    const int tx0  = (tile % tiles_x) * TDIM;
    const int ty0  = (tile / tiles_x) * TDIM;

    const int tx = threadIdx.x % TDIM;
    const int ty = threadIdx.x / TDIM;
    const int ox = tx0 + tx, oy = ty0 + ty;

    const __hip_bfloat16* ab = avg + (long)b * CIN * H * W;

    for (int i = threadIdx.x; i < CIN * HALOD * HALOD; i += TPB) {
        int ci = i / (HALOD * HALOD);
        int r  = i % (HALOD * HALOD);
        int hy = r / HALOD, hx = r % HALOD;
        int gy = ty0 + hy - 1, gx = tx0 + hx - 1;
        float v = 0.f;
        if (gy >= 0 && gy < H && gx >= 0 && gx < W)
            v = __bfloat162float(ab[((long)ci * H + gy) * W + gx]);
        fs[ci][hy][hx] = v;
    }
    __syncthreads();

    float acc[COCHUNK];
    #pragma unroll
    for (int j = 0; j < COCHUNK; ++j) acc[j] = 0.f;

    for (int ci = 0; ci < CIN; ++ci) {
        float f0 = fs[ci][ty    ][tx], f1 = fs[ci][ty    ][tx+1], f2 = fs[ci][ty    ][tx+2];
        float f3 = fs[ci][ty + 1][tx], f4 = fs[ci][ty + 1][tx+1], f5 = fs[ci][ty + 1][tx+2];
        float f6 = fs[ci][ty + 2][tx], f7 = fs[ci][ty + 2][tx+1], f8 = fs[ci][ty + 2][tx+2];
        #pragma unroll
        for (int j = 0; j < COCHUNK; ++j) {
            const float* ww = w + ((long)(co0 + j) * CIN + ci) * 9;
            acc[j] += f0 * ww[0] + f1 * ww[1] + f2 * ww[2]
                    + f3 * ww[3] + f4 * ww[4] + f5 * ww[5]
                    + f6 * ww[6] + f7 * ww[7] + f8 * ww[8];
        }
    }

    if (ox < W && oy < H) {
        #pragma unroll
        for (int j = 0; j < COCHUNK; ++j) {
            int co = co0 + j;
            float v = acc[j] * bn_s[co] + bn_b[co];
            out[(((long)b * Cout + co) * H + oy) * W + ox] = v / (1.f + expf(-v));
        }
    }
}

// ===========================================================================
extern "C" void kernel_launch(void* const* d_in, const int* in_sizes, int n_in,
                              void* d_out, int out_size, void* d_ws, size_t ws_size,
                              hipStream_t stream)
{
    const int B = 16;
    const int C[3] = {64, 128, 256};
    const int S[3] = {160, 80, 40};

    float* out = (float*)d_out;
    long out_off[3]; long off = 0;
    for (int l = 0; l < 3; ++l) { out_off[l] = off; off += (long)B * C[l] * S[l] * S[l]; }

    // ---- new-path workspace layout (bytes) ----
    const long avgcl_bytes[3] = {32768000L, 8192000L, 2048000L};   // B*H*W*40*2
    long avgcl_off[3]; long boff = 0;
    for (int l = 0; l < 3; ++l) { avgcl_off[l] = boff; boff += avgcl_bytes[l]; }
    const long avgcl_total = boff;
    const long ap_bytes[3] = {47104L, 94208L, 188416L};             // (C/32)*23552
    long ap_off[3];
    for (int l = 0; l < 3; ++l) { ap_off[l] = boff; boff += ap_bytes[l]; }
    // enc MFMA weight packs (hi+lo), per level: CIN*1152 bytes each
    const long we_bytes[3] = {73728L, 147456L, 294912L};
    long wehi_off[3], welo_off[3];
    for (int l = 0; l < 3; ++l) { wehi_off[l] = boff; boff += we_bytes[l];
                                  welo_off[l] = boff; boff += we_bytes[l]; }
    const long part5_off = boff;
    const long part5_bytes = 4L * B * 36 * 1600 * 4;
    const size_t need_full = (size_t)(part5_off + part5_bytes);
    const size_t need_min  = (size_t)part5_off;

    char* wsb = (char*)d_ws;

    if (ws_size >= need_min) {
        // ================= NEW PATH =================
        const bool split5 = ws_size >= need_full;
        hipMemsetAsync(wsb, 0, avgcl_total, stream);   // zero avg_cl incl. ci-pad

        for (int l = 0; l < 3; ++l) {
            const float* dec_w = (const float*)d_in[9 * l + 6];
            int total = (C[l] / 32) * 23 * 2 * 32;
            pack_w<<<(total + 255) / 256, 256, 0, stream>>>(
                dec_w, (__hip_bfloat16*)(wsb + ap_off[l]), total);
        }
        {   // enc3 MFMA weight pack: cg2 x chunk4 x 9 x h2 x m32
            const float* enc_w3 = (const float*)d_in[1];
            int total = 2 * (64 / 16) * 9 * 2 * 32;   // 4608
            pack_we<64><<<(total + 255) / 256, 256, 0, stream>>>(
                enc_w3, (__hip_bfloat16*)(wsb + wehi_off[0]),
                (__hip_bfloat16*)(wsb + welo_off[0]), total);
        }
        {   // enc4 MFMA weight pack: cg2 x chunk8 x 9 x h2 x m32
            const float* enc_w4 = (const float*)d_in[10];
            int total = 2 * (128 / 16) * 9 * 2 * 32;  // 9216
            pack_we<128><<<(total + 255) / 256, 256, 0, stream>>>(
                enc_w4, (__hip_bfloat16*)(wsb + wehi_off[1]),
                (__hip_bfloat16*)(wsb + welo_off[1]), total);
        }

        for (int l = 0; l < 3; ++l) {
            const int base = 9 * l;
            const float* feat     = (const float*)d_in[base + 0];
            const float* enc_w    = (const float*)d_in[base + 1];
            const float* enc_bn_s = (const float*)d_in[base + 2];
            const float* enc_bn_b = (const float*)d_in[base + 3];
            const float* enc_thr  = (const float*)d_in[base + 4];
            const float* enc_beta = (const float*)d_in[base + 5];
            const float* dec_bn_s = (const float*)d_in[base + 7];
            const float* dec_bn_b = (const float*)d_in[base + 8];

            const int Hs = S[l], Wsz = S[l];
            __hip_bfloat16* avg_cl = (__hip_bfloat16*)(wsb + avgcl_off[l]);
            const __hip_bfloat16* ap = (const __hip_bfloat16*)(wsb + ap_off[l]);
            float* r = out + out_off[l];

            if (l == 0) {
                // 160x160: MFMA encoder (split bf16), 10x10 tiles of 16x16
                dim3 eg(100, B);
                enc_mfma<64><<<eg, 256, 0, stream>>>(
                    feat, (const __hip_bfloat16*)(wsb + wehi_off[0]),
                    (const __hip_bfloat16*)(wsb + welo_off[0]),
                    enc_bn_s, enc_bn_b, enc_thr, enc_beta, avg_cl, Hs, Wsz, 10);
                dim3 dg(100, B, 1);
                dec_mfma<2><<<dg, 256, 0, stream>>>(avg_cl, ap, dec_bn_s, dec_bn_b, r, 64, Hs, Wsz, 10);
            } else if (l == 1) {
                // 80x80: MFMA encoder (split bf16), 5x5 tiles of 16x16
                dim3 eg(25, B);
                enc_mfma<128><<<eg, 256, 0, stream>>>(
                    feat, (const __hip_bfloat16*)(wsb + wehi_off[1]),
                    (const __hip_bfloat16*)(wsb + welo_off[1]),
                    enc_bn_s, enc_bn_b, enc_thr, enc_beta, avg_cl, Hs, Wsz, 5);
                dim3 dg(25, B, 1);
                dec_mfma<4><<<dg, 256, 0, stream>>>(avg_cl, ap, dec_bn_s, dec_bn_b, r, 128, Hs, Wsz, 5);
            } else {
                if (split5) {
                    float* partial5 = (float*)(wsb + part5_off);
                    dim3 eg(25, B, 12);
                    enc_tiled<256, 64, 16, 12, 8, true, true><<<eg, 64, 0, stream>>>(
                        feat, enc_w, enc_bn_s, enc_bn_b, enc_thr, enc_beta, nullptr, partial5, Hs, Wsz, 5);
                    int total = B * 36 * Hs * Wsz;
                    combine_lif<4, true><<<(total + 255) / 256, 256, 0, stream>>>(
                        partial5, enc_bn_s, enc_bn_b, enc_thr, enc_beta, avg_cl, Hs, Wsz, total);
                } else {
                    dim3 eg(25, B, 3);
                    enc_tiled<256, 256, 16, 12, 8, false, true><<<eg, 64, 0, stream>>>(
                        feat, enc_w, enc_bn_s, enc_bn_b, enc_thr, enc_beta, avg_cl, nullptr, Hs, Wsz, 5);
                }
                dim3 dg(9, B, 2);
                dec_mfma<4><<<dg, 256, 0, stream>>>(avg_cl, ap, dec_bn_s, dec_bn_b, r, 256, Hs, Wsz, 3);
            }
        }
    } else {
        // ================= FALLBACK (NCHW, VALU decoder) =================
        __hip_bfloat16* ws = (__hip_bfloat16*)d_ws;
        long avg_off2[3]; long eoff = 0;
        for (int l = 0; l < 3; ++l) { avg_off2[l] = eoff; eoff += (long)B * 36 * S[l] * S[l]; }
        float* partial5 = (float*)(ws + ((eoff + 7) & ~7L));
        const long part5f = 4L * B * 36 * 40 * 40;
        const size_t old_need = (size_t)((eoff + 7) & ~7L) * 2 + part5f * 4;
        const bool split5 = ws_size >= old_need;

        for (int l = 0; l < 3; ++l) {
            const int base = 9 * l;
            const float* feat     = (const float*)d_in[base + 0];
            const float* enc_w    = (const float*)d_in[base + 1];
            const float* enc_bn_s = (const float*)d_in[base + 2];
            const float* enc_bn_b = (const float*)d_in[base + 3];
            const float* enc_thr  = (const float*)d_in[base + 4];
            const float* enc_beta = (const float*)d_in[base + 5];
            const float* dec_w    = (const float*)d_in[base + 6];
            const float* dec_bn_s = (const float*)d_in[base + 7];
            const float* dec_bn_b = (const float*)d_in[base + 8];

            const int Hs = S[l], Wsz = S[l], Cl = C[l];
            __hip_bfloat16* avg = ws + avg_off2[l];
            float* r = out + out_off[l];

            if (l == 0) {
                dim3 eg(100, B, 3);
                enc_tiled<64, 64, 16, 12, 16, false, false><<<eg, 256, 0, stream>>>(
                    feat, enc_w, enc_bn_s, enc_bn_b, enc_thr, enc_beta, avg, nullptr, Hs, Wsz, 10);
                dim3 dg(100, B, 2);
                dec_tiled<32, 16><<<dg, 256, 0, stream>>>(avg, dec_w, dec_bn_s, dec_bn_b, r, Cl, Hs, Wsz, 10);
            } else if (l == 1) {
                dim3 eg(25, B, 3);
                enc_tiled<128, 128, 16, 12, 16, false, false><<<eg, 256, 0, stream>>>(
                    feat, enc_w, enc_bn_s, enc_bn_b, enc_thr, enc_beta, avg, nullptr, Hs, Wsz, 5);
                dim3 dg(25, B, 4);
                dec_tiled<32, 16><<<dg, 256, 0, stream>>>(avg, dec_w, dec_bn_s, dec_bn_b, r, Cl, Hs, Wsz, 5);
            } else {
                if (split5) {
                    dim3 eg(25, B, 12);
                    enc_tiled<256, 64, 16, 12, 8, true, false><<<eg, 64, 0, stream>>>(
                        feat, enc_w, enc_bn_s, enc_bn_b, enc_thr, enc_beta, nullptr, partial5, Hs, Wsz, 5);
                    int total = B * 36 * Hs * Wsz;
                    combine_lif<4, false><<<(total + 255) / 256, 256, 0, stream>>>(
                        partial5, enc_bn_s, enc_bn_b, enc_thr, enc_beta, avg, Hs, Wsz, total);
                } else {
                    dim3 eg(25, B, 3);
                    enc_tiled<256, 256, 16, 12, 8, false, false><<<eg, 64, 0, stream>>>(
                        feat, enc_w, enc_bn_s, enc_bn_b, enc_thr, enc_beta, avg, nullptr, Hs, Wsz, 5);
                }
                dim3 dg(25, B, 16);
                dec_tiled<16, 8><<<dg, 64, 0, stream>>>(avg, dec_w, dec_bn_s, dec_bn_b, r, Cl, Hs, Wsz, 5);
            }
        }
    }
}

// Round 14
// 759.595 us; speedup vs baseline: 1.9066x; 1.0248x over previous
//
#include <hip/hip_runtime.h>
#include <hip/hip_bf16.h>

typedef __attribute__((ext_vector_type(8)))  short short8v;
typedef __attribute__((ext_vector_type(16))) float f32x16;
typedef __attribute__((ext_vector_type(4)))  int   int4v;

// ===========================================================================
// Encoder weight prepack for MFMA (split bf16 hi/lo).
// ===========================================================================
template<int CIN>
__global__ __launch_bounds__(256) void pack_we(
    const float* __restrict__ w, __hip_bfloat16* __restrict__ whi,
    __hip_bfloat16* __restrict__ wlo, int total)
{
    const int NCHUNK = CIN / 16;
    int idx = blockIdx.x * 256 + threadIdx.x;
    if (idx >= total) return;
    int m  = idx & 31;
    int h  = (idx >> 5) & 1;
    int s  = (idx >> 6) % 9;
    int c  = (idx / 576) % NCHUNK;
    int cg = idx / (576 * NCHUNK);
    int co = cg * 32 + m;
    unsigned short vh[8], vl[8];
    #pragma unroll
    for (int j = 0; j < 8; ++j) {
        int ci = c * 16 + h * 8 + j;
        float x = (co < 36) ? w[(long)co * CIN * 9 + ci * 9 + s] : 0.f;
        __hip_bfloat16 xh = __float2bfloat16(x);
        float rem = x - __bfloat162float(xh);
        __hip_bfloat16 xl = __float2bfloat16(rem);
        vh[j] = *(unsigned short*)&xh;
        vl[j] = *(unsigned short*)&xl;
    }
    *(int4v*)(whi + (long)idx * 8) = *(int4v*)vh;
    *(int4v*)(wlo + (long)idx * 8) = *(int4v*)vl;
}

// ===========================================================================
// feat_cl: fp32 NCHW -> channel-last bf16 hi/lo [p][CIN]  (p = b*HW + y*W + x)
// LDS-transposed: coalesced fp32 reads, 16B packed writes.
// ===========================================================================
template<int CIN>
__global__ __launch_bounds__(256) void feat_cl(
    const float* __restrict__ f, __hip_bfloat16* __restrict__ fh,
    __hip_bfloat16* __restrict__ fl, int HW, int npx)
{
    __shared__ float t[CIN][64];
    const int p0 = blockIdx.x * 64;

    for (int i = threadIdx.x; i < CIN * 64; i += 256) {
        int ci = i >> 6, px = i & 63;
        int p = p0 + px;
        float v = 0.f;
        if (p < npx) {
            int b = p / HW, r = p - b * HW;
            v = f[((long)b * CIN + ci) * HW + r];
        }
        t[ci][px] = v;
    }
    __syncthreads();

    for (int i = threadIdx.x; i < 64 * (CIN / 8); i += 256) {
        int px = i & 63, oct = i >> 6;
        int p = p0 + px;
        if (p >= npx) continue;
        unsigned short vh[8], vl[8];
        #pragma unroll
        for (int j = 0; j < 8; ++j) {
            float v = t[oct * 8 + j][px];
            __hip_bfloat16 xh = __float2bfloat16(v);
            float rem = v - __bfloat162float(xh);
            __hip_bfloat16 xl = __float2bfloat16(rem);
            vh[j] = *(unsigned short*)&xh;
            vl[j] = *(unsigned short*)&xl;
        }
        *(int4v*)(fh + (long)p * CIN + oct * 8) = *(int4v*)vh;
        *(int4v*)(fl + (long)p * CIN + oct * 8) = *(int4v*)vl;
    }
}

// ===========================================================================
// MFMA encoder, CL-staged variant: staging is pure int4v copies from the
// pre-converted hi/lo channel-last feat. MFMA/epilogue identical to enc_mfma
// (in-situ verified R12/R13, absmax 0.047).
// ===========================================================================
template<int CIN>
__global__ __launch_bounds__(256) void enc_mfma_cl(
    const __hip_bfloat16* __restrict__ fh,   // [npx][CIN] hi
    const __hip_bfloat16* __restrict__ fl,   // [npx][CIN] lo
    const __hip_bfloat16* __restrict__ whi,
    const __hip_bfloat16* __restrict__ wlo,
    const float* __restrict__ bn_s, const float* __restrict__ bn_b,
    const float* __restrict__ thr, const float* __restrict__ beta_raw,
    __hip_bfloat16* __restrict__ avg,        // [16][H][W][40]
    int H, int W, int tiles_x)
{
    const int NCHUNK = CIN / 16;
    __shared__ __align__(16) short hi_t[324 * 24];
    __shared__ __align__(16) short lo_t[324 * 24];

    const int tid = threadIdx.x;
    const int b   = blockIdx.y;
    const int tx0 = (blockIdx.x % tiles_x) * 16;
    const int ty0 = (blockIdx.x / tiles_x) * 16;

    const int lane = tid & 63;
    const int wv   = tid >> 6;
    const int h    = lane >> 5;
    const int n    = lane & 31;
    const int lx   = n & 15;
    const int ly0  = wv * 4 + (n >> 4);

    f32x16 acc[2][2];
    #pragma unroll
    for (int cg = 0; cg < 2; ++cg)
        #pragma unroll
        for (int pf = 0; pf < 2; ++pf)
            #pragma unroll
            for (int k = 0; k < 16; ++k) acc[cg][pf][k] = 0.f;

    const char* aph = (const char*)whi + h * 512 + n * 16;
    const char* apl = (const char*)wlo + h * 512 + n * 16;
    const long  cgstride = (long)NCHUNK * 9216;

    for (int c = 0; c < NCHUNK; ++c) {
        // ---- stage: pure vector copies (no conversion VALU) ----
        for (int i = tid; i < 648; i += 256) {
            int p   = i >> 1, oct = i & 1;
            int hy = p / 18, hx = p - hy * 18;
            int gy = ty0 + hy - 1, gx = tx0 + hx - 1;
            int4v vh = {0, 0, 0, 0}, vl = {0, 0, 0, 0};
            if (gy >= 0 && gy < H && gx >= 0 && gx < W) {
                long pp = ((long)(b * H + gy) * W + gx) * CIN + c * 16 + oct * 8;
                vh = *(const int4v*)(fh + pp);
                vl = *(const int4v*)(fl + pp);
            }
            *(int4v*)((char*)hi_t + p * 48 + oct * 16) = vh;
            *(int4v*)((char*)lo_t + p * 48 + oct * 16) = vl;
        }
        __syncthreads();

        const char* ahc = aph + (long)c * 9216;
        const char* alc = apl + (long)c * 9216;
        #pragma unroll
        for (int s = 0; s < 9; ++s) {
            const int dy = s / 3, dx = s % 3;
            const int p0 = (ly0 + dy) * 18 + (lx + dx);
            const int p1 = p0 + 36;
            short8v bh0 = *(const short8v*)((const char*)hi_t + p0 * 48 + h * 16);
            short8v bh1 = *(const short8v*)((const char*)hi_t + p1 * 48 + h * 16);
            short8v bl0 = *(const short8v*)((const char*)lo_t + p0 * 48 + h * 16);
            short8v bl1 = *(const short8v*)((const char*)lo_t + p1 * 48 + h * 16);
            #pragma unroll
            for (int cg = 0; cg < 2; ++cg) {
                short8v af = *(const short8v*)(ahc + cg * cgstride + s * 1024);
                short8v al = *(const short8v*)(alc + cg * cgstride + s * 1024);
                acc[cg][0] = __builtin_amdgcn_mfma_f32_32x32x16_bf16(af, bh0, acc[cg][0], 0, 0, 0);
                acc[cg][0] = __builtin_amdgcn_mfma_f32_32x32x16_bf16(af, bl0, acc[cg][0], 0, 0, 0);
                acc[cg][0] = __builtin_amdgcn_mfma_f32_32x32x16_bf16(al, bh0, acc[cg][0], 0, 0, 0);
                acc[cg][1] = __builtin_amdgcn_mfma_f32_32x32x16_bf16(af, bh1, acc[cg][1], 0, 0, 0);
                acc[cg][1] = __builtin_amdgcn_mfma_f32_32x32x16_bf16(af, bl1, acc[cg][1], 0, 0, 0);
                acc[cg][1] = __builtin_amdgcn_mfma_f32_32x32x16_bf16(al, bh1, acc[cg][1], 0, 0, 0);
            }
        }
        __syncthreads();
    }

    #pragma unroll
    for (int cg = 0; cg < 2; ++cg) {
        #pragma unroll
        for (int r = 0; r < 16; ++r) {
            const int co = (cg << 5) + (r & 3) + ((r >> 2) << 3) + (h << 2);
            if (co < 36) {
                const float sc   = bn_s[co], sb = bn_b[co];
                const float beta = 1.f / (1.f + expf(-beta_raw[co]));
                const float t    = thr[co];
                #pragma unroll
                for (int pf = 0; pf < 2; ++pf) {
                    const int gy = ty0 + ly0 + pf * 2, gx = tx0 + lx;
                    float hv = acc[cg][pf][r] * sc + sb;
                    float m = 0.f, c2 = 0.f;
                    #pragma unroll
                    for (int s4 = 0; s4 < 4; ++s4) {
                        m = beta * m + hv;
                        if (m > t) { c2 += 1.f; m -= t; }
                    }
                    if (gy < H && gx < W)
                        avg[((long)(b * H + gy) * W + gx) * 40 + co] =
                            __float2bfloat16(c2 * 0.25f);
                }
            }
        }
    }
}

// ===========================================================================
// MFMA encoder with in-kernel conversion (R13-exact): fallback when ws small.
// ===========================================================================
template<int CIN>
__global__ __launch_bounds__(256) void enc_mfma(
    const float* __restrict__ feat,
    const __hip_bfloat16* __restrict__ whi,
    const __hip_bfloat16* __restrict__ wlo,
    const float* __restrict__ bn_s, const float* __restrict__ bn_b,
    const float* __restrict__ thr, const float* __restrict__ beta_raw,
    __hip_bfloat16* __restrict__ avg,
    int H, int W, int tiles_x)
{
    const int NCHUNK = CIN / 16;
    __shared__ __align__(16) short hi_t[324 * 24];
    __shared__ __align__(16) short lo_t[324 * 24];

    const int tid = threadIdx.x;
    const int b   = blockIdx.y;
    const int tx0 = (blockIdx.x % tiles_x) * 16;
    const int ty0 = (blockIdx.x / tiles_x) * 16;

    const int lane = tid & 63;
    const int wv   = tid >> 6;
    const int h    = lane >> 5;
    const int n    = lane & 31;
    const int lx   = n & 15;
    const int ly0  = wv * 4 + (n >> 4);

    f32x16 acc[2][2];
    #pragma unroll
    for (int cg = 0; cg < 2; ++cg)
        #pragma unroll
        for (int pf = 0; pf < 2; ++pf)
            #pragma unroll
            for (int k = 0; k < 16; ++k) acc[cg][pf][k] = 0.f;

    const float* fb = feat + (long)b * CIN * H * W;
    const char* aph = (const char*)whi + h * 512 + n * 16;
    const char* apl = (const char*)wlo + h * 512 + n * 16;
    const long  cgstride = (long)NCHUNK * 9216;

    for (int c = 0; c < NCHUNK; ++c) {
        for (int i = tid; i < 324 * 16; i += 256) {
            int cil = i / 324;
            int p   = i - cil * 324;
            int hy = p / 18, hx = p - hy * 18;
            int gy = ty0 + hy - 1, gx = tx0 + hx - 1;
            float v = 0.f;
            if (gy >= 0 && gy < H && gx >= 0 && gx < W)
                v = fb[((long)(c * 16 + cil) * H + gy) * W + gx];
            __hip_bfloat16 vh = __float2bfloat16(v);
            float rem = v - __bfloat162float(vh);
            __hip_bfloat16 vl = __float2bfloat16(rem);
            hi_t[p * 24 + cil] = *(short*)&vh;
            lo_t[p * 24 + cil] = *(short*)&vl;
        }
        __syncthreads();

        const char* ahc = aph + (long)c * 9216;
        const char* alc = apl + (long)c * 9216;
        #pragma unroll
        for (int s = 0; s < 9; ++s) {
            const int dy = s / 3, dx = s % 3;
            const int p0 = (ly0 + dy) * 18 + (lx + dx);
            const int p1 = p0 + 36;
            short8v bh0 = *(const short8v*)((const char*)hi_t + p0 * 48 + h * 16);
            short8v bh1 = *(const short8v*)((const char*)hi_t + p1 * 48 + h * 16);
            short8v bl0 = *(const short8v*)((const char*)lo_t + p0 * 48 + h * 16);
            short8v bl1 = *(const short8v*)((const char*)lo_t + p1 * 48 + h * 16);
            #pragma unroll
            for (int cg = 0; cg < 2; ++cg) {
                short8v af = *(const short8v*)(ahc + cg * cgstride + s * 1024);
                short8v al = *(const short8v*)(alc + cg * cgstride + s * 1024);
                acc[cg][0] = __builtin_amdgcn_mfma_f32_32x32x16_bf16(af, bh0, acc[cg][0], 0, 0, 0);
                acc[cg][0] = __builtin_amdgcn_mfma_f32_32x32x16_bf16(af, bl0, acc[cg][0], 0, 0, 0);
                acc[cg][0] = __builtin_amdgcn_mfma_f32_32x32x16_bf16(al, bh0, acc[cg][0], 0, 0, 0);
                acc[cg][1] = __builtin_amdgcn_mfma_f32_32x32x16_bf16(af, bh1, acc[cg][1], 0, 0, 0);
                acc[cg][1] = __builtin_amdgcn_mfma_f32_32x32x16_bf16(af, bl1, acc[cg][1], 0, 0, 0);
                acc[cg][1] = __builtin_amdgcn_mfma_f32_32x32x16_bf16(al, bh1, acc[cg][1], 0, 0, 0);
            }
        }
        __syncthreads();
    }

    #pragma unroll
    for (int cg = 0; cg < 2; ++cg) {
        #pragma unroll
        for (int r = 0; r < 16; ++r) {
            const int co = (cg << 5) + (r & 3) + ((r >> 2) << 3) + (h << 2);
            if (co < 36) {
                const float sc   = bn_s[co], sb = bn_b[co];
                const float beta = 1.f / (1.f + expf(-beta_raw[co]));
                const float t    = thr[co];
                #pragma unroll
                for (int pf = 0; pf < 2; ++pf) {
                    const int gy = ty0 + ly0 + pf * 2, gx = tx0 + lx;
                    float hv = acc[cg][pf][r] * sc + sb;
                    float m = 0.f, c2 = 0.f;
                    #pragma unroll
                    for (int s4 = 0; s4 < 4; ++s4) {
                        m = beta * m + hv;
                        if (m > t) { c2 += 1.f; m -= t; }
                    }
                    if (gy < H && gx < W)
                        avg[((long)(b * H + gy) * W + gx) * 40 + co] =
                            __float2bfloat16(c2 * 0.25f);
                }
            }
        }
    }
}

// ===========================================================================
// Original encoder (enc5 ci-split + fallback path).
// ===========================================================================
template<int CIN, int CIPER, int CICHUNK, int COCHUNK, int TDIM, bool PARTIAL, bool CL>
__global__ __launch_bounds__(TDIM* TDIM) void enc_tiled(
    const float* __restrict__ feat,
    const float* __restrict__ w,
    const float* __restrict__ bn_s, const float* __restrict__ bn_b,
    const float* __restrict__ thr, const float* __restrict__ beta_raw,
    __hip_bfloat16* __restrict__ avg,
    float* __restrict__ partial,
    int H, int W, int tiles_x)
{
    const int TPB  = TDIM * TDIM;
    const int HALOD = TDIM + 2;
    const int NCO  = 36 / COCHUNK;
    __shared__ float fs[CICHUNK][HALOD][HALOD];

    const int tile = blockIdx.x;
    const int b    = blockIdx.y;
    const int coc  = blockIdx.z % NCO;
    const int cis  = blockIdx.z / NCO;
    const int co0  = coc * COCHUNK;
    const int tx0  = (tile % tiles_x) * TDIM;
    const int ty0  = (tile / tiles_x) * TDIM;

    const int tx = threadIdx.x % TDIM;
    const int ty = threadIdx.x / TDIM;
    const int ox = tx0 + tx, oy = ty0 + ty;

    float acc[COCHUNK];
    #pragma unroll
    for (int c = 0; c < COCHUNK; ++c) acc[c] = 0.f;

    const float* fb = feat + (long)b * CIN * H * W;
    const int ci_base = cis * CIPER;

    for (int cc = ci_base; cc < ci_base + CIPER; cc += CICHUNK) {
        for (int i = threadIdx.x; i < CICHUNK * HALOD * HALOD; i += TPB) {
            int ci = i / (HALOD * HALOD);
            int r  = i % (HALOD * HALOD);
            int hy = r / HALOD, hx = r % HALOD;
            int gy = ty0 + hy - 1, gx = tx0 + hx - 1;
            float v = 0.f;
            if (gy >= 0 && gy < H && gx >= 0 && gx < W)
                v = fb[((long)(cc + ci) * H + gy) * W + gx];
            fs[ci][hy][hx] = v;
        }
        __syncthreads();

        for (int ci = 0; ci < CICHUNK; ++ci) {
            float f0 = fs[ci][ty    ][tx], f1 = fs[ci][ty    ][tx+1], f2 = fs[ci][ty    ][tx+2];
            float f3 = fs[ci][ty + 1][tx], f4 = fs[ci][ty + 1][tx+1], f5 = fs[ci][ty + 1][tx+2];
            float f6 = fs[ci][ty + 2][tx], f7 = fs[ci][ty + 2][tx+1], f8 = fs[ci][ty + 2][tx+2];
            const float* wq = w + (long)(cc + ci) * 9;
            #pragma unroll
            for (int j = 0; j < COCHUNK; ++j) {
                const float* ww = wq + (long)(co0 + j) * CIN * 9;
                acc[j] += f0 * ww[0] + f1 * ww[1] + f2 * ww[2]
                        + f3 * ww[3] + f4 * ww[4] + f5 * ww[5]
                        + f6 * ww[6] + f7 * ww[7] + f8 * ww[8];
            }
        }
        __syncthreads();
    }

    if (ox < W && oy < H) {
        if (PARTIAL) {
            #pragma unroll
            for (int j = 0; j < COCHUNK; ++j)
                partial[((((long)cis * 16 + b) * 36 + (co0 + j)) * H + oy) * W + ox] = acc[j];
        } else {
            float cnt[COCHUNK];
            #pragma unroll
            for (int j = 0; j < COCHUNK; ++j) {
                int co = co0 + j;
                float hh   = acc[j] * bn_s[co] + bn_b[co];
                float beta = 1.f / (1.f + expf(-beta_raw[co]));
                float t    = thr[co];
                float m = 0.f, c2 = 0.f;
                #pragma unroll
                for (int s = 0; s < 4; ++s) {
                    m = beta * m + hh;
                    if (m > t) { c2 += 1.f; m -= t; }
                }
                cnt[j] = c2 * 0.25f;
            }
            if (CL) {
                unsigned* dp = (unsigned*)(avg + ((long)(b * H + oy) * W + ox) * 40 + co0);
                #pragma unroll
                for (int j2 = 0; j2 < COCHUNK / 2; ++j2) {
                    __hip_bfloat16 h0 = __float2bfloat16(cnt[2 * j2]);
                    __hip_bfloat16 h1 = __float2bfloat16(cnt[2 * j2 + 1]);
                    unsigned u0 = *(unsigned short*)&h0;
                    unsigned u1 = *(unsigned short*)&h1;
                    dp[j2] = u0 | (u1 << 16);
                }
            } else {
                #pragma unroll
                for (int j = 0; j < COCHUNK; ++j)
                    avg[(((long)b * 36 + (co0 + j)) * H + oy) * W + ox] = __float2bfloat16(cnt[j]);
            }
        }
    }
}

// ===========================================================================
// Combine ci-split partials + BN + LIF + mean -> bf16 avg (CL or NCHW).
// ===========================================================================
template<int SPLITS, bool CL>
__global__ __launch_bounds__(256) void combine_lif(
    const float* __restrict__ partial,
    const float* __restrict__ bn_s, const float* __restrict__ bn_b,
    const float* __restrict__ thr, const float* __restrict__ beta_raw,
    __hip_bfloat16* __restrict__ avg, int H, int W, int total)
{
    int idx = blockIdx.x * 256 + threadIdx.x;
    if (idx >= total) return;
    int HW = H * W;
    int co = (idx / HW) % 36;
    float hh = 0.f;
    #pragma unroll
    for (int s = 0; s < SPLITS; ++s) hh += partial[(long)s * total + idx];
    hh = hh * bn_s[co] + bn_b[co];
    float beta = 1.f / (1.f + expf(-beta_raw[co]));
    float t    = thr[co];
    float m = 0.f, cnt = 0.f;
    #pragma unroll
    for (int s = 0; s < 4; ++s) {
        m = beta * m + hh;
        if (m > t) { cnt += 1.f; m -= t; }
    }
    if (CL) {
        int b = idx / (36 * HW);
        int rem = idx % HW;
        int y = rem / W, x = rem % W;
        avg[((long)(b * H + y) * W + x) * 40 + co] = __float2bfloat16(cnt * 0.25f);
    } else {
        avg[idx] = __float2bfloat16(cnt * 0.25f);
    }
}

// ===========================================================================
// Weight prepack for MFMA decoder.
// ===========================================================================
__global__ __launch_bounds__(256) void pack_w(
    const float* __restrict__ w, __hip_bfloat16* __restrict__ ap, int total)
{
    int idx = blockIdx.x * 256 + threadIdx.x;
    if (idx >= total) return;
    int m  = idx & 31;
    int h  = (idx >> 5) & 1;
    int s  = (idx >> 6) % 23;
    int cg = idx / (23 * 64);
    int o  = 2 * s + h;
    int co = cg * 32 + m;
    unsigned short v[8];
    #pragma unroll
    for (int j = 0; j < 8; ++j) {
        float x = 0.f;
        if (o < 45) {
            int tap = o / 5, oct = o % 5, ci = oct * 8 + j;
            if (ci < 36) x = w[(long)co * 324 + ci * 9 + tap];
        }
        __hip_bfloat16 hv = __float2bfloat16(x);
        v[j] = *(unsigned short*)&hv;
    }
    *(int4v*)(ap + (long)idx * 8) = *(int4v*)v;
}

// ===========================================================================
// MFMA decoder: conv3x3(36->Cout) + BN + SiLU.
// ===========================================================================
template<int COG>
__global__ __launch_bounds__(256) void dec_mfma(
    const __hip_bfloat16* __restrict__ avg_cl,
    const __hip_bfloat16* __restrict__ apack,
    const float* __restrict__ bn_s, const float* __restrict__ bn_b,
    float* __restrict__ out, int Cout, int H, int W, int tiles_x)
{
    __shared__ __hip_bfloat16 tile[12960];

    const int tid    = threadIdx.x;
    const int b      = blockIdx.y;
    const int cgbase = blockIdx.z * COG;
    const int tx0 = (blockIdx.x % tiles_x) * 16;
    const int ty0 = (blockIdx.x / tiles_x) * 16;

    {
        const __hip_bfloat16* ab = avg_cl + (long)b * H * W * 40;
        for (int i = tid; i < 1620; i += 256) {
            int row = i / 90, u = i - row * 90;
            int px = u / 5, un = u - px * 5;
            int gy = ty0 + row - 1, gx = tx0 + px - 1;
            int4v v = {0, 0, 0, 0};
            if (gy >= 0 && gy < H && gx >= 0 && gx < W)
                v = *(const int4v*)(ab + ((long)gy * W + gx) * 40 + un * 8);
            *(int4v*)(tile + (row * 18 + px) * 40 + un * 8) = v;
        }
    }
    __syncthreads();

    const int lane = tid & 63;
    const int wv   = tid >> 6;
    const int h    = lane >> 5;
    const int n    = lane & 31;
    const int lx   = n & 15;
    const int ly0  = wv * 4 + (n >> 4);

    const char* tb  = (const char*)tile;
    const int   bb0 = ((ly0 + 1) * 18 + (lx + 1)) * 80;
    const int   bb1 = bb0 + 2 * 18 * 80;

    const char* ap = (const char*)apack + (long)cgbase * 23552 + h * 512 + n * 16;

    f32x16 acc[COG][2];
    #pragma unroll
    for (int cg = 0; cg < COG; ++cg)
        #pragma unroll
        for (int pf = 0; pf < 2; ++pf)
            #pragma unroll
            for (int k = 0; k < 16; ++k) acc[cg][pf][k] = 0.f;

    #pragma unroll
    for (int s = 0; s < 23; ++s) {
        int o0 = 2 * s;     if (o0 > 44) o0 = 44;
        int o1 = 2 * s + 1; if (o1 > 44) o1 = 44;
        const int C0 = ((o0 / 5) / 3 - 1) * 1440 + ((o0 / 5) % 3 - 1) * 80 + (o0 % 5) * 16;
        const int C1 = ((o1 / 5) / 3 - 1) * 1440 + ((o1 / 5) % 3 - 1) * 80 + (o1 % 5) * 16;
        const int offc = h ? C1 : C0;
        short8v bf0 = *(const short8v*)(tb + (bb0 + offc));
        short8v bf1 = *(const short8v*)(tb + (bb1 + offc));
        #pragma unroll
        for (int cg = 0; cg < COG; ++cg) {
            short8v af = *(const short8v*)(ap + cg * 23552 + s * 1024);
            acc[cg][0] = __builtin_amdgcn_mfma_f32_32x32x16_bf16(af, bf0, acc[cg][0], 0, 0, 0);
            acc[cg][1] = __builtin_amdgcn_mfma_f32_32x32x16_bf16(af, bf1, acc[cg][1], 0, 0, 0);
        }
    }

    #pragma unroll
    for (int cg = 0; cg < COG; ++cg) {
        #pragma unroll
        for (int r = 0; r < 16; ++r) {
            const int co = ((cgbase + cg) << 5) + (r & 3) + ((r >> 2) << 3) + (h << 2);
            const float sc = bn_s[co], bc = bn_b[co];
            #pragma unroll
            for (int pf = 0; pf < 2; ++pf) {
                const int ly = ly0 + pf * 2;
                const int gy = ty0 + ly, gx = tx0 + lx;
                float v = acc[cg][pf][r] * sc + bc;
                v = v / (1.f + __expf(-v));
                if (gy < H && gx < W)
                    out[(((long)b * Cout + co) * H + gy) * W + gx] = v;
            }
        }
    }
}

// ===========================================================================
// Fallback decoder (VALU, NCHW avg).
// ===========================================================================
template<int COCHUNK, int TDIM>
__global__ __launch_bounds__(TDIM* TDIM) void dec_tiled(
    const __hip_bfloat16* __restrict__ avg,
    const float* __restrict__ w,
    const float* __restrict__ bn_s, const float* __restrict__ bn_b,
    float* __restrict__ out,
    int Cout, int H, int W, int tiles_x)
{
    const int CIN = 36;
    const int TPB = TDIM * TDIM;
    const int HALOD = TDIM + 2;
    __shared__ float fs[CIN][HALOD][HALOD];

    const int tile = blockIdx.x;
    const int b    = blockIdx.y;
    const int co0  = blockIdx.z * COCHUNK;
    const int tx0  = (tile % tiles_x) * TDIM;
    const int ty0  = (tile / tiles_x) * TDIM;

    const int tx = threadIdx.x % TDIM;
    const int ty = threadIdx.x / TDIM;
    const int ox = tx0 + tx, oy = ty0 + ty;

    const __hip_bfloat16* ab = avg + (long)b * CIN * H * W;

    for (int i = threadIdx.x; i < CIN * HALOD * HALOD; i += TPB) {
        int ci = i / (HALOD * HALOD);
        int r  = i % (HALOD * HALOD);
        int hy = r / HALOD, hx = r % HALOD;
        int gy = ty0 + hy - 1, gx = tx0 + hx - 1;
        float v = 0.f;
        if (gy >= 0 && gy < H && gx >= 0 && gx < W)
            v = __bfloat162float(ab[((long)ci * H + gy) * W + gx]);
        fs[ci][hy][hx] = v;
    }
    __syncthreads();

    float acc[COCHUNK];
    #pragma unroll
    for (int j = 0; j < COCHUNK; ++j) acc[j] = 0.f;

    for (int ci = 0; ci < CIN; ++ci) {
        float f0 = fs[ci][ty    ][tx], f1 = fs[ci][ty    ][tx+1], f2 = fs[ci][ty    ][tx+2];
        float f3 = fs[ci][ty + 1][tx], f4 = fs[ci][ty + 1][tx+1], f5 = fs[ci][ty + 1][tx+2];
        float f6 = fs[ci][ty + 2][tx], f7 = fs[ci][ty + 2][tx+1], f8 = fs[ci][ty + 2][tx+2];
        #pragma unroll
        for (int j = 0; j < COCHUNK; ++j) {
            const float* ww = w + ((long)(co0 + j) * CIN + ci) * 9;
            acc[j] += f0 * ww[0] + f1 * ww[1] + f2 * ww[2]
                    + f3 * ww[3] + f4 * ww[4] + f5 * ww[5]
                    + f6 * ww[6] + f7 * ww[7] + f8 * ww[8];
        }
    }

    if (ox < W && oy < H) {
        #pragma unroll
        for (int j = 0; j < COCHUNK; ++j) {
            int co = co0 + j;
            float v = acc[j] * bn_s[co] + bn_b[co];
            out[(((long)b * Cout + co) * H + oy) * W + ox] = v / (1.f + expf(-v));
        }
    }
}

// ===========================================================================
extern "C" void kernel_launch(void* const* d_in, const int* in_sizes, int n_in,
                              void* d_out, int out_size, void* d_ws, size_t ws_size,
                              hipStream_t stream)
{
    const int B = 16;
    const int C[3] = {64, 128, 256};
    const int S[3] = {160, 80, 40};

    float* out = (float*)d_out;
    long out_off[3]; long off = 0;
    for (int l = 0; l < 3; ++l) { out_off[l] = off; off += (long)B * C[l] * S[l] * S[l]; }

    // ---- workspace layout (bytes) ----
    const long avgcl_bytes[3] = {32768000L, 8192000L, 2048000L};
    long avgcl_off[3]; long boff = 0;
    for (int l = 0; l < 3; ++l) { avgcl_off[l] = boff; boff += avgcl_bytes[l]; }
    const long avgcl_total = boff;
    const long ap_bytes[3] = {47104L, 94208L, 188416L};
    long ap_off[3];
    for (int l = 0; l < 3; ++l) { ap_off[l] = boff; boff += ap_bytes[l]; }
    const long we_bytes[3] = {73728L, 147456L, 294912L};
    long wehi_off[3], welo_off[3];
    for (int l = 0; l < 3; ++l) { wehi_off[l] = boff; boff += we_bytes[l];
                                  welo_off[l] = boff; boff += we_bytes[l]; }
    const long part5_off = boff;
    const long part5_bytes = 4L * B * 36 * 1600 * 4;
    boff += part5_bytes;
    const size_t need_full = (size_t)boff;
    const size_t need_min  = (size_t)part5_off;
    // channel-last bf16 hi/lo feat (levels 0,1 only)
    const long fcl_bytes[2] = {52428800L, 26214400L};   // 16*HW*CIN*2
    long fclhi_off[2], fcllo_off[2];
    for (int l = 0; l < 2; ++l) { fclhi_off[l] = boff; boff += fcl_bytes[l];
                                  fcllo_off[l] = boff; boff += fcl_bytes[l]; }
    const size_t need_cl = (size_t)boff;

    char* wsb = (char*)d_ws;

    if (ws_size >= need_min) {
        const bool split5 = ws_size >= need_full;
        const bool use_cl = ws_size >= need_cl;
        hipMemsetAsync(wsb, 0, avgcl_total, stream);

        for (int l = 0; l < 3; ++l) {
            const float* dec_w = (const float*)d_in[9 * l + 6];
            int total = (C[l] / 32) * 23 * 2 * 32;
            pack_w<<<(total + 255) / 256, 256, 0, stream>>>(
                dec_w, (__hip_bfloat16*)(wsb + ap_off[l]), total);
        }
        {
            const float* enc_w3 = (const float*)d_in[1];
            int total = 2 * (64 / 16) * 9 * 2 * 32;
            pack_we<64><<<(total + 255) / 256, 256, 0, stream>>>(
                enc_w3, (__hip_bfloat16*)(wsb + wehi_off[0]),
                (__hip_bfloat16*)(wsb + welo_off[0]), total);
        }
        {
            const float* enc_w4 = (const float*)d_in[10];
            int total = 2 * (128 / 16) * 9 * 2 * 32;
            pack_we<128><<<(total + 255) / 256, 256, 0, stream>>>(
                enc_w4, (__hip_bfloat16*)(wsb + wehi_off[1]),
                (__hip_bfloat16*)(wsb + welo_off[1]), total);
        }
        if (use_cl) {
            // pre-convert feat -> channel-last bf16 hi/lo (levels 0,1)
            {
                int HW = 160 * 160, npx = B * HW;
                feat_cl<64><<<(npx + 63) / 64, 256, 0, stream>>>(
                    (const float*)d_in[0], (__hip_bfloat16*)(wsb + fclhi_off[0]),
                    (__hip_bfloat16*)(wsb + fcllo_off[0]), HW, npx);
            }
            {
                int HW = 80 * 80, npx = B * HW;
                feat_cl<128><<<(npx + 63) / 64, 256, 0, stream>>>(
                    (const float*)d_in[9], (__hip_bfloat16*)(wsb + fclhi_off[1]),
                    (__hip_bfloat16*)(wsb + fcllo_off[1]), HW, npx);
            }
        }

        for (int l = 0; l < 3; ++l) {
            const int base = 9 * l;
            const float* feat     = (const float*)d_in[base + 0];
            const float* enc_w    = (const float*)d_in[base + 1];
            const float* enc_bn_s = (const float*)d_in[base + 2];
            const float* enc_bn_b = (const float*)d_in[base + 3];
            const float* enc_thr  = (const float*)d_in[base + 4];
            const float* enc_beta = (const float*)d_in[base + 5];
            const float* dec_bn_s = (const float*)d_in[base + 7];
            const float* dec_bn_b = (const float*)d_in[base + 8];

            const int Hs = S[l], Wsz = S[l];
            __hip_bfloat16* avg_cl = (__hip_bfloat16*)(wsb + avgcl_off[l]);
            const __hip_bfloat16* ap = (const __hip_bfloat16*)(wsb + ap_off[l]);
            float* r = out + out_off[l];

            if (l == 0) {
                dim3 eg(100, B);
                if (use_cl)
                    enc_mfma_cl<64><<<eg, 256, 0, stream>>>(
                        (const __hip_bfloat16*)(wsb + fclhi_off[0]),
                        (const __hip_bfloat16*)(wsb + fcllo_off[0]),
                        (const __hip_bfloat16*)(wsb + wehi_off[0]),
                        (const __hip_bfloat16*)(wsb + welo_off[0]),
                        enc_bn_s, enc_bn_b, enc_thr, enc_beta, avg_cl, Hs, Wsz, 10);
                else
                    enc_mfma<64><<<eg, 256, 0, stream>>>(
                        feat, (const __hip_bfloat16*)(wsb + wehi_off[0]),
                        (const __hip_bfloat16*)(wsb + welo_off[0]),
                        enc_bn_s, enc_bn_b, enc_thr, enc_beta, avg_cl, Hs, Wsz, 10);
                dim3 dg(100, B, 1);
                dec_mfma<2><<<dg, 256, 0, stream>>>(avg_cl, ap, dec_bn_s, dec_bn_b, r, 64, Hs, Wsz, 10);
            } else if (l == 1) {
                dim3 eg(25, B);
                if (use_cl)
                    enc_mfma_cl<128><<<eg, 256, 0, stream>>>(
                        (const __hip_bfloat16*)(wsb + fclhi_off[1]),
                        (const __hip_bfloat16*)(wsb + fcllo_off[1]),
                        (const __hip_bfloat16*)(wsb + wehi_off[1]),
                        (const __hip_bfloat16*)(wsb + welo_off[1]),
                        enc_bn_s, enc_bn_b, enc_thr, enc_beta, avg_cl, Hs, Wsz, 5);
                else
                    enc_mfma<128><<<eg, 256, 0, stream>>>(
                        feat, (const __hip_bfloat16*)(wsb + wehi_off[1]),
                        (const __hip_bfloat16*)(wsb + welo_off[1]),
                        enc_bn_s, enc_bn_b, enc_thr, enc_beta, avg_cl, Hs, Wsz, 5);
                dim3 dg(25, B, 1);
                dec_mfma<4><<<dg, 256, 0, stream>>>(avg_cl, ap, dec_bn_s, dec_bn_b, r, 128, Hs, Wsz, 5);
            } else {
                if (split5) {
                    float* partial5 = (float*)(wsb + part5_off);
                    dim3 eg(25, B, 12);
                    enc_tiled<256, 64, 16, 12, 8, true, true><<<eg, 64, 0, stream>>>(
                        feat, enc_w, enc_bn_s, enc_bn_b, enc_thr, enc_beta, nullptr, partial5, Hs, Wsz, 5);
                    int total = B * 36 * Hs * Wsz;
                    combine_lif<4, true><<<(total + 255) / 256, 256, 0, stream>>>(
                        partial5, enc_bn_s, enc_bn_b, enc_thr, enc_beta, avg_cl, Hs, Wsz, total);
                } else {
                    dim3 eg(25, B, 3);
                    enc_tiled<256, 256, 16, 12, 8, false, true><<<eg, 64, 0, stream>>>(
                        feat, enc_w, enc_bn_s, enc_bn_b, enc_thr, enc_beta, avg_cl, nullptr, Hs, Wsz, 5);
                }
                dim3 dg(9, B, 2);
                dec_mfma<4><<<dg, 256, 0, stream>>>(avg_cl, ap, dec_bn_s, dec_bn_b, r, 256, Hs, Wsz, 3);
            }
        }
    } else {
        // ================= FALLBACK (NCHW, VALU decoder) =================
        __hip_bfloat16* ws = (__hip_bfloat16*)d_ws;
        long avg_off2[3]; long eoff = 0;
        for (int l = 0; l < 3; ++l) { avg_off2[l] = eoff; eoff += (long)B * 36 * S[l] * S[l]; }
        float* partial5 = (float*)(ws + ((eoff + 7) & ~7L));
        const long part5f = 4L * B * 36 * 40 * 40;
        const size_t old_need = (size_t)((eoff + 7) & ~7L) * 2 + part5f * 4;
        const bool split5 = ws_size >= old_need;

        for (int l = 0; l < 3; ++l) {
            const int base = 9 * l;
            const float* feat     = (const float*)d_in[base + 0];
            const float* enc_w    = (const float*)d_in[base + 1];
            const float* enc_bn_s = (const float*)d_in[base + 2];
            const float* enc_bn_b = (const float*)d_in[base + 3];
            const float* enc_thr  = (const float*)d_in[base + 4];
            const float* enc_beta = (const float*)d_in[base + 5];
            const float* dec_w    = (const float*)d_in[base + 6];
            const float* dec_bn_s = (const float*)d_in[base + 7];
            const float* dec_bn_b = (const float*)d_in[base + 8];

            const int Hs = S[l], Wsz = S[l], Cl = C[l];
            __hip_bfloat16* avg = ws + avg_off2[l];
            float* r = out + out_off[l];

            if (l == 0) {
                dim3 eg(100, B, 3);
                enc_tiled<64, 64, 16, 12, 16, false, false><<<eg, 256, 0, stream>>>(
                    feat, enc_w, enc_bn_s, enc_bn_b, enc_thr, enc_beta, avg, nullptr, Hs, Wsz, 10);
                dim3 dg(100, B, 2);
                dec_tiled<32, 16><<<dg, 256, 0, stream>>>(avg, dec_w, dec_bn_s, dec_bn_b, r, Cl, Hs, Wsz, 10);
            } else if (l == 1) {
                dim3 eg(25, B, 3);
                enc_tiled<128, 128, 16, 12, 16, false, false><<<eg, 256, 0, stream>>>(
                    feat, enc_w, enc_bn_s, enc_bn_b, enc_thr, enc_beta, avg, nullptr, Hs, Wsz, 5);
                dim3 dg(25, B, 4);
                dec_tiled<32, 16><<<dg, 256, 0, stream>>>(avg, dec_w, dec_bn_s, dec_bn_b, r, Cl, Hs, Wsz, 5);
            } else {
                if (split5) {
                    dim3 eg(25, B, 12);
                    enc_tiled<256, 64, 16, 12, 8, true, false><<<eg, 64, 0, stream>>>(
                        feat, enc_w, enc_bn_s, enc_bn_b, enc_thr, enc_beta, nullptr, partial5, Hs, Wsz, 5);
                    int total = B * 36 * Hs * Wsz;
                    combine_lif<4, false><<<(total + 255) / 256, 256, 0, stream>>>(
                        partial5, enc_bn_s, enc_bn_b, enc_thr, enc_beta, avg, Hs, Wsz, total);
                } else {
                    dim3 eg(25, B, 3);
                    enc_tiled<256, 256, 16, 12, 8, false, false><<<eg, 64, 0, stream>>>(
                        feat, enc_w, enc_bn_s, enc_bn_b, enc_thr, enc_beta, avg, nullptr, Hs, Wsz, 5);
                }
                dim3 dg(25, B, 16);
                dec_tiled<16, 8><<<dg, 64, 0, stream>>>(avg, dec_w, dec_bn_s, dec_bn_b, r, Cl, Hs, Wsz, 5);
            }
        }
    }
}

// Round 15
// 663.345 us; speedup vs baseline: 2.1833x; 1.1451x over previous
//
#include <hip/hip_runtime.h>
#include <hip/hip_bf16.h>

typedef __attribute__((ext_vector_type(8)))  short short8v;
typedef __attribute__((ext_vector_type(16))) float f32x16;
typedef __attribute__((ext_vector_type(4)))  int   int4v;

// ===========================================================================
// Encoder weight prepack for MFMA (split bf16 hi/lo).
// ===========================================================================
template<int CIN>
__global__ __launch_bounds__(256) void pack_we(
    const float* __restrict__ w, __hip_bfloat16* __restrict__ whi,
    __hip_bfloat16* __restrict__ wlo, int total)
{
    const int NCHUNK = CIN / 16;
    int idx = blockIdx.x * 256 + threadIdx.x;
    if (idx >= total) return;
    int m  = idx & 31;
    int h  = (idx >> 5) & 1;
    int s  = (idx >> 6) % 9;
    int c  = (idx / 576) % NCHUNK;
    int cg = idx / (576 * NCHUNK);
    int co = cg * 32 + m;
    unsigned short vh[8], vl[8];
    #pragma unroll
    for (int j = 0; j < 8; ++j) {
        int ci = c * 16 + h * 8 + j;
        float x = (co < 36) ? w[(long)co * CIN * 9 + ci * 9 + s] : 0.f;
        __hip_bfloat16 xh = __float2bfloat16(x);
        float rem = x - __bfloat162float(xh);
        __hip_bfloat16 xl = __float2bfloat16(rem);
        vh[j] = *(unsigned short*)&xh;
        vl[j] = *(unsigned short*)&xl;
    }
    *(int4v*)(whi + (long)idx * 8) = *(int4v*)vh;
    *(int4v*)(wlo + (long)idx * 8) = *(int4v*)vl;
}

// ===========================================================================
// feat_cl: fp32 NCHW -> channel-last bf16 hi/lo [p][CIN].
// ===========================================================================
template<int CIN>
__global__ __launch_bounds__(256) void feat_cl(
    const float* __restrict__ f, __hip_bfloat16* __restrict__ fh,
    __hip_bfloat16* __restrict__ fl, int HW, int npx)
{
    __shared__ float t[CIN][64];
    const int p0 = blockIdx.x * 64;

    for (int i = threadIdx.x; i < CIN * 64; i += 256) {
        int ci = i >> 6, px = i & 63;
        int p = p0 + px;
        float v = 0.f;
        if (p < npx) {
            int b = p / HW, r = p - b * HW;
            v = f[((long)b * CIN + ci) * HW + r];
        }
        t[ci][px] = v;
    }
    __syncthreads();

    for (int i = threadIdx.x; i < 64 * (CIN / 8); i += 256) {
        int px = i & 63, oct = i >> 6;
        int p = p0 + px;
        if (p >= npx) continue;
        unsigned short vh[8], vl[8];
        #pragma unroll
        for (int j = 0; j < 8; ++j) {
            float v = t[oct * 8 + j][px];
            __hip_bfloat16 xh = __float2bfloat16(v);
            float rem = v - __bfloat162float(xh);
            __hip_bfloat16 xl = __float2bfloat16(rem);
            vh[j] = *(unsigned short*)&xh;
            vl[j] = *(unsigned short*)&xl;
        }
        *(int4v*)(fh + (long)p * CIN + oct * 8) = *(int4v*)vh;
        *(int4v*)(fl + (long)p * CIN + oct * 8) = *(int4v*)vl;
    }
}

// ===========================================================================
// MFMA encoder, CL-staged, coalesced epilogue.
// After the last chunk the 31KB staging LDS is reused as a [256px][40ch]
// bf16 output tile: LIF results scattered to LDS (b16), then 16B coalesced
// global stores. Requires H,W multiples of 16 (true: 160, 80).
// MFMA core identical to R12/R13/R14 (in-situ verified, absmax 0.047).
// ===========================================================================
template<int CIN>
__global__ __launch_bounds__(256) void enc_mfma_cl(
    const __hip_bfloat16* __restrict__ fh,   // [npx][CIN] hi
    const __hip_bfloat16* __restrict__ fl,   // [npx][CIN] lo
    const __hip_bfloat16* __restrict__ whi,
    const __hip_bfloat16* __restrict__ wlo,
    const float* __restrict__ bn_s, const float* __restrict__ bn_b,
    const float* __restrict__ thr, const float* __restrict__ beta_raw,
    __hip_bfloat16* __restrict__ avg,        // [16][H][W][40]
    int H, int W, int tiles_x)
{
    const int NCHUNK = CIN / 16;
    __shared__ __align__(16) short sbuf[324 * 48];   // hi_t | lo_t ; epilogue tile
    short* hi_t = sbuf;
    short* lo_t = sbuf + 324 * 24;

    const int tid = threadIdx.x;
    const int b   = blockIdx.y;
    const int tx0 = (blockIdx.x % tiles_x) * 16;
    const int ty0 = (blockIdx.x / tiles_x) * 16;

    const int lane = tid & 63;
    const int wv   = tid >> 6;
    const int h    = lane >> 5;
    const int n    = lane & 31;
    const int lx   = n & 15;
    const int ly0  = wv * 4 + (n >> 4);

    f32x16 acc[2][2];
    #pragma unroll
    for (int cg = 0; cg < 2; ++cg)
        #pragma unroll
        for (int pf = 0; pf < 2; ++pf)
            #pragma unroll
            for (int k = 0; k < 16; ++k) acc[cg][pf][k] = 0.f;

    const char* aph = (const char*)whi + h * 512 + n * 16;
    const char* apl = (const char*)wlo + h * 512 + n * 16;
    const long  cgstride = (long)NCHUNK * 9216;

    for (int c = 0; c < NCHUNK; ++c) {
        for (int i = tid; i < 648; i += 256) {
            int p   = i >> 1, oct = i & 1;
            int hy = p / 18, hx = p - hy * 18;
            int gy = ty0 + hy - 1, gx = tx0 + hx - 1;
            int4v vh = {0, 0, 0, 0}, vl = {0, 0, 0, 0};
            if (gy >= 0 && gy < H && gx >= 0 && gx < W) {
                long pp = ((long)(b * H + gy) * W + gx) * CIN + c * 16 + oct * 8;
                vh = *(const int4v*)(fh + pp);
                vl = *(const int4v*)(fl + pp);
            }
            *(int4v*)((char*)hi_t + p * 48 + oct * 16) = vh;
            *(int4v*)((char*)lo_t + p * 48 + oct * 16) = vl;
        }
        __syncthreads();

        const char* ahc = aph + (long)c * 9216;
        const char* alc = apl + (long)c * 9216;
        #pragma unroll
        for (int s = 0; s < 9; ++s) {
            const int dy = s / 3, dx = s % 3;
            const int p0 = (ly0 + dy) * 18 + (lx + dx);
            const int p1 = p0 + 36;
            short8v bh0 = *(const short8v*)((const char*)hi_t + p0 * 48 + h * 16);
            short8v bh1 = *(const short8v*)((const char*)hi_t + p1 * 48 + h * 16);
            short8v bl0 = *(const short8v*)((const char*)lo_t + p0 * 48 + h * 16);
            short8v bl1 = *(const short8v*)((const char*)lo_t + p1 * 48 + h * 16);
            #pragma unroll
            for (int cg = 0; cg < 2; ++cg) {
                short8v af = *(const short8v*)(ahc + cg * cgstride + s * 1024);
                short8v al = *(const short8v*)(alc + cg * cgstride + s * 1024);
                acc[cg][0] = __builtin_amdgcn_mfma_f32_32x32x16_bf16(af, bh0, acc[cg][0], 0, 0, 0);
                acc[cg][0] = __builtin_amdgcn_mfma_f32_32x32x16_bf16(af, bl0, acc[cg][0], 0, 0, 0);
                acc[cg][0] = __builtin_amdgcn_mfma_f32_32x32x16_bf16(al, bh0, acc[cg][0], 0, 0, 0);
                acc[cg][1] = __builtin_amdgcn_mfma_f32_32x32x16_bf16(af, bh1, acc[cg][1], 0, 0, 0);
                acc[cg][1] = __builtin_amdgcn_mfma_f32_32x32x16_bf16(af, bl1, acc[cg][1], 0, 0, 0);
                acc[cg][1] = __builtin_amdgcn_mfma_f32_32x32x16_bf16(al, bh1, acc[cg][1], 0, 0, 0);
            }
        }
        __syncthreads();
    }

    // ---- epilogue: LIF -> LDS transpose -> coalesced 16B stores ----
    for (int i = tid; i < 1280; i += 256)
        *(int4v*)((char*)sbuf + i * 16) = (int4v){0, 0, 0, 0};
    __syncthreads();

    #pragma unroll
    for (int cg = 0; cg < 2; ++cg) {
        #pragma unroll
        for (int r = 0; r < 16; ++r) {
            const int co = (cg << 5) + (r & 3) + ((r >> 2) << 3) + (h << 2);
            if (co < 36) {
                const float sc   = bn_s[co], sb = bn_b[co];
                const float beta = 1.f / (1.f + expf(-beta_raw[co]));
                const float t    = thr[co];
                #pragma unroll
                for (int pf = 0; pf < 2; ++pf) {
                    const int ly = ly0 + pf * 2;
                    float hv = acc[cg][pf][r] * sc + sb;
                    float m = 0.f, c2 = 0.f;
                    #pragma unroll
                    for (int s4 = 0; s4 < 4; ++s4) {
                        m = beta * m + hv;
                        if (m > t) { c2 += 1.f; m -= t; }
                    }
                    __hip_bfloat16 ov = __float2bfloat16(c2 * 0.25f);
                    sbuf[(ly * 16 + lx) * 40 + co] = *(short*)&ov;
                }
            }
        }
    }
    __syncthreads();

    const long tilebase = ((long)(b * H + ty0) * W + tx0) * 40;
    for (int i = tid; i < 1280; i += 256) {
        int px = i / 5, u = i - px * 5;
        int py2 = px >> 4, px2 = px & 15;
        *(int4v*)(avg + tilebase + ((long)py2 * W + px2) * 40 + u * 8) =
            *(const int4v*)(sbuf + px * 40 + u * 8);
    }
}

// ===========================================================================
// MFMA encoder with in-kernel conversion (fallback when ws small).
// ===========================================================================
template<int CIN>
__global__ __launch_bounds__(256) void enc_mfma(
    const float* __restrict__ feat,
    const __hip_bfloat16* __restrict__ whi,
    const __hip_bfloat16* __restrict__ wlo,
    const float* __restrict__ bn_s, const float* __restrict__ bn_b,
    const float* __restrict__ thr, const float* __restrict__ beta_raw,
    __hip_bfloat16* __restrict__ avg,
    int H, int W, int tiles_x)
{
    const int NCHUNK = CIN / 16;
    __shared__ __align__(16) short hi_t[324 * 24];
    __shared__ __align__(16) short lo_t[324 * 24];

    const int tid = threadIdx.x;
    const int b   = blockIdx.y;
    const int tx0 = (blockIdx.x % tiles_x) * 16;
    const int ty0 = (blockIdx.x / tiles_x) * 16;

    const int lane = tid & 63;
    const int wv   = tid >> 6;
    const int h    = lane >> 5;
    const int n    = lane & 31;
    const int lx   = n & 15;
    const int ly0  = wv * 4 + (n >> 4);

    f32x16 acc[2][2];
    #pragma unroll
    for (int cg = 0; cg < 2; ++cg)
        #pragma unroll
        for (int pf = 0; pf < 2; ++pf)
            #pragma unroll
            for (int k = 0; k < 16; ++k) acc[cg][pf][k] = 0.f;

    const float* fb = feat + (long)b * CIN * H * W;
    const char* aph = (const char*)whi + h * 512 + n * 16;
    const char* apl = (const char*)wlo + h * 512 + n * 16;
    const long  cgstride = (long)NCHUNK * 9216;

    for (int c = 0; c < NCHUNK; ++c) {
        for (int i = tid; i < 324 * 16; i += 256) {
            int cil = i / 324;
            int p   = i - cil * 324;
            int hy = p / 18, hx = p - hy * 18;
            int gy = ty0 + hy - 1, gx = tx0 + hx - 1;
            float v = 0.f;
            if (gy >= 0 && gy < H && gx >= 0 && gx < W)
                v = fb[((long)(c * 16 + cil) * H + gy) * W + gx];
            __hip_bfloat16 vh = __float2bfloat16(v);
            float rem = v - __bfloat162float(vh);
            __hip_bfloat16 vl = __float2bfloat16(rem);
            hi_t[p * 24 + cil] = *(short*)&vh;
            lo_t[p * 24 + cil] = *(short*)&vl;
        }
        __syncthreads();

        const char* ahc = aph + (long)c * 9216;
        const char* alc = apl + (long)c * 9216;
        #pragma unroll
        for (int s = 0; s < 9; ++s) {
            const int dy = s / 3, dx = s % 3;
            const int p0 = (ly0 + dy) * 18 + (lx + dx);
            const int p1 = p0 + 36;
            short8v bh0 = *(const short8v*)((const char*)hi_t + p0 * 48 + h * 16);
            short8v bh1 = *(const short8v*)((const char*)hi_t + p1 * 48 + h * 16);
            short8v bl0 = *(const short8v*)((const char*)lo_t + p0 * 48 + h * 16);
            short8v bl1 = *(const short8v*)((const char*)lo_t + p1 * 48 + h * 16);
            #pragma unroll
            for (int cg = 0; cg < 2; ++cg) {
                short8v af = *(const short8v*)(ahc + cg * cgstride + s * 1024);
                short8v al = *(const short8v*)(alc + cg * cgstride + s * 1024);
                acc[cg][0] = __builtin_amdgcn_mfma_f32_32x32x16_bf16(af, bh0, acc[cg][0], 0, 0, 0);
                acc[cg][0] = __builtin_amdgcn_mfma_f32_32x32x16_bf16(af, bl0, acc[cg][0], 0, 0, 0);
                acc[cg][0] = __builtin_amdgcn_mfma_f32_32x32x16_bf16(al, bh0, acc[cg][0], 0, 0, 0);
                acc[cg][1] = __builtin_amdgcn_mfma_f32_32x32x16_bf16(af, bh1, acc[cg][1], 0, 0, 0);
                acc[cg][1] = __builtin_amdgcn_mfma_f32_32x32x16_bf16(af, bl1, acc[cg][1], 0, 0, 0);
                acc[cg][1] = __builtin_amdgcn_mfma_f32_32x32x16_bf16(al, bh1, acc[cg][1], 0, 0, 0);
            }
        }
        __syncthreads();
    }

    #pragma unroll
    for (int cg = 0; cg < 2; ++cg) {
        #pragma unroll
        for (int r = 0; r < 16; ++r) {
            const int co = (cg << 5) + (r & 3) + ((r >> 2) << 3) + (h << 2);
            if (co < 36) {
                const float sc   = bn_s[co], sb = bn_b[co];
                const float beta = 1.f / (1.f + expf(-beta_raw[co]));
                const float t    = thr[co];
                #pragma unroll
                for (int pf = 0; pf < 2; ++pf) {
                    const int gy = ty0 + ly0 + pf * 2, gx = tx0 + lx;
                    float hv = acc[cg][pf][r] * sc + sb;
                    float m = 0.f, c2 = 0.f;
                    #pragma unroll
                    for (int s4 = 0; s4 < 4; ++s4) {
                        m = beta * m + hv;
                        if (m > t) { c2 += 1.f; m -= t; }
                    }
                    if (gy < H && gx < W)
                        avg[((long)(b * H + gy) * W + gx) * 40 + co] =
                            __float2bfloat16(c2 * 0.25f);
                }
            }
        }
    }
}

// ===========================================================================
// Original encoder (enc5 ci-split + fallback path).
// ===========================================================================
template<int CIN, int CIPER, int CICHUNK, int COCHUNK, int TDIM, bool PARTIAL, bool CL>
__global__ __launch_bounds__(TDIM* TDIM) void enc_tiled(
    const float* __restrict__ feat,
    const float* __restrict__ w,
    const float* __restrict__ bn_s, const float* __restrict__ bn_b,
    const float* __restrict__ thr, const float* __restrict__ beta_raw,
    __hip_bfloat16* __restrict__ avg,
    float* __restrict__ partial,
    int H, int W, int tiles_x)
{
    const int TPB  = TDIM * TDIM;
    const int HALOD = TDIM + 2;
    const int NCO  = 36 / COCHUNK;
    __shared__ float fs[CICHUNK][HALOD][HALOD];

    const int tile = blockIdx.x;
    const int b    = blockIdx.y;
    const int coc  = blockIdx.z % NCO;
    const int cis  = blockIdx.z / NCO;
    const int co0  = coc * COCHUNK;
    const int tx0  = (tile % tiles_x) * TDIM;
    const int ty0  = (tile / tiles_x) * TDIM;

    const int tx = threadIdx.x % TDIM;
    const int ty = threadIdx.x / TDIM;
    const int ox = tx0 + tx, oy = ty0 + ty;

    float acc[COCHUNK];
    #pragma unroll
    for (int c = 0; c < COCHUNK; ++c) acc[c] = 0.f;

    const float* fb = feat + (long)b * CIN * H * W;
    const int ci_base = cis * CIPER;

    for (int cc = ci_base; cc < ci_base + CIPER; cc += CICHUNK) {
        for (int i = threadIdx.x; i < CICHUNK * HALOD * HALOD; i += TPB) {
            int ci = i / (HALOD * HALOD);
            int r  = i % (HALOD * HALOD);
            int hy = r / HALOD, hx = r % HALOD;
            int gy = ty0 + hy - 1, gx = tx0 + hx - 1;
            float v = 0.f;
            if (gy >= 0 && gy < H && gx >= 0 && gx < W)
                v = fb[((long)(cc + ci) * H + gy) * W + gx];
            fs[ci][hy][hx] = v;
        }
        __syncthreads();

        for (int ci = 0; ci < CICHUNK; ++ci) {
            float f0 = fs[ci][ty    ][tx], f1 = fs[ci][ty    ][tx+1], f2 = fs[ci][ty    ][tx+2];
            float f3 = fs[ci][ty + 1][tx], f4 = fs[ci][ty + 1][tx+1], f5 = fs[ci][ty + 1][tx+2];
            float f6 = fs[ci][ty + 2][tx], f7 = fs[ci][ty + 2][tx+1], f8 = fs[ci][ty + 2][tx+2];
            const float* wq = w + (long)(cc + ci) * 9;
            #pragma unroll
            for (int j = 0; j < COCHUNK; ++j) {
                const float* ww = wq + (long)(co0 + j) * CIN * 9;
                acc[j] += f0 * ww[0] + f1 * ww[1] + f2 * ww[2]
                        + f3 * ww[3] + f4 * ww[4] + f5 * ww[5]
                        + f6 * ww[6] + f7 * ww[7] + f8 * ww[8];
            }
        }
        __syncthreads();
    }

    if (ox < W && oy < H) {
        if (PARTIAL) {
            #pragma unroll
            for (int j = 0; j < COCHUNK; ++j)
                partial[((((long)cis * 16 + b) * 36 + (co0 + j)) * H + oy) * W + ox] = acc[j];
        } else {
            float cnt[COCHUNK];
            #pragma unroll
            for (int j = 0; j < COCHUNK; ++j) {
                int co = co0 + j;
                float hh   = acc[j] * bn_s[co] + bn_b[co];
                float beta = 1.f / (1.f + expf(-beta_raw[co]));
                float t    = thr[co];
                float m = 0.f, c2 = 0.f;
                #pragma unroll
                for (int s = 0; s < 4; ++s) {
                    m = beta * m + hh;
                    if (m > t) { c2 += 1.f; m -= t; }
                }
                cnt[j] = c2 * 0.25f;
            }
            if (CL) {
                unsigned* dp = (unsigned*)(avg + ((long)(b * H + oy) * W + ox) * 40 + co0);
                #pragma unroll
                for (int j2 = 0; j2 < COCHUNK / 2; ++j2) {
                    __hip_bfloat16 h0 = __float2bfloat16(cnt[2 * j2]);
                    __hip_bfloat16 h1 = __float2bfloat16(cnt[2 * j2 + 1]);
                    unsigned u0 = *(unsigned short*)&h0;
                    unsigned u1 = *(unsigned short*)&h1;
                    dp[j2] = u0 | (u1 << 16);
                }
            } else {
                #pragma unroll
                for (int j = 0; j < COCHUNK; ++j)
                    avg[(((long)b * 36 + (co0 + j)) * H + oy) * W + ox] = __float2bfloat16(cnt[j]);
            }
        }
    }
}

// ===========================================================================
// Combine ci-split partials + BN + LIF + mean -> bf16 avg (CL or NCHW).
// ===========================================================================
template<int SPLITS, bool CL>
__global__ __launch_bounds__(256) void combine_lif(
    const float* __restrict__ partial,
    const float* __restrict__ bn_s, const float* __restrict__ bn_b,
    const float* __restrict__ thr, const float* __restrict__ beta_raw,
    __hip_bfloat16* __restrict__ avg, int H, int W, int total)
{
    int idx = blockIdx.x * 256 + threadIdx.x;
    if (idx >= total) return;
    int HW = H * W;
    int co = (idx / HW) % 36;
    float hh = 0.f;
    #pragma unroll
    for (int s = 0; s < SPLITS; ++s) hh += partial[(long)s * total + idx];
    hh = hh * bn_s[co] + bn_b[co];
    float beta = 1.f / (1.f + expf(-beta_raw[co]));
    float t    = thr[co];
    float m = 0.f, cnt = 0.f;
    #pragma unroll
    for (int s = 0; s < 4; ++s) {
        m = beta * m + hh;
        if (m > t) { cnt += 1.f; m -= t; }
    }
    if (CL) {
        int b = idx / (36 * HW);
        int rem = idx % HW;
        int y = rem / W, x = rem % W;
        avg[((long)(b * H + y) * W + x) * 40 + co] = __float2bfloat16(cnt * 0.25f);
    } else {
        avg[idx] = __float2bfloat16(cnt * 0.25f);
    }
}

// ===========================================================================
// Weight prepack for MFMA decoder.
// ===========================================================================
__global__ __launch_bounds__(256) void pack_w(
    const float* __restrict__ w, __hip_bfloat16* __restrict__ ap, int total)
{
    int idx = blockIdx.x * 256 + threadIdx.x;
    if (idx >= total) return;
    int m  = idx & 31;
    int h  = (idx >> 5) & 1;
    int s  = (idx >> 6) % 23;
    int cg = idx / (23 * 64);
    int o  = 2 * s + h;
    int co = cg * 32 + m;
    unsigned short v[8];
    #pragma unroll
    for (int j = 0; j < 8; ++j) {
        float x = 0.f;
        if (o < 45) {
            int tap = o / 5, oct = o % 5, ci = oct * 8 + j;
            if (ci < 36) x = w[(long)co * 324 + ci * 9 + tap];
        }
        __hip_bfloat16 hv = __float2bfloat16(x);
        v[j] = *(unsigned short*)&hv;
    }
    *(int4v*)(ap + (long)idx * 8) = *(int4v*)v;
}

// ===========================================================================
// MFMA decoder: conv3x3(36->Cout) + BN + SiLU.
// ===========================================================================
template<int COG>
__global__ __launch_bounds__(256) void dec_mfma(
    const __hip_bfloat16* __restrict__ avg_cl,
    const __hip_bfloat16* __restrict__ apack,
    const float* __restrict__ bn_s, const float* __restrict__ bn_b,
    float* __restrict__ out, int Cout, int H, int W, int tiles_x)
{
    __shared__ __hip_bfloat16 tile[12960];

    const int tid    = threadIdx.x;
    const int b      = blockIdx.y;
    const int cgbase = blockIdx.z * COG;
    const int tx0 = (blockIdx.x % tiles_x) * 16;
    const int ty0 = (blockIdx.x / tiles_x) * 16;

    {
        const __hip_bfloat16* ab = avg_cl + (long)b * H * W * 40;
        for (int i = tid; i < 1620; i += 256) {
            int row = i / 90, u = i - row * 90;
            int px = u / 5, un = u - px * 5;
            int gy = ty0 + row - 1, gx = tx0 + px - 1;
            int4v v = {0, 0, 0, 0};
            if (gy >= 0 && gy < H && gx >= 0 && gx < W)
                v = *(const int4v*)(ab + ((long)gy * W + gx) * 40 + un * 8);
            *(int4v*)(tile + (row * 18 + px) * 40 + un * 8) = v;
        }
    }
    __syncthreads();

    const int lane = tid & 63;
    const int wv   = tid >> 6;
    const int h    = lane >> 5;
    const int n    = lane & 31;
    const int lx   = n & 15;
    const int ly0  = wv * 4 + (n >> 4);

    const char* tb  = (const char*)tile;
    const int   bb0 = ((ly0 + 1) * 18 + (lx + 1)) * 80;
    const int   bb1 = bb0 + 2 * 18 * 80;

    const char* ap = (const char*)apack + (long)cgbase * 23552 + h * 512 + n * 16;

    f32x16 acc[COG][2];
    #pragma unroll
    for (int cg = 0; cg < COG; ++cg)
        #pragma unroll
        for (int pf = 0; pf < 2; ++pf)
            #pragma unroll
            for (int k = 0; k < 16; ++k) acc[cg][pf][k] = 0.f;

    #pragma unroll
    for (int s = 0; s < 23; ++s) {
        int o0 = 2 * s;     if (o0 > 44) o0 = 44;
        int o1 = 2 * s + 1; if (o1 > 44) o1 = 44;
        const int C0 = ((o0 / 5) / 3 - 1) * 1440 + ((o0 / 5) % 3 - 1) * 80 + (o0 % 5) * 16;
        const int C1 = ((o1 / 5) / 3 - 1) * 1440 + ((o1 / 5) % 3 - 1) * 80 + (o1 % 5) * 16;
        const int offc = h ? C1 : C0;
        short8v bf0 = *(const short8v*)(tb + (bb0 + offc));
        short8v bf1 = *(const short8v*)(tb + (bb1 + offc));
        #pragma unroll
        for (int cg = 0; cg < COG; ++cg) {
            short8v af = *(const short8v*)(ap + cg * 23552 + s * 1024);
            acc[cg][0] = __builtin_amdgcn_mfma_f32_32x32x16_bf16(af, bf0, acc[cg][0], 0, 0, 0);
            acc[cg][1] = __builtin_amdgcn_mfma_f32_32x32x16_bf16(af, bf1, acc[cg][1], 0, 0, 0);
        }
    }

    #pragma unroll
    for (int cg = 0; cg < COG; ++cg) {
        #pragma unroll
        for (int r = 0; r < 16; ++r) {
            const int co = ((cgbase + cg) << 5) + (r & 3) + ((r >> 2) << 3) + (h << 2);
            const float sc = bn_s[co], bc = bn_b[co];
            #pragma unroll
            for (int pf = 0; pf < 2; ++pf) {
                const int ly = ly0 + pf * 2;
                const int gy = ty0 + ly, gx = tx0 + lx;
                float v = acc[cg][pf][r] * sc + bc;
                v = v / (1.f + __expf(-v));
                if (gy < H && gx < W)
                    out[(((long)b * Cout + co) * H + gy) * W + gx] = v;
            }
        }
    }
}

// ===========================================================================
// Fallback decoder (VALU, NCHW avg).
// ===========================================================================
template<int COCHUNK, int TDIM>
__global__ __launch_bounds__(TDIM* TDIM) void dec_tiled(
    const __hip_bfloat16* __restrict__ avg,
    const float* __restrict__ w,
    const float* __restrict__ bn_s, const float* __restrict__ bn_b,
    float* __restrict__ out,
    int Cout, int H, int W, int tiles_x)
{
    const int CIN = 36;
    const int TPB = TDIM * TDIM;
    const int HALOD = TDIM + 2;
    __shared__ float fs[CIN][HALOD][HALOD];

    const int tile = blockIdx.x;
    const int b    = blockIdx.y;
    const int co0  = blockIdx.z * COCHUNK;
    const int tx0  = (tile % tiles_x) * TDIM;
    const int ty0  = (tile / tiles_x) * TDIM;

    const int tx = threadIdx.x % TDIM;
    const int ty = threadIdx.x / TDIM;
    const int ox = tx0 + tx, oy = ty0 + ty;

    const __hip_bfloat16* ab = avg + (long)b * CIN * H * W;

    for (int i = threadIdx.x; i < CIN * HALOD * HALOD; i += TPB) {
        int ci = i / (HALOD * HALOD);
        int r  = i % (HALOD * HALOD);
        int hy = r / HALOD, hx = r % HALOD;
        int gy = ty0 + hy - 1, gx = tx0 + hx - 1;
        float v = 0.f;
        if (gy >= 0 && gy < H && gx >= 0 && gx < W)
            v = __bfloat162float(ab[((long)ci * H + gy) * W + gx]);
        fs[ci][hy][hx] = v;
    }
    __syncthreads();

    float acc[COCHUNK];
    #pragma unroll
    for (int j = 0; j < COCHUNK; ++j) acc[j] = 0.f;

    for (int ci = 0; ci < CIN; ++ci) {
        float f0 = fs[ci][ty    ][tx], f1 = fs[ci][ty    ][tx+1], f2 = fs[ci][ty    ][tx+2];
        float f3 = fs[ci][ty + 1][tx], f4 = fs[ci][ty + 1][tx+1], f5 = fs[ci][ty + 1][tx+2];
        float f6 = fs[ci][ty + 2][tx], f7 = fs[ci][ty + 2][tx+1], f8 = fs[ci][ty + 2][tx+2];
        #pragma unroll
        for (int j = 0; j < COCHUNK; ++j) {
            const float* ww = w + ((long)(co0 + j) * CIN + ci) * 9;
            acc[j] += f0 * ww[0] + f1 * ww[1] + f2 * ww[2]
                    + f3 * ww[3] + f4 * ww[4] + f5 * ww[5]
                    + f6 * ww[6] + f7 * ww[7] + f8 * ww[8];
        }
    }

    if (ox < W && oy < H) {
        #pragma unroll
        for (int j = 0; j < COCHUNK; ++j) {
            int co = co0 + j;
            float v = acc[j] * bn_s[co] + bn_b[co];
            out[(((long)b * Cout + co) * H + oy) * W + ox] = v / (1.f + expf(-v));
        }
    }
}

// ===========================================================================
extern "C" void kernel_launch(void* const* d_in, const int* in_sizes, int n_in,
                              void* d_out, int out_size, void* d_ws, size_t ws_size,
                              hipStream_t stream)
{
    const int B = 16;
    const int C[3] = {64, 128, 256};
    const int S[3] = {160, 80, 40};

    float* out = (float*)d_out;
    long out_off[3]; long off = 0;
    for (int l = 0; l < 3; ++l) { out_off[l] = off; off += (long)B * C[l] * S[l] * S[l]; }

    // ---- workspace layout (bytes) ----
    const long avgcl_bytes[3] = {32768000L, 8192000L, 2048000L};
    long avgcl_off[3]; long boff = 0;
    for (int l = 0; l < 3; ++l) { avgcl_off[l] = boff; boff += avgcl_bytes[l]; }
    const long avgcl_total = boff;
    const long ap_bytes[3] = {47104L, 94208L, 188416L};
    long ap_off[3];
    for (int l = 0; l < 3; ++l) { ap_off[l] = boff; boff += ap_bytes[l]; }
    const long we_bytes[3] = {73728L, 147456L, 294912L};
    long wehi_off[3], welo_off[3];
    for (int l = 0; l < 3; ++l) { wehi_off[l] = boff; boff += we_bytes[l];
                                  welo_off[l] = boff; boff += we_bytes[l]; }
    const long part5_off = boff;
    const long part5_bytes = 4L * B * 36 * 1600 * 4;
    boff += part5_bytes;
    const size_t need_full = (size_t)boff;
    const size_t need_min  = (size_t)part5_off;
    const long fcl_bytes[2] = {52428800L, 26214400L};
    long fclhi_off[2], fcllo_off[2];
    for (int l = 0; l < 2; ++l) { fclhi_off[l] = boff; boff += fcl_bytes[l];
                                  fcllo_off[l] = boff; boff += fcl_bytes[l]; }
    const size_t need_cl = (size_t)boff;

    char* wsb = (char*)d_ws;

    if (ws_size >= need_min) {
        const bool split5 = ws_size >= need_full;
        const bool use_cl = ws_size >= need_cl;
        hipMemsetAsync(wsb, 0, avgcl_total, stream);

        for (int l = 0; l < 3; ++l) {
            const float* dec_w = (const float*)d_in[9 * l + 6];
            int total = (C[l] / 32) * 23 * 2 * 32;
            pack_w<<<(total + 255) / 256, 256, 0, stream>>>(
                dec_w, (__hip_bfloat16*)(wsb + ap_off[l]), total);
        }
        {
            const float* enc_w3 = (const float*)d_in[1];
            int total = 2 * (64 / 16) * 9 * 2 * 32;
            pack_we<64><<<(total + 255) / 256, 256, 0, stream>>>(
                enc_w3, (__hip_bfloat16*)(wsb + wehi_off[0]),
                (__hip_bfloat16*)(wsb + welo_off[0]), total);
        }
        {
            const float* enc_w4 = (const float*)d_in[10];
            int total = 2 * (128 / 16) * 9 * 2 * 32;
            pack_we<128><<<(total + 255) / 256, 256, 0, stream>>>(
                enc_w4, (__hip_bfloat16*)(wsb + wehi_off[1]),
                (__hip_bfloat16*)(wsb + welo_off[1]), total);
        }
        if (use_cl) {
            {
                int HW = 160 * 160, npx = B * HW;
                feat_cl<64><<<(npx + 63) / 64, 256, 0, stream>>>(
                    (const float*)d_in[0], (__hip_bfloat16*)(wsb + fclhi_off[0]),
                    (__hip_bfloat16*)(wsb + fcllo_off[0]), HW, npx);
            }
            {
                int HW = 80 * 80, npx = B * HW;
                feat_cl<128><<<(npx + 63) / 64, 256, 0, stream>>>(
                    (const float*)d_in[9], (__hip_bfloat16*)(wsb + fclhi_off[1]),
                    (__hip_bfloat16*)(wsb + fcllo_off[1]), HW, npx);
            }
        }

        for (int l = 0; l < 3; ++l) {
            const int base = 9 * l;
            const float* feat     = (const float*)d_in[base + 0];
            const float* enc_w    = (const float*)d_in[base + 1];
            const float* enc_bn_s = (const float*)d_in[base + 2];
            const float* enc_bn_b = (const float*)d_in[base + 3];
            const float* enc_thr  = (const float*)d_in[base + 4];
            const float* enc_beta = (const float*)d_in[base + 5];
            const float* dec_bn_s = (const float*)d_in[base + 7];
            const float* dec_bn_b = (const float*)d_in[base + 8];

            const int Hs = S[l], Wsz = S[l];
            __hip_bfloat16* avg_cl = (__hip_bfloat16*)(wsb + avgcl_off[l]);
            const __hip_bfloat16* ap = (const __hip_bfloat16*)(wsb + ap_off[l]);
            float* r = out + out_off[l];

            if (l == 0) {
                dim3 eg(100, B);
                if (use_cl)
                    enc_mfma_cl<64><<<eg, 256, 0, stream>>>(
                        (const __hip_bfloat16*)(wsb + fclhi_off[0]),
                        (const __hip_bfloat16*)(wsb + fcllo_off[0]),
                        (const __hip_bfloat16*)(wsb + wehi_off[0]),
                        (const __hip_bfloat16*)(wsb + welo_off[0]),
                        enc_bn_s, enc_bn_b, enc_thr, enc_beta, avg_cl, Hs, Wsz, 10);
                else
                    enc_mfma<64><<<eg, 256, 0, stream>>>(
                        feat, (const __hip_bfloat16*)(wsb + wehi_off[0]),
                        (const __hip_bfloat16*)(wsb + welo_off[0]),
                        enc_bn_s, enc_bn_b, enc_thr, enc_beta, avg_cl, Hs, Wsz, 10);
                dim3 dg(100, B, 1);
                dec_mfma<2><<<dg, 256, 0, stream>>>(avg_cl, ap, dec_bn_s, dec_bn_b, r, 64, Hs, Wsz, 10);
            } else if (l == 1) {
                dim3 eg(25, B);
                if (use_cl)
                    enc_mfma_cl<128><<<eg, 256, 0, stream>>>(
                        (const __hip_bfloat16*)(wsb + fclhi_off[1]),
                        (const __hip_bfloat16*)(wsb + fcllo_off[1]),
                        (const __hip_bfloat16*)(wsb + wehi_off[1]),
                        (const __hip_bfloat16*)(wsb + welo_off[1]),
                        enc_bn_s, enc_bn_b, enc_thr, enc_beta, avg_cl, Hs, Wsz, 5);
                else
                    enc_mfma<128><<<eg, 256, 0, stream>>>(
                        feat, (const __hip_bfloat16*)(wsb + wehi_off[1]),
                        (const __hip_bfloat16*)(wsb + welo_off[1]),
                        enc_bn_s, enc_bn_b, enc_thr, enc_beta, avg_cl, Hs, Wsz, 5);
                // dec4: 800 blocks (COG=2, z=2) for latency hiding
                dim3 dg(25, B, 2);
                dec_mfma<2><<<dg, 256, 0, stream>>>(avg_cl, ap, dec_bn_s, dec_bn_b, r, 128, Hs, Wsz, 5);
            } else {
                if (split5) {
                    float* partial5 = (float*)(wsb + part5_off);
                    dim3 eg(25, B, 12);
                    enc_tiled<256, 64, 16, 12, 8, true, true><<<eg, 64, 0, stream>>>(
                        feat, enc_w, enc_bn_s, enc_bn_b, enc_thr, enc_beta, nullptr, partial5, Hs, Wsz, 5);
                    int total = B * 36 * Hs * Wsz;
                    combine_lif<4, true><<<(total + 255) / 256, 256, 0, stream>>>(
                        partial5, enc_bn_s, enc_bn_b, enc_thr, enc_beta, avg_cl, Hs, Wsz, total);
                } else {
                    dim3 eg(25, B, 3);
                    enc_tiled<256, 256, 16, 12, 8, false, true><<<eg, 64, 0, stream>>>(
                        feat, enc_w, enc_bn_s, enc_bn_b, enc_thr, enc_beta, avg_cl, nullptr, Hs, Wsz, 5);
                }
                // dec5: 1152 blocks (COG=2, z=4)
                dim3 dg(9, B, 4);
                dec_mfma<2><<<dg, 256, 0, stream>>>(avg_cl, ap, dec_bn_s, dec_bn_b, r, 256, Hs, Wsz, 3);
            }
        }
    } else {
        // ================= FALLBACK (NCHW, VALU decoder) =================
        __hip_bfloat16* ws = (__hip_bfloat16*)d_ws;
        long avg_off2[3]; long eoff = 0;
        for (int l = 0; l < 3; ++l) { avg_off2[l] = eoff; eoff += (long)B * 36 * S[l] * S[l]; }
        float* partial5 = (float*)(ws + ((eoff + 7) & ~7L));
        const long part5f = 4L * B * 36 * 40 * 40;
        const size_t old_need = (size_t)((eoff + 7) & ~7L) * 2 + part5f * 4;
        const bool split5 = ws_size >= old_need;

        for (int l = 0; l < 3; ++l) {
            const int base = 9 * l;
            const float* feat     = (const float*)d_in[base + 0];
            const float* enc_w    = (const float*)d_in[base + 1];
            const float* enc_bn_s = (const float*)d_in[base + 2];
            const float* enc_bn_b = (const float*)d_in[base + 3];
            const float* enc_thr  = (const float*)d_in[base + 4];
            const float* enc_beta = (const float*)d_in[base + 5];
            const float* dec_w    = (const float*)d_in[base + 6];
            const float* dec_bn_s = (const float*)d_in[base + 7];
            const float* dec_bn_b = (const float*)d_in[base + 8];

            const int Hs = S[l], Wsz = S[l], Cl = C[l];
            __hip_bfloat16* avg = ws + avg_off2[l];
            float* r = out + out_off[l];

            if (l == 0) {
                dim3 eg(100, B, 3);
                enc_tiled<64, 64, 16, 12, 16, false, false><<<eg, 256, 0, stream>>>(
                    feat, enc_w, enc_bn_s, enc_bn_b, enc_thr, enc_beta, avg, nullptr, Hs, Wsz, 10);
                dim3 dg(100, B, 2);
                dec_tiled<32, 16><<<dg, 256, 0, stream>>>(avg, dec_w, dec_bn_s, dec_bn_b, r, Cl, Hs, Wsz, 10);
            } else if (l == 1) {
                dim3 eg(25, B, 3);
                enc_tiled<128, 128, 16, 12, 16, false, false><<<eg, 256, 0, stream>>>(
                    feat, enc_w, enc_bn_s, enc_bn_b, enc_thr, enc_beta, avg, nullptr, Hs, Wsz, 5);
                dim3 dg(25, B, 4);
                dec_tiled<32, 16><<<dg, 256, 0, stream>>>(avg, dec_w, dec_bn_s, dec_bn_b, r, Cl, Hs, Wsz, 5);
            } else {
                if (split5) {
                    dim3 eg(25, B, 12);
                    enc_tiled<256, 64, 16, 12, 8, true, false><<<eg, 64, 0, stream>>>(
                        feat, enc_w, enc_bn_s, enc_bn_b, enc_thr, enc_beta, nullptr, partial5, Hs, Wsz, 5);
                    int total = B * 36 * Hs * Wsz;
                    combine_lif<4, false><<<(total + 255) / 256, 256, 0, stream>>>(
                        partial5, enc_bn_s, enc_bn_b, enc_thr, enc_beta, avg, Hs, Wsz, total);
                } else {
                    dim3 eg(25, B, 3);
                    enc_tiled<256, 256, 16, 12, 8, false, false><<<eg, 64, 0, stream>>>(
                        feat, enc_w, enc_bn_s, enc_bn_b, enc_thr, enc_beta, avg, nullptr, Hs, Wsz, 5);
                }
                dim3 dg(25, B, 16);
                dec_tiled<16, 8><<<dg, 64, 0, stream>>>(avg, dec_w, dec_bn_s, dec_bn_b, r, Cl, Hs, Wsz, 5);
            }
        }
    }
}

// Round 16
// 614.682 us; speedup vs baseline: 2.3561x; 1.0792x over previous
//
#include <hip/hip_runtime.h>
#include <hip/hip_bf16.h>

typedef __attribute__((ext_vector_type(8)))  short short8v;
typedef __attribute__((ext_vector_type(16))) float f32x16;
typedef __attribute__((ext_vector_type(4)))  int   int4v;

// ===========================================================================
// Encoder weight prepack for MFMA (split bf16 hi/lo).
// ===========================================================================
template<int CIN>
__global__ __launch_bounds__(256) void pack_we(
    const float* __restrict__ w, __hip_bfloat16* __restrict__ whi,
    __hip_bfloat16* __restrict__ wlo, int total)
{
    const int NCHUNK = CIN / 16;
    int idx = blockIdx.x * 256 + threadIdx.x;
    if (idx >= total) return;
    int m  = idx & 31;
    int h  = (idx >> 5) & 1;
    int s  = (idx >> 6) % 9;
    int c  = (idx / 576) % NCHUNK;
    int cg = idx / (576 * NCHUNK);
    int co = cg * 32 + m;
    unsigned short vh[8], vl[8];
    #pragma unroll
    for (int j = 0; j < 8; ++j) {
        int ci = c * 16 + h * 8 + j;
        float x = (co < 36) ? w[(long)co * CIN * 9 + ci * 9 + s] : 0.f;
        __hip_bfloat16 xh = __float2bfloat16(x);
        float rem = x - __bfloat162float(xh);
        __hip_bfloat16 xl = __float2bfloat16(rem);
        vh[j] = *(unsigned short*)&xh;
        vl[j] = *(unsigned short*)&xl;
    }
    *(int4v*)(whi + (long)idx * 8) = *(int4v*)vh;
    *(int4v*)(wlo + (long)idx * 8) = *(int4v*)vl;
}

// ===========================================================================
// feat_cl: fp32 NCHW -> channel-last bf16 hi/lo [p][CIN]. PXB px per block.
// ===========================================================================
template<int CIN, int PXB>
__global__ __launch_bounds__(256) void feat_cl(
    const float* __restrict__ f, __hip_bfloat16* __restrict__ fh,
    __hip_bfloat16* __restrict__ fl, int HW, int npx)
{
    __shared__ float t[CIN][PXB];
    const int p0 = blockIdx.x * PXB;

    for (int i = threadIdx.x; i < CIN * PXB; i += 256) {
        int ci = i / PXB, px = i % PXB;
        int p = p0 + px;
        float v = 0.f;
        if (p < npx) {
            int b = p / HW, r = p - b * HW;
            v = f[((long)b * CIN + ci) * HW + r];
        }
        t[ci][px] = v;
    }
    __syncthreads();

    for (int i = threadIdx.x; i < PXB * (CIN / 8); i += 256) {
        int px = i % PXB, oct = i / PXB;
        int p = p0 + px;
        if (p >= npx) continue;
        unsigned short vh[8], vl[8];
        #pragma unroll
        for (int j = 0; j < 8; ++j) {
            float v = t[oct * 8 + j][px];
            __hip_bfloat16 xh = __float2bfloat16(v);
            float rem = v - __bfloat162float(xh);
            __hip_bfloat16 xl = __float2bfloat16(rem);
            vh[j] = *(unsigned short*)&xh;
            vl[j] = *(unsigned short*)&xl;
        }
        *(int4v*)(fh + (long)p * CIN + oct * 8) = *(int4v*)vh;
        *(int4v*)(fl + (long)p * CIN + oct * 8) = *(int4v*)vl;
    }
}

// ===========================================================================
// MFMA encoder, CL-staged, coalesced epilogue (enc3/enc4).
// MFMA core in-situ verified R12-R15 (absmax 0.047).
// ===========================================================================
template<int CIN>
__global__ __launch_bounds__(256) void enc_mfma_cl(
    const __hip_bfloat16* __restrict__ fh,   // [npx][CIN] hi
    const __hip_bfloat16* __restrict__ fl,   // [npx][CIN] lo
    const __hip_bfloat16* __restrict__ whi,
    const __hip_bfloat16* __restrict__ wlo,
    const float* __restrict__ bn_s, const float* __restrict__ bn_b,
    const float* __restrict__ thr, const float* __restrict__ beta_raw,
    __hip_bfloat16* __restrict__ avg,        // [16][H][W][40]
    int H, int W, int tiles_x)
{
    const int NCHUNK = CIN / 16;
    __shared__ __align__(16) short sbuf[324 * 48];
    short* hi_t = sbuf;
    short* lo_t = sbuf + 324 * 24;

    const int tid = threadIdx.x;
    const int b   = blockIdx.y;
    const int tx0 = (blockIdx.x % tiles_x) * 16;
    const int ty0 = (blockIdx.x / tiles_x) * 16;

    const int lane = tid & 63;
    const int wv   = tid >> 6;
    const int h    = lane >> 5;
    const int n    = lane & 31;
    const int lx   = n & 15;
    const int ly0  = wv * 4 + (n >> 4);

    f32x16 acc[2][2];
    #pragma unroll
    for (int cg = 0; cg < 2; ++cg)
        #pragma unroll
        for (int pf = 0; pf < 2; ++pf)
            #pragma unroll
            for (int k = 0; k < 16; ++k) acc[cg][pf][k] = 0.f;

    const char* aph = (const char*)whi + h * 512 + n * 16;
    const char* apl = (const char*)wlo + h * 512 + n * 16;
    const long  cgstride = (long)NCHUNK * 9216;

    for (int c = 0; c < NCHUNK; ++c) {
        for (int i = tid; i < 648; i += 256) {
            int p   = i >> 1, oct = i & 1;
            int hy = p / 18, hx = p - hy * 18;
            int gy = ty0 + hy - 1, gx = tx0 + hx - 1;
            int4v vh = {0, 0, 0, 0}, vl = {0, 0, 0, 0};
            if (gy >= 0 && gy < H && gx >= 0 && gx < W) {
                long pp = ((long)(b * H + gy) * W + gx) * CIN + c * 16 + oct * 8;
                vh = *(const int4v*)(fh + pp);
                vl = *(const int4v*)(fl + pp);
            }
            *(int4v*)((char*)hi_t + p * 48 + oct * 16) = vh;
            *(int4v*)((char*)lo_t + p * 48 + oct * 16) = vl;
        }
        __syncthreads();

        const char* ahc = aph + (long)c * 9216;
        const char* alc = apl + (long)c * 9216;
        #pragma unroll
        for (int s = 0; s < 9; ++s) {
            const int dy = s / 3, dx = s % 3;
            const int p0 = (ly0 + dy) * 18 + (lx + dx);
            const int p1 = p0 + 36;
            short8v bh0 = *(const short8v*)((const char*)hi_t + p0 * 48 + h * 16);
            short8v bh1 = *(const short8v*)((const char*)hi_t + p1 * 48 + h * 16);
            short8v bl0 = *(const short8v*)((const char*)lo_t + p0 * 48 + h * 16);
            short8v bl1 = *(const short8v*)((const char*)lo_t + p1 * 48 + h * 16);
            #pragma unroll
            for (int cg = 0; cg < 2; ++cg) {
                short8v af = *(const short8v*)(ahc + cg * cgstride + s * 1024);
                short8v al = *(const short8v*)(alc + cg * cgstride + s * 1024);
                acc[cg][0] = __builtin_amdgcn_mfma_f32_32x32x16_bf16(af, bh0, acc[cg][0], 0, 0, 0);
                acc[cg][0] = __builtin_amdgcn_mfma_f32_32x32x16_bf16(af, bl0, acc[cg][0], 0, 0, 0);
                acc[cg][0] = __builtin_amdgcn_mfma_f32_32x32x16_bf16(al, bh0, acc[cg][0], 0, 0, 0);
                acc[cg][1] = __builtin_amdgcn_mfma_f32_32x32x16_bf16(af, bh1, acc[cg][1], 0, 0, 0);
                acc[cg][1] = __builtin_amdgcn_mfma_f32_32x32x16_bf16(af, bl1, acc[cg][1], 0, 0, 0);
                acc[cg][1] = __builtin_amdgcn_mfma_f32_32x32x16_bf16(al, bh1, acc[cg][1], 0, 0, 0);
            }
        }
        __syncthreads();
    }

    // ---- epilogue: LIF -> LDS transpose -> coalesced 16B stores ----
    for (int i = tid; i < 1280; i += 256)
        *(int4v*)((char*)sbuf + i * 16) = (int4v){0, 0, 0, 0};
    __syncthreads();

    #pragma unroll
    for (int cg = 0; cg < 2; ++cg) {
        #pragma unroll
        for (int r = 0; r < 16; ++r) {
            const int co = (cg << 5) + (r & 3) + ((r >> 2) << 3) + (h << 2);
            if (co < 36) {
                const float sc   = bn_s[co], sb = bn_b[co];
                const float beta = 1.f / (1.f + expf(-beta_raw[co]));
                const float t    = thr[co];
                #pragma unroll
                for (int pf = 0; pf < 2; ++pf) {
                    const int ly = ly0 + pf * 2;
                    float hv = acc[cg][pf][r] * sc + sb;
                    float m = 0.f, c2 = 0.f;
                    #pragma unroll
                    for (int s4 = 0; s4 < 4; ++s4) {
                        m = beta * m + hv;
                        if (m > t) { c2 += 1.f; m -= t; }
                    }
                    __hip_bfloat16 ov = __float2bfloat16(c2 * 0.25f);
                    sbuf[(ly * 16 + lx) * 40 + co] = *(short*)&ov;
                }
            }
        }
    }
    __syncthreads();

    const long tilebase = ((long)(b * H + ty0) * W + tx0) * 40;
    for (int i = tid; i < 1280; i += 256) {
        int px = i / 5, u = i - px * 5;
        int py2 = px >> 4, px2 = px & 15;
        *(int4v*)(avg + tilebase + ((long)py2 * W + px2) * 40 + u * 8) =
            *(const int4v*)(sbuf + px * 40 + u * 8);
    }
}

// ===========================================================================
// MFMA encoder, ci-split partial variant (enc5): each block handles CIPER
// of CIN channels (blockIdx.z = cis), writes raw fp32 conv sums to partial
// [cis][b][co][y][x]; combine_lif<4,true> sums + LIF -> avg_cl.
// MFMA core identical to enc_mfma_cl (verified).
// ===========================================================================
template<int CIN, int CIPER>
__global__ __launch_bounds__(256) void enc_mfma_p(
    const __hip_bfloat16* __restrict__ fh,
    const __hip_bfloat16* __restrict__ fl,
    const __hip_bfloat16* __restrict__ whi,
    const __hip_bfloat16* __restrict__ wlo,
    float* __restrict__ partial,
    int H, int W, int tiles_x)
{
    const int NCH_TOT = CIN / 16;
    const int NCH_PER = CIPER / 16;
    __shared__ __align__(16) short sbuf[324 * 48];
    short* hi_t = sbuf;
    short* lo_t = sbuf + 324 * 24;

    const int tid = threadIdx.x;
    const int b   = blockIdx.y;
    const int cis = blockIdx.z;
    const int tx0 = (blockIdx.x % tiles_x) * 16;
    const int ty0 = (blockIdx.x / tiles_x) * 16;

    const int lane = tid & 63;
    const int wv   = tid >> 6;
    const int h    = lane >> 5;
    const int n    = lane & 31;
    const int lx   = n & 15;
    const int ly0  = wv * 4 + (n >> 4);

    f32x16 acc[2][2];
    #pragma unroll
    for (int cg = 0; cg < 2; ++cg)
        #pragma unroll
        for (int pf = 0; pf < 2; ++pf)
            #pragma unroll
            for (int k = 0; k < 16; ++k) acc[cg][pf][k] = 0.f;

    const char* aph = (const char*)whi + h * 512 + n * 16;
    const char* apl = (const char*)wlo + h * 512 + n * 16;
    const long  cgstride = (long)NCH_TOT * 9216;

    for (int c = 0; c < NCH_PER; ++c) {
        const int gc = cis * NCH_PER + c;
        for (int i = tid; i < 648; i += 256) {
            int p   = i >> 1, oct = i & 1;
            int hy = p / 18, hx = p - hy * 18;
            int gy = ty0 + hy - 1, gx = tx0 + hx - 1;
            int4v vh = {0, 0, 0, 0}, vl = {0, 0, 0, 0};
            if (gy >= 0 && gy < H && gx >= 0 && gx < W) {
                long pp = ((long)(b * H + gy) * W + gx) * CIN + gc * 16 + oct * 8;
                vh = *(const int4v*)(fh + pp);
                vl = *(const int4v*)(fl + pp);
            }
            *(int4v*)((char*)hi_t + p * 48 + oct * 16) = vh;
            *(int4v*)((char*)lo_t + p * 48 + oct * 16) = vl;
        }
        __syncthreads();

        const char* ahc = aph + (long)gc * 9216;
        const char* alc = apl + (long)gc * 9216;
        #pragma unroll
        for (int s = 0; s < 9; ++s) {
            const int dy = s / 3, dx = s % 3;
            const int p0 = (ly0 + dy) * 18 + (lx + dx);
            const int p1 = p0 + 36;
            short8v bh0 = *(const short8v*)((const char*)hi_t + p0 * 48 + h * 16);
            short8v bh1 = *(const short8v*)((const char*)hi_t + p1 * 48 + h * 16);
            short8v bl0 = *(const short8v*)((const char*)lo_t + p0 * 48 + h * 16);
            short8v bl1 = *(const short8v*)((const char*)lo_t + p1 * 48 + h * 16);
            #pragma unroll
            for (int cg = 0; cg < 2; ++cg) {
                short8v af = *(const short8v*)(ahc + cg * cgstride + s * 1024);
                short8v al = *(const short8v*)(alc + cg * cgstride + s * 1024);
                acc[cg][0] = __builtin_amdgcn_mfma_f32_32x32x16_bf16(af, bh0, acc[cg][0], 0, 0, 0);
                acc[cg][0] = __builtin_amdgcn_mfma_f32_32x32x16_bf16(af, bl0, acc[cg][0], 0, 0, 0);
                acc[cg][0] = __builtin_amdgcn_mfma_f32_32x32x16_bf16(al, bh0, acc[cg][0], 0, 0, 0);
                acc[cg][1] = __builtin_amdgcn_mfma_f32_32x32x16_bf16(af, bh1, acc[cg][1], 0, 0, 0);
                acc[cg][1] = __builtin_amdgcn_mfma_f32_32x32x16_bf16(af, bl1, acc[cg][1], 0, 0, 0);
                acc[cg][1] = __builtin_amdgcn_mfma_f32_32x32x16_bf16(al, bh1, acc[cg][1], 0, 0, 0);
            }
        }
        __syncthreads();
    }

    // ---- epilogue: raw fp32 partial stores (16-lane contiguous rows) ----
    const int HW = H * W;
    const long total = (long)16 * 36 * HW;
    #pragma unroll
    for (int cg = 0; cg < 2; ++cg) {
        #pragma unroll
        for (int r = 0; r < 16; ++r) {
            const int co = (cg << 5) + (r & 3) + ((r >> 2) << 3) + (h << 2);
            if (co < 36) {
                #pragma unroll
                for (int pf = 0; pf < 2; ++pf) {
                    const int gy = ty0 + ly0 + pf * 2, gx = tx0 + lx;
                    if (gy < H && gx < W)
                        partial[(long)cis * total + ((long)(b * 36 + co) * HW + gy * W + gx)]
                            = acc[cg][pf][r];
                }
            }
        }
    }
}

// ===========================================================================
// Original encoder (enc5 fallback + small-ws fallback path).
// ===========================================================================
template<int CIN, int CIPER, int CICHUNK, int COCHUNK, int TDIM, bool PARTIAL, bool CL>
__global__ __launch_bounds__(TDIM* TDIM) void enc_tiled(
    const float* __restrict__ feat,
    const float* __restrict__ w,
    const float* __restrict__ bn_s, const float* __restrict__ bn_b,
    const float* __restrict__ thr, const float* __restrict__ beta_raw,
    __hip_bfloat16* __restrict__ avg,
    float* __restrict__ partial,
    int H, int W, int tiles_x)
{
    const int TPB  = TDIM * TDIM;
    const int HALOD = TDIM + 2;
    const int NCO  = 36 / COCHUNK;
    __shared__ float fs[CICHUNK][HALOD][HALOD];

    const int tile = blockIdx.x;
    const int b    = blockIdx.y;
    const int coc  = blockIdx.z % NCO;
    const int cis  = blockIdx.z / NCO;
    const int co0  = coc * COCHUNK;
    const int tx0  = (tile % tiles_x) * TDIM;
    const int ty0  = (tile / tiles_x) * TDIM;

    const int tx = threadIdx.x % TDIM;
    const int ty = threadIdx.x / TDIM;
    const int ox = tx0 + tx, oy = ty0 + ty;

    float acc[COCHUNK];
    #pragma unroll
    for (int c = 0; c < COCHUNK; ++c) acc[c] = 0.f;

    const float* fb = feat + (long)b * CIN * H * W;
    const int ci_base = cis * CIPER;

    for (int cc = ci_base; cc < ci_base + CIPER; cc += CICHUNK) {
        for (int i = threadIdx.x; i < CICHUNK * HALOD * HALOD; i += TPB) {
            int ci = i / (HALOD * HALOD);
            int r  = i % (HALOD * HALOD);
            int hy = r / HALOD, hx = r % HALOD;
            int gy = ty0 + hy - 1, gx = tx0 + hx - 1;
            float v = 0.f;
            if (gy >= 0 && gy < H && gx >= 0 && gx < W)
                v = fb[((long)(cc + ci) * H + gy) * W + gx];
            fs[ci][hy][hx] = v;
        }
        __syncthreads();

        for (int ci = 0; ci < CICHUNK; ++ci) {
            float f0 = fs[ci][ty    ][tx], f1 = fs[ci][ty    ][tx+1], f2 = fs[ci][ty    ][tx+2];
            float f3 = fs[ci][ty + 1][tx], f4 = fs[ci][ty + 1][tx+1], f5 = fs[ci][ty + 1][tx+2];
            float f6 = fs[ci][ty + 2][tx], f7 = fs[ci][ty + 2][tx+1], f8 = fs[ci][ty + 2][tx+2];
            const float* wq = w + (long)(cc + ci) * 9;
            #pragma unroll
            for (int j = 0; j < COCHUNK; ++j) {
                const float* ww = wq + (long)(co0 + j) * CIN * 9;
                acc[j] += f0 * ww[0] + f1 * ww[1] + f2 * ww[2]
                        + f3 * ww[3] + f4 * ww[4] + f5 * ww[5]
                        + f6 * ww[6] + f7 * ww[7] + f8 * ww[8];
            }
        }
        __syncthreads();
    }

    if (ox < W && oy < H) {
        if (PARTIAL) {
            #pragma unroll
            for (int j = 0; j < COCHUNK; ++j)
                partial[((((long)cis * 16 + b) * 36 + (co0 + j)) * H + oy) * W + ox] = acc[j];
        } else {
            float cnt[COCHUNK];
            #pragma unroll
            for (int j = 0; j < COCHUNK; ++j) {
                int co = co0 + j;
                float hh   = acc[j] * bn_s[co] + bn_b[co];
                float beta = 1.f / (1.f + expf(-beta_raw[co]));
                float t    = thr[co];
                float m = 0.f, c2 = 0.f;
                #pragma unroll
                for (int s = 0; s < 4; ++s) {
                    m = beta * m + hh;
                    if (m > t) { c2 += 1.f; m -= t; }
                }
                cnt[j] = c2 * 0.25f;
            }
            if (CL) {
                unsigned* dp = (unsigned*)(avg + ((long)(b * H + oy) * W + ox) * 40 + co0);
                #pragma unroll
                for (int j2 = 0; j2 < COCHUNK / 2; ++j2) {
                    __hip_bfloat16 h0 = __float2bfloat16(cnt[2 * j2]);
                    __hip_bfloat16 h1 = __float2bfloat16(cnt[2 * j2 + 1]);
                    unsigned u0 = *(unsigned short*)&h0;
                    unsigned u1 = *(unsigned short*)&h1;
                    dp[j2] = u0 | (u1 << 16);
                }
            } else {
                #pragma unroll
                for (int j = 0; j < COCHUNK; ++j)
                    avg[(((long)b * 36 + (co0 + j)) * H + oy) * W + ox] = __float2bfloat16(cnt[j]);
            }
        }
    }
}

// ===========================================================================
// Combine ci-split partials + BN + LIF + mean -> bf16 avg (CL or NCHW).
// ===========================================================================
template<int SPLITS, bool CL>
__global__ __launch_bounds__(256) void combine_lif(
    const float* __restrict__ partial,
    const float* __restrict__ bn_s, const float* __restrict__ bn_b,
    const float* __restrict__ thr, const float* __restrict__ beta_raw,
    __hip_bfloat16* __restrict__ avg, int H, int W, int total)
{
    int idx = blockIdx.x * 256 + threadIdx.x;
    if (idx >= total) return;
    int HW = H * W;
    int co = (idx / HW) % 36;
    float hh = 0.f;
    #pragma unroll
    for (int s = 0; s < SPLITS; ++s) hh += partial[(long)s * total + idx];
    hh = hh * bn_s[co] + bn_b[co];
    float beta = 1.f / (1.f + expf(-beta_raw[co]));
    float t    = thr[co];
    float m = 0.f, cnt = 0.f;
    #pragma unroll
    for (int s = 0; s < 4; ++s) {
        m = beta * m + hh;
        if (m > t) { cnt += 1.f; m -= t; }
    }
    if (CL) {
        int b = idx / (36 * HW);
        int rem = idx % HW;
        int y = rem / W, x = rem % W;
        avg[((long)(b * H + y) * W + x) * 40 + co] = __float2bfloat16(cnt * 0.25f);
    } else {
        avg[idx] = __float2bfloat16(cnt * 0.25f);
    }
}

// ===========================================================================
// Weight prepack for MFMA decoder.
// ===========================================================================
__global__ __launch_bounds__(256) void pack_w(
    const float* __restrict__ w, __hip_bfloat16* __restrict__ ap, int total)
{
    int idx = blockIdx.x * 256 + threadIdx.x;
    if (idx >= total) return;
    int m  = idx & 31;
    int h  = (idx >> 5) & 1;
    int s  = (idx >> 6) % 23;
    int cg = idx / (23 * 64);
    int o  = 2 * s + h;
    int co = cg * 32 + m;
    unsigned short v[8];
    #pragma unroll
    for (int j = 0; j < 8; ++j) {
        float x = 0.f;
        if (o < 45) {
            int tap = o / 5, oct = o % 5, ci = oct * 8 + j;
            if (ci < 36) x = w[(long)co * 324 + ci * 9 + tap];
        }
        __hip_bfloat16 hv = __float2bfloat16(x);
        v[j] = *(unsigned short*)&hv;
    }
    *(int4v*)(ap + (long)idx * 8) = *(int4v*)v;
}

// ===========================================================================
// MFMA decoder: conv3x3(36->Cout) + BN + SiLU.
// ===========================================================================
template<int COG>
__global__ __launch_bounds__(256) void dec_mfma(
    const __hip_bfloat16* __restrict__ avg_cl,
    const __hip_bfloat16* __restrict__ apack,
    const float* __restrict__ bn_s, const float* __restrict__ bn_b,
    float* __restrict__ out, int Cout, int H, int W, int tiles_x)
{
    __shared__ __hip_bfloat16 tile[12960];

    const int tid    = threadIdx.x;
    const int b      = blockIdx.y;
    const int cgbase = blockIdx.z * COG;
    const int tx0 = (blockIdx.x % tiles_x) * 16;
    const int ty0 = (blockIdx.x / tiles_x) * 16;

    {
        const __hip_bfloat16* ab = avg_cl + (long)b * H * W * 40;
        for (int i = tid; i < 1620; i += 256) {
            int row = i / 90, u = i - row * 90;
            int px = u / 5, un = u - px * 5;
            int gy = ty0 + row - 1, gx = tx0 + px - 1;
            int4v v = {0, 0, 0, 0};
            if (gy >= 0 && gy < H && gx >= 0 && gx < W)
                v = *(const int4v*)(ab + ((long)gy * W + gx) * 40 + un * 8);
            *(int4v*)(tile + (row * 18 + px) * 40 + un * 8) = v;
        }
    }
    __syncthreads();

    const int lane = tid & 63;
    const int wv   = tid >> 6;
    const int h    = lane >> 5;
    const int n    = lane & 31;
    const int lx   = n & 15;
    const int ly0  = wv * 4 + (n >> 4);

    const char* tb  = (const char*)tile;
    const int   bb0 = ((ly0 + 1) * 18 + (lx + 1)) * 80;
    const int   bb1 = bb0 + 2 * 18 * 80;

    const char* ap = (const char*)apack + (long)cgbase * 23552 + h * 512 + n * 16;

    f32x16 acc[COG][2];
    #pragma unroll
    for (int cg = 0; cg < COG; ++cg)
        #pragma unroll
        for (int pf = 0; pf < 2; ++pf)
            #pragma unroll
            for (int k = 0; k < 16; ++k) acc[cg][pf][k] = 0.f;

    #pragma unroll
    for (int s = 0; s < 23; ++s) {
        int o0 = 2 * s;     if (o0 > 44) o0 = 44;
        int o1 = 2 * s + 1; if (o1 > 44) o1 = 44;
        const int C0 = ((o0 / 5) / 3 - 1) * 1440 + ((o0 / 5) % 3 - 1) * 80 + (o0 % 5) * 16;
        const int C1 = ((o1 / 5) / 3 - 1) * 1440 + ((o1 / 5) % 3 - 1) * 80 + (o1 % 5) * 16;
        const int offc = h ? C1 : C0;
        short8v bf0 = *(const short8v*)(tb + (bb0 + offc));
        short8v bf1 = *(const short8v*)(tb + (bb1 + offc));
        #pragma unroll
        for (int cg = 0; cg < COG; ++cg) {
            short8v af = *(const short8v*)(ap + cg * 23552 + s * 1024);
            acc[cg][0] = __builtin_amdgcn_mfma_f32_32x32x16_bf16(af, bf0, acc[cg][0], 0, 0, 0);
            acc[cg][1] = __builtin_amdgcn_mfma_f32_32x32x16_bf16(af, bf1, acc[cg][1], 0, 0, 0);
        }
    }

    #pragma unroll
    for (int cg = 0; cg < COG; ++cg) {
        #pragma unroll
        for (int r = 0; r < 16; ++r) {
            const int co = ((cgbase + cg) << 5) + (r & 3) + ((r >> 2) << 3) + (h << 2);
            const float sc = bn_s[co], bc = bn_b[co];
            #pragma unroll
            for (int pf = 0; pf < 2; ++pf) {
                const int ly = ly0 + pf * 2;
                const int gy = ty0 + ly, gx = tx0 + lx;
                float v = acc[cg][pf][r] * sc + bc;
                v = v / (1.f + __expf(-v));
                if (gy < H && gx < W)
                    out[(((long)b * Cout + co) * H + gy) * W + gx] = v;
            }
        }
    }
}

// ===========================================================================
// Fallback decoder (VALU, NCHW avg).
// ===========================================================================
template<int COCHUNK, int TDIM>
__global__ __launch_bounds__(TDIM* TDIM) void dec_tiled(
    const __hip_bfloat16* __restrict__ avg,
    const float* __restrict__ w,
    const float* __restrict__ bn_s, const float* __restrict__ bn_b,
    float* __restrict__ out,
    int Cout, int H, int W, int tiles_x)
{
    const int CIN = 36;
    const int TPB = TDIM * TDIM;
    const int HALOD = TDIM + 2;
    __shared__ float fs[CIN][HALOD][HALOD];

    const int tile = blockIdx.x;
    const int b    = blockIdx.y;
    const int co0  = blockIdx.z * COCHUNK;
    const int tx0  = (tile % tiles_x) * TDIM;
    const int ty0  = (tile / tiles_x) * TDIM;

    const int tx = threadIdx.x % TDIM;
    const int ty = threadIdx.x / TDIM;
    const int ox = tx0 + tx, oy = ty0 + ty;

    const __hip_bfloat16* ab = avg + (long)b * CIN * H * W;

    for (int i = threadIdx.x; i < CIN * HALOD * HALOD; i += TPB) {
        int ci = i / (HALOD * HALOD);
        int r  = i % (HALOD * HALOD);
        int hy = r / HALOD, hx = r % HALOD;
        int gy = ty0 + hy - 1, gx = tx0 + hx - 1;
        float v = 0.f;
        if (gy >= 0 && gy < H && gx >= 0 && gx < W)
            v = __bfloat162float(ab[((long)ci * H + gy) * W + gx]);
        fs[ci][hy][hx] = v;
    }
    __syncthreads();

    float acc[COCHUNK];
    #pragma unroll
    for (int j = 0; j < COCHUNK; ++j) acc[j] = 0.f;

    for (int ci = 0; ci < CIN; ++ci) {
        float f0 = fs[ci][ty    ][tx], f1 = fs[ci][ty    ][tx+1], f2 = fs[ci][ty    ][tx+2];
        float f3 = fs[ci][ty + 1][tx], f4 = fs[ci][ty + 1][tx+1], f5 = fs[ci][ty + 1][tx+2];
        float f6 = fs[ci][ty + 2][tx], f7 = fs[ci][ty + 2][tx+1], f8 = fs[ci][ty + 2][tx+2];
        #pragma unroll
        for (int j = 0; j < COCHUNK; ++j) {
            const float* ww = w + ((long)(co0 + j) * CIN + ci) * 9;
            acc[j] += f0 * ww[0] + f1 * ww[1] + f2 * ww[2]
                    + f3 * ww[3] + f4 * ww[4] + f5 * ww[5]
                    + f6 * ww[6] + f7 * ww[7] + f8 * ww[8];
        }
    }

    if (ox < W && oy < H) {
        #pragma unroll
        for (int j = 0; j < COCHUNK; ++j) {
            int co = co0 + j;
            float v = acc[j] * bn_s[co] + bn_b[co];
            out[(((long)b * Cout + co) * H + oy) * W + ox] = v / (1.f + expf(-v));
        }
    }
}

// ===========================================================================
extern "C" void kernel_launch(void* const* d_in, const int* in_sizes, int n_in,
                              void* d_out, int out_size, void* d_ws, size_t ws_size,
                              hipStream_t stream)
{
    const int B = 16;
    const int C[3] = {64, 128, 256};
    const int S[3] = {160, 80, 40};

    float* out = (float*)d_out;
    long out_off[3]; long off = 0;
    for (int l = 0; l < 3; ++l) { out_off[l] = off; off += (long)B * C[l] * S[l] * S[l]; }

    // ---- workspace layout (bytes) ----
    const long avgcl_bytes[3] = {32768000L, 8192000L, 2048000L};
    long avgcl_off[3]; long boff = 0;
    for (int l = 0; l < 3; ++l) { avgcl_off[l] = boff; boff += avgcl_bytes[l]; }
    const long avgcl_total = boff;
    const long ap_bytes[3] = {47104L, 94208L, 188416L};
    long ap_off[3];
    for (int l = 0; l < 3; ++l) { ap_off[l] = boff; boff += ap_bytes[l]; }
    const long we_bytes[3] = {73728L, 147456L, 294912L};
    long wehi_off[3], welo_off[3];
    for (int l = 0; l < 3; ++l) { wehi_off[l] = boff; boff += we_bytes[l];
                                  welo_off[l] = boff; boff += we_bytes[l]; }
    const long part5_off = boff;
    const long part5_bytes = 4L * B * 36 * 1600 * 4;
    boff += part5_bytes;
    const size_t need_full = (size_t)boff;
    const size_t need_min  = (size_t)part5_off;
    const long fcl_bytes[3] = {52428800L, 26214400L, 13107200L};
    long fclhi_off[3], fcllo_off[3];
    for (int l = 0; l < 2; ++l) { fclhi_off[l] = boff; boff += fcl_bytes[l];
                                  fcllo_off[l] = boff; boff += fcl_bytes[l]; }
    const size_t need_cl = (size_t)boff;
    fclhi_off[2] = boff; boff += fcl_bytes[2];
    fcllo_off[2] = boff; boff += fcl_bytes[2];
    const size_t need_cl5 = (size_t)boff;

    char* wsb = (char*)d_ws;

    if (ws_size >= need_min) {
        const bool split5  = ws_size >= need_full;
        const bool use_cl  = ws_size >= need_cl;
        const bool use_cl5 = ws_size >= need_cl5;
        hipMemsetAsync(wsb, 0, avgcl_total, stream);

        for (int l = 0; l < 3; ++l) {
            const float* dec_w = (const float*)d_in[9 * l + 6];
            int total = (C[l] / 32) * 23 * 2 * 32;
            pack_w<<<(total + 255) / 256, 256, 0, stream>>>(
                dec_w, (__hip_bfloat16*)(wsb + ap_off[l]), total);
        }
        {
            const float* enc_w3 = (const float*)d_in[1];
            int total = 2 * (64 / 16) * 9 * 2 * 32;
            pack_we<64><<<(total + 255) / 256, 256, 0, stream>>>(
                enc_w3, (__hip_bfloat16*)(wsb + wehi_off[0]),
                (__hip_bfloat16*)(wsb + welo_off[0]), total);
        }
        {
            const float* enc_w4 = (const float*)d_in[10];
            int total = 2 * (128 / 16) * 9 * 2 * 32;
            pack_we<128><<<(total + 255) / 256, 256, 0, stream>>>(
                enc_w4, (__hip_bfloat16*)(wsb + wehi_off[1]),
                (__hip_bfloat16*)(wsb + welo_off[1]), total);
        }
        if (use_cl5) {
            const float* enc_w5 = (const float*)d_in[19];
            int total = 2 * (256 / 16) * 9 * 2 * 32;
            pack_we<256><<<(total + 255) / 256, 256, 0, stream>>>(
                enc_w5, (__hip_bfloat16*)(wsb + wehi_off[2]),
                (__hip_bfloat16*)(wsb + welo_off[2]), total);
        }
        if (use_cl) {
            {
                int HW = 160 * 160, npx = B * HW;
                feat_cl<64, 64><<<(npx + 63) / 64, 256, 0, stream>>>(
                    (const float*)d_in[0], (__hip_bfloat16*)(wsb + fclhi_off[0]),
                    (__hip_bfloat16*)(wsb + fcllo_off[0]), HW, npx);
            }
            {
                int HW = 80 * 80, npx = B * HW;
                feat_cl<128, 64><<<(npx + 63) / 64, 256, 0, stream>>>(
                    (const float*)d_in[9], (__hip_bfloat16*)(wsb + fclhi_off[1]),
                    (__hip_bfloat16*)(wsb + fcllo_off[1]), HW, npx);
            }
        }
        if (use_cl5) {
            int HW = 40 * 40, npx = B * HW;
            feat_cl<256, 32><<<(npx + 31) / 32, 256, 0, stream>>>(
                (const float*)d_in[18], (__hip_bfloat16*)(wsb + fclhi_off[2]),
                (__hip_bfloat16*)(wsb + fcllo_off[2]), HW, npx);
        }

        for (int l = 0; l < 3; ++l) {
            const int base = 9 * l;
            const float* feat     = (const float*)d_in[base + 0];
            const float* enc_w    = (const float*)d_in[base + 1];
            const float* enc_bn_s = (const float*)d_in[base + 2];
            const float* enc_bn_b = (const float*)d_in[base + 3];
            const float* enc_thr  = (const float*)d_in[base + 4];
            const float* enc_beta = (const float*)d_in[base + 5];
            const float* dec_bn_s = (const float*)d_in[base + 7];
            const float* dec_bn_b = (const float*)d_in[base + 8];

            const int Hs = S[l], Wsz = S[l];
            __hip_bfloat16* avg_cl = (__hip_bfloat16*)(wsb + avgcl_off[l]);
            const __hip_bfloat16* ap = (const __hip_bfloat16*)(wsb + ap_off[l]);
            float* r = out + out_off[l];

            if (l == 0) {
                dim3 eg(100, B);
                if (use_cl)
                    enc_mfma_cl<64><<<eg, 256, 0, stream>>>(
                        (const __hip_bfloat16*)(wsb + fclhi_off[0]),
                        (const __hip_bfloat16*)(wsb + fcllo_off[0]),
                        (const __hip_bfloat16*)(wsb + wehi_off[0]),
                        (const __hip_bfloat16*)(wsb + welo_off[0]),
                        enc_bn_s, enc_bn_b, enc_thr, enc_beta, avg_cl, Hs, Wsz, 10);
                else
                    enc_tiled<64, 64, 16, 12, 16, false, true><<<dim3(100, B, 3), 256, 0, stream>>>(
                        feat, enc_w, enc_bn_s, enc_bn_b, enc_thr, enc_beta, avg_cl, nullptr, Hs, Wsz, 10);
                dim3 dg(100, B, 1);
                dec_mfma<2><<<dg, 256, 0, stream>>>(avg_cl, ap, dec_bn_s, dec_bn_b, r, 64, Hs, Wsz, 10);
            } else if (l == 1) {
                dim3 eg(25, B);
                if (use_cl)
                    enc_mfma_cl<128><<<eg, 256, 0, stream>>>(
                        (const __hip_bfloat16*)(wsb + fclhi_off[1]),
                        (const __hip_bfloat16*)(wsb + fcllo_off[1]),
                        (const __hip_bfloat16*)(wsb + wehi_off[1]),
                        (const __hip_bfloat16*)(wsb + welo_off[1]),
                        enc_bn_s, enc_bn_b, enc_thr, enc_beta, avg_cl, Hs, Wsz, 5);
                else
                    enc_tiled<128, 128, 16, 12, 16, false, true><<<dim3(25, B, 3), 256, 0, stream>>>(
                        feat, enc_w, enc_bn_s, enc_bn_b, enc_thr, enc_beta, avg_cl, nullptr, Hs, Wsz, 5);
                dim3 dg(25, B, 2);
                dec_mfma<2><<<dg, 256, 0, stream>>>(avg_cl, ap, dec_bn_s, dec_bn_b, r, 128, Hs, Wsz, 5);
            } else {
                if (use_cl5) {
                    float* partial5 = (float*)(wsb + part5_off);
                    dim3 eg(9, B, 4);   // 3x3 masked tiles x 4 ci-splits
                    enc_mfma_p<256, 64><<<eg, 256, 0, stream>>>(
                        (const __hip_bfloat16*)(wsb + fclhi_off[2]),
                        (const __hip_bfloat16*)(wsb + fcllo_off[2]),
                        (const __hip_bfloat16*)(wsb + wehi_off[2]),
                        (const __hip_bfloat16*)(wsb + welo_off[2]),
                        partial5, Hs, Wsz, 3);
                    int total = B * 36 * Hs * Wsz;
                    combine_lif<4, true><<<(total + 255) / 256, 256, 0, stream>>>(
                        partial5, enc_bn_s, enc_bn_b, enc_thr, enc_beta, avg_cl, Hs, Wsz, total);
                } else if (split5) {
                    float* partial5 = (float*)(wsb + part5_off);
                    dim3 eg(25, B, 12);
                    enc_tiled<256, 64, 16, 12, 8, true, true><<<eg, 64, 0, stream>>>(
                        feat, enc_w, enc_bn_s, enc_bn_b, enc_thr, enc_beta, nullptr, partial5, Hs, Wsz, 5);
                    int total = B * 36 * Hs * Wsz;
                    combine_lif<4, true><<<(total + 255) / 256, 256, 0, stream>>>(
                        partial5, enc_bn_s, enc_bn_b, enc_thr, enc_beta, avg_cl, Hs, Wsz, total);
                } else {
                    dim3 eg(25, B, 3);
                    enc_tiled<256, 256, 16, 12, 8, false, true><<<eg, 64, 0, stream>>>(
                        feat, enc_w, enc_bn_s, enc_bn_b, enc_thr, enc_beta, avg_cl, nullptr, Hs, Wsz, 5);
                }
                dim3 dg(9, B, 4);
                dec_mfma<2><<<dg, 256, 0, stream>>>(avg_cl, ap, dec_bn_s, dec_bn_b, r, 256, Hs, Wsz, 3);
            }
        }
    } else {
        // ================= FALLBACK (NCHW, VALU decoder) =================
        __hip_bfloat16* ws = (__hip_bfloat16*)d_ws;
        long avg_off2[3]; long eoff = 0;
        for (int l = 0; l < 3; ++l) { avg_off2[l] = eoff; eoff += (long)B * 36 * S[l] * S[l]; }
        float* partial5 = (float*)(ws + ((eoff + 7) & ~7L));
        const long part5f = 4L * B * 36 * 40 * 40;
        const size_t old_need = (size_t)((eoff + 7) & ~7L) * 2 + part5f * 4;
        const bool split5 = ws_size >= old_need;

        for (int l = 0; l < 3; ++l) {
            const int base = 9 * l;
            const float* feat     = (const float*)d_in[base + 0];
            const float* enc_w    = (const float*)d_in[base + 1];
            const float* enc_bn_s = (const float*)d_in[base + 2];
            const float* enc_bn_b = (const float*)d_in[base + 3];
            const float* enc_thr  = (const float*)d_in[base + 4];
            const float* enc_beta = (const float*)d_in[base + 5];
            const float* dec_w    = (const float*)d_in[base + 6];
            const float* dec_bn_s = (const float*)d_in[base + 7];
            const float* dec_bn_b = (const float*)d_in[base + 8];

            const int Hs = S[l], Wsz = S[l], Cl = C[l];
            __hip_bfloat16* avg = ws + avg_off2[l];
            float* r = out + out_off[l];

            if (l == 0) {
                dim3 eg(100, B, 3);
                enc_tiled<64, 64, 16, 12, 16, false, false><<<eg, 256, 0, stream>>>(
                    feat, enc_w, enc_bn_s, enc_bn_b, enc_thr, enc_beta, avg, nullptr, Hs, Wsz, 10);
                dim3 dg(100, B, 2);
                dec_tiled<32, 16><<<dg, 256, 0, stream>>>(avg, dec_w, dec_bn_s, dec_bn_b, r, Cl, Hs, Wsz, 10);
            } else if (l == 1) {
                dim3 eg(25, B, 3);
                enc_tiled<128, 128, 16, 12, 16, false, false><<<eg, 256, 0, stream>>>(
                    feat, enc_w, enc_bn_s, enc_bn_b, enc_thr, enc_beta, avg, nullptr, Hs, Wsz, 5);
                dim3 dg(25, B, 4);
                dec_tiled<32, 16><<<dg, 256, 0, stream>>>(avg, dec_w, dec_bn_s, dec_bn_b, r, Cl, Hs, Wsz, 5);
            } else {
                if (split5) {
                    dim3 eg(25, B, 12);
                    enc_tiled<256, 64, 16, 12, 8, true, false><<<eg, 64, 0, stream>>>(
                        feat, enc_w, enc_bn_s, enc_bn_b, enc_thr, enc_beta, nullptr, partial5, Hs, Wsz, 5);
                    int total = B * 36 * Hs * Wsz;
                    combine_lif<4, false><<<(total + 255) / 256, 256, 0, stream>>>(
                        partial5, enc_bn_s, enc_bn_b, enc_thr, enc_beta, avg, Hs, Wsz, total);
                } else {
                    dim3 eg(25, B, 3);
                    enc_tiled<256, 256, 16, 12, 8, false, false><<<eg, 64, 0, stream>>>(
                        feat, enc_w, enc_bn_s, enc_bn_b, enc_thr, enc_beta, avg, nullptr, Hs, Wsz, 5);
                }
                dim3 dg(25, B, 16);
                dec_tiled<16, 8><<<dg, 64, 0, stream>>>(avg, dec_w, dec_bn_s, dec_bn_b, r, Cl, Hs, Wsz, 5);
            }
        }
    }
}

// Round 17
// 581.783 us; speedup vs baseline: 2.4894x; 1.0565x over previous
//
#include <hip/hip_runtime.h>
#include <hip/hip_bf16.h>

typedef __attribute__((ext_vector_type(8)))  short short8v;
typedef __attribute__((ext_vector_type(16))) float f32x16;
typedef __attribute__((ext_vector_type(4)))  int   int4v;

// ===========================================================================
// Encoder weight prepack for MFMA (split bf16 hi/lo).
// ===========================================================================
template<int CIN>
__global__ __launch_bounds__(256) void pack_we(
    const float* __restrict__ w, __hip_bfloat16* __restrict__ whi,
    __hip_bfloat16* __restrict__ wlo, int total)
{
    const int NCHUNK = CIN / 16;
    int idx = blockIdx.x * 256 + threadIdx.x;
    if (idx >= total) return;
    int m  = idx & 31;
    int h  = (idx >> 5) & 1;
    int s  = (idx >> 6) % 9;
    int c  = (idx / 576) % NCHUNK;
    int cg = idx / (576 * NCHUNK);
    int co = cg * 32 + m;
    unsigned short vh[8], vl[8];
    #pragma unroll
    for (int j = 0; j < 8; ++j) {
        int ci = c * 16 + h * 8 + j;
        float x = (co < 36) ? w[(long)co * CIN * 9 + ci * 9 + s] : 0.f;
        __hip_bfloat16 xh = __float2bfloat16(x);
        float rem = x - __bfloat162float(xh);
        __hip_bfloat16 xl = __float2bfloat16(rem);
        vh[j] = *(unsigned short*)&xh;
        vl[j] = *(unsigned short*)&xl;
    }
    *(int4v*)(whi + (long)idx * 8) = *(int4v*)vh;
    *(int4v*)(wlo + (long)idx * 8) = *(int4v*)vl;
}

// ===========================================================================
// feat_hl: fp32 NCHW -> chunk-major interleaved bf16 hi/lo:
//   fhl[((chunk * npx) + p) * 32 + q*8],  q = {hi0-7, hi8-15, lo0-7, lo8-15}
// 64B per (px,chunk); staging reads become fully contiguous (no strided
// cache-line amplification — R16's 1.85x FETCH overshoot).
// ===========================================================================
template<int CIN, int PXB>
__global__ __launch_bounds__(256) void feat_hl(
    const float* __restrict__ f, __hip_bfloat16* __restrict__ fhl,
    int HW, int npx)
{
    const int NCHUNK = CIN / 16;
    __shared__ float t[CIN][PXB];
    const int p0 = blockIdx.x * PXB;

    for (int i = threadIdx.x; i < CIN * PXB; i += 256) {
        int ci = i / PXB, px = i % PXB;
        int p = p0 + px;
        float v = 0.f;
        if (p < npx) {
            int b = p / HW, r = p - b * HW;
            v = f[((long)b * CIN + ci) * HW + r];
        }
        t[ci][px] = v;
    }
    __syncthreads();

    // q-fastest ordering: 4 consecutive 16B writes per px -> 64B coalesced
    for (int i = threadIdx.x; i < PXB * NCHUNK * 4; i += 256) {
        int q  = i & 3;
        int px = (i >> 2) % PXB;
        int c  = i / (4 * PXB);
        int p = p0 + px;
        if (p >= npx) continue;
        const bool lo = (q >= 2);
        const int ch0 = c * 16 + (q & 1) * 8;
        unsigned short v[8];
        #pragma unroll
        for (int j = 0; j < 8; ++j) {
            float x = t[ch0 + j][px];
            __hip_bfloat16 xh = __float2bfloat16(x);
            if (lo) {
                float rem = x - __bfloat162float(xh);
                xh = __float2bfloat16(rem);
            }
            v[j] = *(unsigned short*)&xh;
        }
        *(int4v*)(fhl + ((long)c * npx + p) * 32 + q * 8) = *(int4v*)v;
    }
}

// ===========================================================================
// MFMA encoder, chunk-major-staged, coalesced epilogue (enc3/enc4).
// MFMA core + LDS layout in-situ verified R12-R16 (absmax 0.047).
// ===========================================================================
template<int CIN>
__global__ __launch_bounds__(256) void enc_mfma_cl(
    const __hip_bfloat16* __restrict__ fhl,  // [chunk][npx][32]
    const __hip_bfloat16* __restrict__ whi,
    const __hip_bfloat16* __restrict__ wlo,
    const float* __restrict__ bn_s, const float* __restrict__ bn_b,
    const float* __restrict__ thr, const float* __restrict__ beta_raw,
    __hip_bfloat16* __restrict__ avg,        // [16][H][W][40]
    int H, int W, int tiles_x)
{
    const int NCHUNK = CIN / 16;
    __shared__ __align__(16) short sbuf[324 * 48];
    short* hi_t = sbuf;
    short* lo_t = sbuf + 324 * 24;

    const int tid = threadIdx.x;
    const int b   = blockIdx.y;
    const int tx0 = (blockIdx.x % tiles_x) * 16;
    const int ty0 = (blockIdx.x / tiles_x) * 16;
    const long npx = (long)16 * H * W;

    const int lane = tid & 63;
    const int wv   = tid >> 6;
    const int h    = lane >> 5;
    const int n    = lane & 31;
    const int lx   = n & 15;
    const int ly0  = wv * 4 + (n >> 4);

    f32x16 acc[2][2];
    #pragma unroll
    for (int cg = 0; cg < 2; ++cg)
        #pragma unroll
        for (int pf = 0; pf < 2; ++pf)
            #pragma unroll
            for (int k = 0; k < 16; ++k) acc[cg][pf][k] = 0.f;

    const char* aph = (const char*)whi + h * 512 + n * 16;
    const char* apl = (const char*)wlo + h * 512 + n * 16;
    const long  cgstride = (long)NCHUNK * 9216;

    for (int c = 0; c < NCHUNK; ++c) {
        // ---- stage: contiguous 64B-per-px reads (q-fastest) ----
        for (int i = tid; i < 1296; i += 256) {
            int p = i >> 2, q = i & 3;
            int hy = p / 18, hx = p - hy * 18;
            int gy = ty0 + hy - 1, gx = tx0 + hx - 1;
            int4v v = {0, 0, 0, 0};
            if (gy >= 0 && gy < H && gx >= 0 && gx < W) {
                long pg = (long)(b * H + gy) * W + gx;
                v = *(const int4v*)(fhl + ((long)c * npx + pg) * 32 + q * 8);
            }
            char* dst = (q < 2) ? (char*)hi_t + p * 48 + q * 16
                                : (char*)lo_t + p * 48 + (q - 2) * 16;
            *(int4v*)dst = v;
        }
        __syncthreads();

        const char* ahc = aph + (long)c * 9216;
        const char* alc = apl + (long)c * 9216;
        #pragma unroll
        for (int s = 0; s < 9; ++s) {
            const int dy = s / 3, dx = s % 3;
            const int p0 = (ly0 + dy) * 18 + (lx + dx);
            const int p1 = p0 + 36;
            short8v bh0 = *(const short8v*)((const char*)hi_t + p0 * 48 + h * 16);
            short8v bh1 = *(const short8v*)((const char*)hi_t + p1 * 48 + h * 16);
            short8v bl0 = *(const short8v*)((const char*)lo_t + p0 * 48 + h * 16);
            short8v bl1 = *(const short8v*)((const char*)lo_t + p1 * 48 + h * 16);
            #pragma unroll
            for (int cg = 0; cg < 2; ++cg) {
                short8v af = *(const short8v*)(ahc + cg * cgstride + s * 1024);
                short8v al = *(const short8v*)(alc + cg * cgstride + s * 1024);
                acc[cg][0] = __builtin_amdgcn_mfma_f32_32x32x16_bf16(af, bh0, acc[cg][0], 0, 0, 0);
                acc[cg][0] = __builtin_amdgcn_mfma_f32_32x32x16_bf16(af, bl0, acc[cg][0], 0, 0, 0);
                acc[cg][0] = __builtin_amdgcn_mfma_f32_32x32x16_bf16(al, bh0, acc[cg][0], 0, 0, 0);
                acc[cg][1] = __builtin_amdgcn_mfma_f32_32x32x16_bf16(af, bh1, acc[cg][1], 0, 0, 0);
                acc[cg][1] = __builtin_amdgcn_mfma_f32_32x32x16_bf16(af, bl1, acc[cg][1], 0, 0, 0);
                acc[cg][1] = __builtin_amdgcn_mfma_f32_32x32x16_bf16(al, bh1, acc[cg][1], 0, 0, 0);
            }
        }
        __syncthreads();
    }

    // ---- epilogue: LIF -> LDS transpose -> coalesced 16B stores ----
    for (int i = tid; i < 1280; i += 256)
        *(int4v*)((char*)sbuf + i * 16) = (int4v){0, 0, 0, 0};
    __syncthreads();

    #pragma unroll
    for (int cg = 0; cg < 2; ++cg) {
        #pragma unroll
        for (int r = 0; r < 16; ++r) {
            const int co = (cg << 5) + (r & 3) + ((r >> 2) << 3) + (h << 2);
            if (co < 36) {
                const float sc   = bn_s[co], sb = bn_b[co];
                const float beta = 1.f / (1.f + expf(-beta_raw[co]));
                const float t    = thr[co];
                #pragma unroll
                for (int pf = 0; pf < 2; ++pf) {
                    const int ly = ly0 + pf * 2;
                    float hv = acc[cg][pf][r] * sc + sb;
                    float m = 0.f, c2 = 0.f;
                    #pragma unroll
                    for (int s4 = 0; s4 < 4; ++s4) {
                        m = beta * m + hv;
                        if (m > t) { c2 += 1.f; m -= t; }
                    }
                    __hip_bfloat16 ov = __float2bfloat16(c2 * 0.25f);
                    sbuf[(ly * 16 + lx) * 40 + co] = *(short*)&ov;
                }
            }
        }
    }
    __syncthreads();

    const long tilebase = ((long)(b * H + ty0) * W + tx0) * 40;
    for (int i = tid; i < 1280; i += 256) {
        int px = i / 5, u = i - px * 5;
        int py2 = px >> 4, px2 = px & 15;
        *(int4v*)(avg + tilebase + ((long)py2 * W + px2) * 40 + u * 8) =
            *(const int4v*)(sbuf + px * 40 + u * 8);
    }
}

// ===========================================================================
// MFMA encoder, ci-split partial variant (enc5). Same chunk-major staging.
// ===========================================================================
template<int CIN, int CIPER>
__global__ __launch_bounds__(256) void enc_mfma_p(
    const __hip_bfloat16* __restrict__ fhl,
    const __hip_bfloat16* __restrict__ whi,
    const __hip_bfloat16* __restrict__ wlo,
    float* __restrict__ partial,
    int H, int W, int tiles_x)
{
    const int NCH_TOT = CIN / 16;
    const int NCH_PER = CIPER / 16;
    __shared__ __align__(16) short sbuf[324 * 48];
    short* hi_t = sbuf;
    short* lo_t = sbuf + 324 * 24;

    const int tid = threadIdx.x;
    const int b   = blockIdx.y;
    const int cis = blockIdx.z;
    const int tx0 = (blockIdx.x % tiles_x) * 16;
    const int ty0 = (blockIdx.x / tiles_x) * 16;
    const long npx = (long)16 * H * W;

    const int lane = tid & 63;
    const int wv   = tid >> 6;
    const int h    = lane >> 5;
    const int n    = lane & 31;
    const int lx   = n & 15;
    const int ly0  = wv * 4 + (n >> 4);

    f32x16 acc[2][2];
    #pragma unroll
    for (int cg = 0; cg < 2; ++cg)
        #pragma unroll
        for (int pf = 0; pf < 2; ++pf)
            #pragma unroll
            for (int k = 0; k < 16; ++k) acc[cg][pf][k] = 0.f;

    const char* aph = (const char*)whi + h * 512 + n * 16;
    const char* apl = (const char*)wlo + h * 512 + n * 16;
    const long  cgstride = (long)NCH_TOT * 9216;

    for (int c = 0; c < NCH_PER; ++c) {
        const int gc = cis * NCH_PER + c;
        for (int i = tid; i < 1296; i += 256) {
            int p = i >> 2, q = i & 3;
            int hy = p / 18, hx = p - hy * 18;
            int gy = ty0 + hy - 1, gx = tx0 + hx - 1;
            int4v v = {0, 0, 0, 0};
            if (gy >= 0 && gy < H && gx >= 0 && gx < W) {
                long pg = (long)(b * H + gy) * W + gx;
                v = *(const int4v*)(fhl + ((long)gc * npx + pg) * 32 + q * 8);
            }
            char* dst = (q < 2) ? (char*)hi_t + p * 48 + q * 16
                                : (char*)lo_t + p * 48 + (q - 2) * 16;
            *(int4v*)dst = v;
        }
        __syncthreads();

        const char* ahc = aph + (long)gc * 9216;
        const char* alc = apl + (long)gc * 9216;
        #pragma unroll
        for (int s = 0; s < 9; ++s) {
            const int dy = s / 3, dx = s % 3;
            const int p0 = (ly0 + dy) * 18 + (lx + dx);
            const int p1 = p0 + 36;
            short8v bh0 = *(const short8v*)((const char*)hi_t + p0 * 48 + h * 16);
            short8v bh1 = *(const short8v*)((const char*)hi_t + p1 * 48 + h * 16);
            short8v bl0 = *(const short8v*)((const char*)lo_t + p0 * 48 + h * 16);
            short8v bl1 = *(const short8v*)((const char*)lo_t + p1 * 48 + h * 16);
            #pragma unroll
            for (int cg = 0; cg < 2; ++cg) {
                short8v af = *(const short8v*)(ahc + cg * cgstride + s * 1024);
                short8v al = *(const short8v*)(alc + cg * cgstride + s * 1024);
                acc[cg][0] = __builtin_amdgcn_mfma_f32_32x32x16_bf16(af, bh0, acc[cg][0], 0, 0, 0);
                acc[cg][0] = __builtin_amdgcn_mfma_f32_32x32x16_bf16(af, bl0, acc[cg][0], 0, 0, 0);
                acc[cg][0] = __builtin_amdgcn_mfma_f32_32x32x16_bf16(al, bh0, acc[cg][0], 0, 0, 0);
                acc[cg][1] = __builtin_amdgcn_mfma_f32_32x32x16_bf16(af, bh1, acc[cg][1], 0, 0, 0);
                acc[cg][1] = __builtin_amdgcn_mfma_f32_32x32x16_bf16(af, bl1, acc[cg][1], 0, 0, 0);
                acc[cg][1] = __builtin_amdgcn_mfma_f32_32x32x16_bf16(al, bh1, acc[cg][1], 0, 0, 0);
            }
        }
        __syncthreads();
    }

    const int HW = H * W;
    const long total = (long)16 * 36 * HW;
    #pragma unroll
    for (int cg = 0; cg < 2; ++cg) {
        #pragma unroll
        for (int r = 0; r < 16; ++r) {
            const int co = (cg << 5) + (r & 3) + ((r >> 2) << 3) + (h << 2);
            if (co < 36) {
                #pragma unroll
                for (int pf = 0; pf < 2; ++pf) {
                    const int gy = ty0 + ly0 + pf * 2, gx = tx0 + lx;
                    if (gy < H && gx < W)
                        partial[(long)cis * total + ((long)(b * 36 + co) * HW + gy * W + gx)]
                            = acc[cg][pf][r];
                }
            }
        }
    }
}

// ===========================================================================
// Original encoder (fallback path).
// ===========================================================================
template<int CIN, int CIPER, int CICHUNK, int COCHUNK, int TDIM, bool PARTIAL, bool CL>
__global__ __launch_bounds__(TDIM* TDIM) void enc_tiled(
    const float* __restrict__ feat,
    const float* __restrict__ w,
    const float* __restrict__ bn_s, const float* __restrict__ bn_b,
    const float* __restrict__ thr, const float* __restrict__ beta_raw,
    __hip_bfloat16* __restrict__ avg,
    float* __restrict__ partial,
    int H, int W, int tiles_x)
{
    const int TPB  = TDIM * TDIM;
    const int HALOD = TDIM + 2;
    const int NCO  = 36 / COCHUNK;
    __shared__ float fs[CICHUNK][HALOD][HALOD];

    const int tile = blockIdx.x;
    const int b    = blockIdx.y;
    const int coc  = blockIdx.z % NCO;
    const int cis  = blockIdx.z / NCO;
    const int co0  = coc * COCHUNK;
    const int tx0  = (tile % tiles_x) * TDIM;
    const int ty0  = (tile / tiles_x) * TDIM;

    const int tx = threadIdx.x % TDIM;
    const int ty = threadIdx.x / TDIM;
    const int ox = tx0 + tx, oy = ty0 + ty;

    float acc[COCHUNK];
    #pragma unroll
    for (int c = 0; c < COCHUNK; ++c) acc[c] = 0.f;

    const float* fb = feat + (long)b * CIN * H * W;
    const int ci_base = cis * CIPER;

    for (int cc = ci_base; cc < ci_base + CIPER; cc += CICHUNK) {
        for (int i = threadIdx.x; i < CICHUNK * HALOD * HALOD; i += TPB) {
            int ci = i / (HALOD * HALOD);
            int r  = i % (HALOD * HALOD);
            int hy = r / HALOD, hx = r % HALOD;
            int gy = ty0 + hy - 1, gx = tx0 + hx - 1;
            float v = 0.f;
            if (gy >= 0 && gy < H && gx >= 0 && gx < W)
                v = fb[((long)(cc + ci) * H + gy) * W + gx];
            fs[ci][hy][hx] = v;
        }
        __syncthreads();

        for (int ci = 0; ci < CICHUNK; ++ci) {
            float f0 = fs[ci][ty    ][tx], f1 = fs[ci][ty    ][tx+1], f2 = fs[ci][ty    ][tx+2];
            float f3 = fs[ci][ty + 1][tx], f4 = fs[ci][ty + 1][tx+1], f5 = fs[ci][ty + 1][tx+2];
            float f6 = fs[ci][ty + 2][tx], f7 = fs[ci][ty + 2][tx+1], f8 = fs[ci][ty + 2][tx+2];
            const float* wq = w + (long)(cc + ci) * 9;
            #pragma unroll
            for (int j = 0; j < COCHUNK; ++j) {
                const float* ww = wq + (long)(co0 + j) * CIN * 9;
                acc[j] += f0 * ww[0] + f1 * ww[1] + f2 * ww[2]
                        + f3 * ww[3] + f4 * ww[4] + f5 * ww[5]
                        + f6 * ww[6] + f7 * ww[7] + f8 * ww[8];
            }
        }
        __syncthreads();
    }

    if (ox < W && oy < H) {
        if (PARTIAL) {
            #pragma unroll
            for (int j = 0; j < COCHUNK; ++j)
                partial[((((long)cis * 16 + b) * 36 + (co0 + j)) * H + oy) * W + ox] = acc[j];
        } else {
            float cnt[COCHUNK];
            #pragma unroll
            for (int j = 0; j < COCHUNK; ++j) {
                int co = co0 + j;
                float hh   = acc[j] * bn_s[co] + bn_b[co];
                float beta = 1.f / (1.f + expf(-beta_raw[co]));
                float t    = thr[co];
                float m = 0.f, c2 = 0.f;
                #pragma unroll
                for (int s = 0; s < 4; ++s) {
                    m = beta * m + hh;
                    if (m > t) { c2 += 1.f; m -= t; }
                }
                cnt[j] = c2 * 0.25f;
            }
            if (CL) {
                unsigned* dp = (unsigned*)(avg + ((long)(b * H + oy) * W + ox) * 40 + co0);
                #pragma unroll
                for (int j2 = 0; j2 < COCHUNK / 2; ++j2) {
                    __hip_bfloat16 h0 = __float2bfloat16(cnt[2 * j2]);
                    __hip_bfloat16 h1 = __float2bfloat16(cnt[2 * j2 + 1]);
                    unsigned u0 = *(unsigned short*)&h0;
                    unsigned u1 = *(unsigned short*)&h1;
                    dp[j2] = u0 | (u1 << 16);
                }
            } else {
                #pragma unroll
                for (int j = 0; j < COCHUNK; ++j)
                    avg[(((long)b * 36 + (co0 + j)) * H + oy) * W + ox] = __float2bfloat16(cnt[j]);
            }
        }
    }
}

// ===========================================================================
// Combine ci-split partials + BN + LIF + mean -> bf16 avg (CL or NCHW).
// ===========================================================================
template<int SPLITS, bool CL>
__global__ __launch_bounds__(256) void combine_lif(
    const float* __restrict__ partial,
    const float* __restrict__ bn_s, const float* __restrict__ bn_b,
    const float* __restrict__ thr, const float* __restrict__ beta_raw,
    __hip_bfloat16* __restrict__ avg, int H, int W, int total)
{
    int idx = blockIdx.x * 256 + threadIdx.x;
    if (idx >= total) return;
    int HW = H * W;
    int co = (idx / HW) % 36;
    float hh = 0.f;
    #pragma unroll
    for (int s = 0; s < SPLITS; ++s) hh += partial[(long)s * total + idx];
    hh = hh * bn_s[co] + bn_b[co];
    float beta = 1.f / (1.f + expf(-beta_raw[co]));
    float t    = thr[co];
    float m = 0.f, cnt = 0.f;
    #pragma unroll
    for (int s = 0; s < 4; ++s) {
        m = beta * m + hh;
        if (m > t) { cnt += 1.f; m -= t; }
    }
    if (CL) {
        int b = idx / (36 * HW);
        int rem = idx % HW;
        int y = rem / W, x = rem % W;
        avg[((long)(b * H + y) * W + x) * 40 + co] = __float2bfloat16(cnt * 0.25f);
    } else {
        avg[idx] = __float2bfloat16(cnt * 0.25f);
    }
}

// ===========================================================================
// Weight prepack for MFMA decoder.
// ===========================================================================
__global__ __launch_bounds__(256) void pack_w(
    const float* __restrict__ w, __hip_bfloat16* __restrict__ ap, int total)
{
    int idx = blockIdx.x * 256 + threadIdx.x;
    if (idx >= total) return;
    int m  = idx & 31;
    int h  = (idx >> 5) & 1;
    int s  = (idx >> 6) % 23;
    int cg = idx / (23 * 64);
    int o  = 2 * s + h;
    int co = cg * 32 + m;
    unsigned short v[8];
    #pragma unroll
    for (int j = 0; j < 8; ++j) {
        float x = 0.f;
        if (o < 45) {
            int tap = o / 5, oct = o % 5, ci = oct * 8 + j;
            if (ci < 36) x = w[(long)co * 324 + ci * 9 + tap];
        }
        __hip_bfloat16 hv = __float2bfloat16(x);
        v[j] = *(unsigned short*)&hv;
    }
    *(int4v*)(ap + (long)idx * 8) = *(int4v*)v;
}

// ===========================================================================
// MFMA decoder: conv3x3(36->Cout) + BN + SiLU.
// ===========================================================================
template<int COG>
__global__ __launch_bounds__(256) void dec_mfma(
    const __hip_bfloat16* __restrict__ avg_cl,
    const __hip_bfloat16* __restrict__ apack,
    const float* __restrict__ bn_s, const float* __restrict__ bn_b,
    float* __restrict__ out, int Cout, int H, int W, int tiles_x)
{
    __shared__ __hip_bfloat16 tile[12960];

    const int tid    = threadIdx.x;
    const int b      = blockIdx.y;
    const int cgbase = blockIdx.z * COG;
    const int tx0 = (blockIdx.x % tiles_x) * 16;
    const int ty0 = (blockIdx.x / tiles_x) * 16;

    {
        const __hip_bfloat16* ab = avg_cl + (long)b * H * W * 40;
        for (int i = tid; i < 1620; i += 256) {
            int row = i / 90, u = i - row * 90;
            int px = u / 5, un = u - px * 5;
            int gy = ty0 + row - 1, gx = tx0 + px - 1;
            int4v v = {0, 0, 0, 0};
            if (gy >= 0 && gy < H && gx >= 0 && gx < W)
                v = *(const int4v*)(ab + ((long)gy * W + gx) * 40 + un * 8);
            *(int4v*)(tile + (row * 18 + px) * 40 + un * 8) = v;
        }
    }
    __syncthreads();

    const int lane = tid & 63;
    const int wv   = tid >> 6;
    const int h    = lane >> 5;
    const int n    = lane & 31;
    const int lx   = n & 15;
    const int ly0  = wv * 4 + (n >> 4);

    const char* tb  = (const char*)tile;
    const int   bb0 = ((ly0 + 1) * 18 + (lx + 1)) * 80;
    const int   bb1 = bb0 + 2 * 18 * 80;

    const char* ap = (const char*)apack + (long)cgbase * 23552 + h * 512 + n * 16;

    f32x16 acc[COG][2];
    #pragma unroll
    for (int cg = 0; cg < COG; ++cg)
        #pragma unroll
        for (int pf = 0; pf < 2; ++pf)
            #pragma unroll
            for (int k = 0; k < 16; ++k) acc[cg][pf][k] = 0.f;

    #pragma unroll
    for (int s = 0; s < 23; ++s) {
        int o0 = 2 * s;     if (o0 > 44) o0 = 44;
        int o1 = 2 * s + 1; if (o1 > 44) o1 = 44;
        const int C0 = ((o0 / 5) / 3 - 1) * 1440 + ((o0 / 5) % 3 - 1) * 80 + (o0 % 5) * 16;
        const int C1 = ((o1 / 5) / 3 - 1) * 1440 + ((o1 / 5) % 3 - 1) * 80 + (o1 % 5) * 16;
        const int offc = h ? C1 : C0;
        short8v bf0 = *(const short8v*)(tb + (bb0 + offc));
        short8v bf1 = *(const short8v*)(tb + (bb1 + offc));
        #pragma unroll
        for (int cg = 0; cg < COG; ++cg) {
            short8v af = *(const short8v*)(ap + cg * 23552 + s * 1024);
            acc[cg][0] = __builtin_amdgcn_mfma_f32_32x32x16_bf16(af, bf0, acc[cg][0], 0, 0, 0);
            acc[cg][1] = __builtin_amdgcn_mfma_f32_32x32x16_bf16(af, bf1, acc[cg][1], 0, 0, 0);
        }
    }

    #pragma unroll
    for (int cg = 0; cg < COG; ++cg) {
        #pragma unroll
        for (int r = 0; r < 16; ++r) {
            const int co = ((cgbase + cg) << 5) + (r & 3) + ((r >> 2) << 3) + (h << 2);
            const float sc = bn_s[co], bc = bn_b[co];
            #pragma unroll
            for (int pf = 0; pf < 2; ++pf) {
                const int ly = ly0 + pf * 2;
                const int gy = ty0 + ly, gx = tx0 + lx;
                float v = acc[cg][pf][r] * sc + bc;
                v = v / (1.f + __expf(-v));
                if (gy < H && gx < W)
                    out[(((long)b * Cout + co) * H + gy) * W + gx] = v;
            }
        }
    }
}

// ===========================================================================
// Fallback decoder (VALU, NCHW avg).
// ===========================================================================
template<int COCHUNK, int TDIM>
__global__ __launch_bounds__(TDIM* TDIM) void dec_tiled(
    const __hip_bfloat16* __restrict__ avg,
    const float* __restrict__ w,
    const float* __restrict__ bn_s, const float* __restrict__ bn_b,
    float* __restrict__ out,
    int Cout, int H, int W, int tiles_x)
{
    const int CIN = 36;
    const int TPB = TDIM * TDIM;
    const int HALOD = TDIM + 2;
    __shared__ float fs[CIN][HALOD][HALOD];

    const int tile = blockIdx.x;
    const int b    = blockIdx.y;
    const int co0  = blockIdx.z * COCHUNK;
    const int tx0  = (tile % tiles_x) * TDIM;
    const int ty0  = (tile / tiles_x) * TDIM;

    const int tx = threadIdx.x % TDIM;
    const int ty = threadIdx.x / TDIM;
    const int ox = tx0 + tx, oy = ty0 + ty;

    const __hip_bfloat16* ab = avg + (long)b * CIN * H * W;

    for (int i = threadIdx.x; i < CIN * HALOD * HALOD; i += TPB) {
        int ci = i / (HALOD * HALOD);
        int r  = i % (HALOD * HALOD);
        int hy = r / HALOD, hx = r % HALOD;
        int gy = ty0 + hy - 1, gx = tx0 + hx - 1;
        float v = 0.f;
        if (gy >= 0 && gy < H && gx >= 0 && gx < W)
            v = __bfloat162float(ab[((long)ci * H + gy) * W + gx]);
        fs[ci][hy][hx] = v;
    }
    __syncthreads();

    float acc[COCHUNK];
    #pragma unroll
    for (int j = 0; j < COCHUNK; ++j) acc[j] = 0.f;

    for (int ci = 0; ci < CIN; ++ci) {
        float f0 = fs[ci][ty    ][tx], f1 = fs[ci][ty    ][tx+1], f2 = fs[ci][ty    ][tx+2];
        float f3 = fs[ci][ty + 1][tx], f4 = fs[ci][ty + 1][tx+1], f5 = fs[ci][ty + 1][tx+2];
        float f6 = fs[ci][ty + 2][tx], f7 = fs[ci][ty + 2][tx+1], f8 = fs[ci][ty + 2][tx+2];
        #pragma unroll
        for (int j = 0; j < COCHUNK; ++j) {
            const float* ww = w + ((long)(co0 + j) * CIN + ci) * 9;
            acc[j] += f0 * ww[0] + f1 * ww[1] + f2 * ww[2]
                    + f3 * ww[3] + f4 * ww[4] + f5 * ww[5]
                    + f6 * ww[6] + f7 * ww[7] + f8 * ww[8];
        }
    }

    if (ox < W && oy < H) {
        #pragma unroll
        for (int j = 0; j < COCHUNK; ++j) {
            int co = co0 + j;
            float v = acc[j] * bn_s[co] + bn_b[co];
            out[(((long)b * Cout + co) * H + oy) * W + ox] = v / (1.f + expf(-v));
        }
    }
}

// ===========================================================================
extern "C" void kernel_launch(void* const* d_in, const int* in_sizes, int n_in,
                              void* d_out, int out_size, void* d_ws, size_t ws_size,
                              hipStream_t stream)
{
    const int B = 16;
    const int C[3] = {64, 128, 256};
    const int S[3] = {160, 80, 40};

    float* out = (float*)d_out;
    long out_off[3]; long off = 0;
    for (int l = 0; l < 3; ++l) { out_off[l] = off; off += (long)B * C[l] * S[l] * S[l]; }

    // ---- workspace layout (bytes) ----
    const long avgcl_bytes[3] = {32768000L, 8192000L, 2048000L};
    long avgcl_off[3]; long boff = 0;
    for (int l = 0; l < 3; ++l) { avgcl_off[l] = boff; boff += avgcl_bytes[l]; }
    const long avgcl_total = boff;
    const long ap_bytes[3] = {47104L, 94208L, 188416L};
    long ap_off[3];
    for (int l = 0; l < 3; ++l) { ap_off[l] = boff; boff += ap_bytes[l]; }
    const long we_bytes[3] = {73728L, 147456L, 294912L};
    long wehi_off[3], welo_off[3];
    for (int l = 0; l < 3; ++l) { wehi_off[l] = boff; boff += we_bytes[l];
                                  welo_off[l] = boff; boff += we_bytes[l]; }
    const long part5_off = boff;
    const long part5_bytes = 4L * B * 36 * 1600 * 4;
    boff += part5_bytes;
    const size_t need_full = (size_t)boff;
    const size_t need_min  = (size_t)part5_off;
    // combined chunk-major hi/lo feat
    const long fhl_bytes[3] = {104857600L, 52428800L, 26214400L};
    long fhl_off[3];
    for (int l = 0; l < 2; ++l) { fhl_off[l] = boff; boff += fhl_bytes[l]; }
    const size_t need_cl = (size_t)boff;
    fhl_off[2] = boff; boff += fhl_bytes[2];
    const size_t need_cl5 = (size_t)boff;

    char* wsb = (char*)d_ws;

    if (ws_size >= need_min) {
        const bool split5  = ws_size >= need_full;
        const bool use_cl  = ws_size >= need_cl;
        const bool use_cl5 = ws_size >= need_cl5;
        hipMemsetAsync(wsb, 0, avgcl_total, stream);

        for (int l = 0; l < 3; ++l) {
            const float* dec_w = (const float*)d_in[9 * l + 6];
            int total = (C[l] / 32) * 23 * 2 * 32;
            pack_w<<<(total + 255) / 256, 256, 0, stream>>>(
                dec_w, (__hip_bfloat16*)(wsb + ap_off[l]), total);
        }
        {
            const float* enc_w3 = (const float*)d_in[1];
            int total = 2 * (64 / 16) * 9 * 2 * 32;
            pack_we<64><<<(total + 255) / 256, 256, 0, stream>>>(
                enc_w3, (__hip_bfloat16*)(wsb + wehi_off[0]),
                (__hip_bfloat16*)(wsb + welo_off[0]), total);
        }
        {
            const float* enc_w4 = (const float*)d_in[10];
            int total = 2 * (128 / 16) * 9 * 2 * 32;
            pack_we<128><<<(total + 255) / 256, 256, 0, stream>>>(
                enc_w4, (__hip_bfloat16*)(wsb + wehi_off[1]),
                (__hip_bfloat16*)(wsb + welo_off[1]), total);
        }
        if (use_cl5) {
            const float* enc_w5 = (const float*)d_in[19];
            int total = 2 * (256 / 16) * 9 * 2 * 32;
            pack_we<256><<<(total + 255) / 256, 256, 0, stream>>>(
                enc_w5, (__hip_bfloat16*)(wsb + wehi_off[2]),
                (__hip_bfloat16*)(wsb + welo_off[2]), total);
        }
        if (use_cl) {
            {
                int HW = 160 * 160, npx = B * HW;
                feat_hl<64, 64><<<(npx + 63) / 64, 256, 0, stream>>>(
                    (const float*)d_in[0], (__hip_bfloat16*)(wsb + fhl_off[0]), HW, npx);
            }
            {
                int HW = 80 * 80, npx = B * HW;
                feat_hl<128, 64><<<(npx + 63) / 64, 256, 0, stream>>>(
                    (const float*)d_in[9], (__hip_bfloat16*)(wsb + fhl_off[1]), HW, npx);
            }
        }
        if (use_cl5) {
            int HW = 40 * 40, npx = B * HW;
            feat_hl<256, 32><<<(npx + 31) / 32, 256, 0, stream>>>(
                (const float*)d_in[18], (__hip_bfloat16*)(wsb + fhl_off[2]), HW, npx);
        }

        for (int l = 0; l < 3; ++l) {
            const int base = 9 * l;
            const float* feat     = (const float*)d_in[base + 0];
            const float* enc_w    = (const float*)d_in[base + 1];
            const float* enc_bn_s = (const float*)d_in[base + 2];
            const float* enc_bn_b = (const float*)d_in[base + 3];
            const float* enc_thr  = (const float*)d_in[base + 4];
            const float* enc_beta = (const float*)d_in[base + 5];
            const float* dec_bn_s = (const float*)d_in[base + 7];
            const float* dec_bn_b = (const float*)d_in[base + 8];

            const int Hs = S[l], Wsz = S[l];
            __hip_bfloat16* avg_cl = (__hip_bfloat16*)(wsb + avgcl_off[l]);
            const __hip_bfloat16* ap = (const __hip_bfloat16*)(wsb + ap_off[l]);
            float* r = out + out_off[l];

            if (l == 0) {
                dim3 eg(100, B);
                if (use_cl)
                    enc_mfma_cl<64><<<eg, 256, 0, stream>>>(
                        (const __hip_bfloat16*)(wsb + fhl_off[0]),
                        (const __hip_bfloat16*)(wsb + wehi_off[0]),
                        (const __hip_bfloat16*)(wsb + welo_off[0]),
                        enc_bn_s, enc_bn_b, enc_thr, enc_beta, avg_cl, Hs, Wsz, 10);
                else
                    enc_tiled<64, 64, 16, 12, 16, false, true><<<dim3(100, B, 3), 256, 0, stream>>>(
                        feat, enc_w, enc_bn_s, enc_bn_b, enc_thr, enc_beta, avg_cl, nullptr, Hs, Wsz, 10);
                dim3 dg(100, B, 1);
                dec_mfma<2><<<dg, 256, 0, stream>>>(avg_cl, ap, dec_bn_s, dec_bn_b, r, 64, Hs, Wsz, 10);
            } else if (l == 1) {
                dim3 eg(25, B);
                if (use_cl)
                    enc_mfma_cl<128><<<eg, 256, 0, stream>>>(
                        (const __hip_bfloat16*)(wsb + fhl_off[1]),
                        (const __hip_bfloat16*)(wsb + wehi_off[1]),
                        (const __hip_bfloat16*)(wsb + welo_off[1]),
                        enc_bn_s, enc_bn_b, enc_thr, enc_beta, avg_cl, Hs, Wsz, 5);
                else
                    enc_tiled<128, 128, 16, 12, 16, false, true><<<dim3(25, B, 3), 256, 0, stream>>>(
                        feat, enc_w, enc_bn_s, enc_bn_b, enc_thr, enc_beta, avg_cl, nullptr, Hs, Wsz, 5);
                dim3 dg(25, B, 2);
                dec_mfma<2><<<dg, 256, 0, stream>>>(avg_cl, ap, dec_bn_s, dec_bn_b, r, 128, Hs, Wsz, 5);
            } else {
                if (use_cl5) {
                    float* partial5 = (float*)(wsb + part5_off);
                    dim3 eg(9, B, 4);
                    enc_mfma_p<256, 64><<<eg, 256, 0, stream>>>(
                        (const __hip_bfloat16*)(wsb + fhl_off[2]),
                        (const __hip_bfloat16*)(wsb + wehi_off[2]),
                        (const __hip_bfloat16*)(wsb + welo_off[2]),
                        partial5, Hs, Wsz, 3);
                    int total = B * 36 * Hs * Wsz;
                    combine_lif<4, true><<<(total + 255) / 256, 256, 0, stream>>>(
                        partial5, enc_bn_s, enc_bn_b, enc_thr, enc_beta, avg_cl, Hs, Wsz, total);
                } else if (split5) {
                    float* partial5 = (float*)(wsb + part5_off);
                    dim3 eg(25, B, 12);
                    enc_tiled<256, 64, 16, 12, 8, true, true><<<eg, 64, 0, stream>>>(
                        feat, enc_w, enc_bn_s, enc_bn_b, enc_thr, enc_beta, nullptr, partial5, Hs, Wsz, 5);
                    int total = B * 36 * Hs * Wsz;
                    combine_lif<4, true><<<(total + 255) / 256, 256, 0, stream>>>(
                        partial5, enc_bn_s, enc_bn_b, enc_thr, enc_beta, avg_cl, Hs, Wsz, total);
                } else {
                    dim3 eg(25, B, 3);
                    enc_tiled<256, 256, 16, 12, 8, false, true><<<eg, 64, 0, stream>>>(
                        feat, enc_w, enc_bn_s, enc_bn_b, enc_thr, enc_beta, avg_cl, nullptr, Hs, Wsz, 5);
                }
                dim3 dg(9, B, 4);
                dec_mfma<2><<<dg, 256, 0, stream>>>(avg_cl, ap, dec_bn_s, dec_bn_b, r, 256, Hs, Wsz, 3);
            }
        }
    } else {
        // ================= FALLBACK (NCHW, VALU decoder) =================
        __hip_bfloat16* ws = (__hip_bfloat16*)d_ws;
        long avg_off2[3]; long eoff = 0;
        for (int l = 0; l < 3; ++l) { avg_off2[l] = eoff; eoff += (long)B * 36 * S[l] * S[l]; }
        float* partial5 = (float*)(ws + ((eoff + 7) & ~7L));
        const long part5f = 4L * B * 36 * 40 * 40;
        const size_t old_need = (size_t)((eoff + 7) & ~7L) * 2 + part5f * 4;
        const bool split5 = ws_size >= old_need;

        for (int l = 0; l < 3; ++l) {
            const int base = 9 * l;
            const float* feat     = (const float*)d_in[base + 0];
            const float* enc_w    = (const float*)d_in[base + 1];
            const float* enc_bn_s = (const float*)d_in[base + 2];
            const float* enc_bn_b = (const float*)d_in[base + 3];
            const float* enc_thr  = (const float*)d_in[base + 4];
            const float* enc_beta = (const float*)d_in[base + 5];
            const float* dec_w    = (const float*)d_in[base + 6];
            const float* dec_bn_s = (const float*)d_in[base + 7];
            const float* dec_bn_b = (const float*)d_in[base + 8];

            const int Hs = S[l], Wsz = S[l], Cl = C[l];
            __hip_bfloat16* avg = ws + avg_off2[l];
            float* r = out + out_off[l];

            if (l == 0) {
                dim3 eg(100, B, 3);
                enc_tiled<64, 64, 16, 12, 16, false, false><<<eg, 256, 0, stream>>>(
                    feat, enc_w, enc_bn_s, enc_bn_b, enc_thr, enc_beta, avg, nullptr, Hs, Wsz, 10);
                dim3 dg(100, B, 2);
                dec_tiled<32, 16><<<dg, 256, 0, stream>>>(avg, dec_w, dec_bn_s, dec_bn_b, r, Cl, Hs, Wsz, 10);
            } else if (l == 1) {
                dim3 eg(25, B, 3);
                enc_tiled<128, 128, 16, 12, 16, false, false><<<eg, 256, 0, stream>>>(
                    feat, enc_w, enc_bn_s, enc_bn_b, enc_thr, enc_beta, avg, nullptr, Hs, Wsz, 5);
                dim3 dg(25, B, 4);
                dec_tiled<32, 16><<<dg, 256, 0, stream>>>(avg, dec_w, dec_bn_s, dec_bn_b, r, Cl, Hs, Wsz, 5);
            } else {
                if (split5) {
                    dim3 eg(25, B, 12);
                    enc_tiled<256, 64, 16, 12, 8, true, false><<<eg, 64, 0, stream>>>(
                        feat, enc_w, enc_bn_s, enc_bn_b, enc_thr, enc_beta, nullptr, partial5, Hs, Wsz, 5);
                    int total = B * 36 * Hs * Wsz;
                    combine_lif<4, false><<<(total + 255) / 256, 256, 0, stream>>>(
                        partial5, enc_bn_s, enc_bn_b, enc_thr, enc_beta, avg, Hs, Wsz, total);
                } else {
                    dim3 eg(25, B, 3);
                    enc_tiled<256, 256, 16, 12, 8, false, false><<<eg, 64, 0, stream>>>(
                        feat, enc_w, enc_bn_s, enc_bn_b, enc_thr, enc_beta, avg, nullptr, Hs, Wsz, 5);
                }
                dim3 dg(25, B, 16);
                dec_tiled<16, 8><<<dg, 64, 0, stream>>>(avg, dec_w, dec_bn_s, dec_bn_b, r, Cl, Hs, Wsz, 5);
            }
        }
    }
}

// Round 18
// 571.248 us; speedup vs baseline: 2.5353x; 1.0184x over previous
//
#include <hip/hip_runtime.h>
#include <hip/hip_bf16.h>

typedef __attribute__((ext_vector_type(8)))  short short8v;
typedef __attribute__((ext_vector_type(16))) float f32x16;
typedef __attribute__((ext_vector_type(4)))  int   int4v;

// ===========================================================================
// Encoder weight prepack for MFMA (split bf16 hi/lo).
// ===========================================================================
template<int CIN>
__global__ __launch_bounds__(256) void pack_we(
    const float* __restrict__ w, __hip_bfloat16* __restrict__ whi,
    __hip_bfloat16* __restrict__ wlo, int total)
{
    const int NCHUNK = CIN / 16;
    int idx = blockIdx.x * 256 + threadIdx.x;
    if (idx >= total) return;
    int m  = idx & 31;
    int h  = (idx >> 5) & 1;
    int s  = (idx >> 6) % 9;
    int c  = (idx / 576) % NCHUNK;
    int cg = idx / (576 * NCHUNK);
    int co = cg * 32 + m;
    unsigned short vh[8], vl[8];
    #pragma unroll
    for (int j = 0; j < 8; ++j) {
        int ci = c * 16 + h * 8 + j;
        float x = (co < 36) ? w[(long)co * CIN * 9 + ci * 9 + s] : 0.f;
        __hip_bfloat16 xh = __float2bfloat16(x);
        float rem = x - __bfloat162float(xh);
        __hip_bfloat16 xl = __float2bfloat16(rem);
        vh[j] = *(unsigned short*)&xh;
        vl[j] = *(unsigned short*)&xl;
    }
    *(int4v*)(whi + (long)idx * 8) = *(int4v*)vh;
    *(int4v*)(wlo + (long)idx * 8) = *(int4v*)vl;
}

// ===========================================================================
// feat_hl: fp32 NCHW -> chunk-major interleaved bf16 hi/lo:
//   fhl[((chunk * npx) + p) * 32 + q*8],  q = {hi0-7, hi8-15, lo0-7, lo8-15}
// ===========================================================================
template<int CIN, int PXB>
__global__ __launch_bounds__(256) void feat_hl(
    const float* __restrict__ f, __hip_bfloat16* __restrict__ fhl,
    int HW, int npx)
{
    const int NCHUNK = CIN / 16;
    __shared__ float t[CIN][PXB];
    const int p0 = blockIdx.x * PXB;

    for (int i = threadIdx.x; i < CIN * PXB; i += 256) {
        int ci = i / PXB, px = i % PXB;
        int p = p0 + px;
        float v = 0.f;
        if (p < npx) {
            int b = p / HW, r = p - b * HW;
            v = f[((long)b * CIN + ci) * HW + r];
        }
        t[ci][px] = v;
    }
    __syncthreads();

    for (int i = threadIdx.x; i < PXB * NCHUNK * 4; i += 256) {
        int q  = i & 3;
        int px = (i >> 2) % PXB;
        int c  = i / (4 * PXB);
        int p = p0 + px;
        if (p >= npx) continue;
        const bool lo = (q >= 2);
        const int ch0 = c * 16 + (q & 1) * 8;
        unsigned short v[8];
        #pragma unroll
        for (int j = 0; j < 8; ++j) {
            float x = t[ch0 + j][px];
            __hip_bfloat16 xh = __float2bfloat16(x);
            if (lo) {
                float rem = x - __bfloat162float(xh);
                xh = __float2bfloat16(rem);
            }
            v[j] = *(unsigned short*)&xh;
        }
        *(int4v*)(fhl + ((long)c * npx + p) * 32 + q * 8) = *(int4v*)v;
    }
}

// ===========================================================================
// MFMA encoder, chunk-major-staged, reg-prefetch pipelined (T14 split:
// issue chunk c+1 loads BEFORE chunk c's MFMA block; write regs->LDS after
// the barrier). LDS single-buffered (31KB), barrier count unchanged.
// MFMA core + LDS layout in-situ verified R12-R17 (absmax 0.047).
// ===========================================================================
template<int CIN>
__global__ __launch_bounds__(256) void enc_mfma_cl(
    const __hip_bfloat16* __restrict__ fhl,  // [chunk][npx][32]
    const __hip_bfloat16* __restrict__ whi,
    const __hip_bfloat16* __restrict__ wlo,
    const float* __restrict__ bn_s, const float* __restrict__ bn_b,
    const float* __restrict__ thr, const float* __restrict__ beta_raw,
    __hip_bfloat16* __restrict__ avg,        // [16][H][W][40]
    int H, int W, int tiles_x)
{
    const int NCHUNK = CIN / 16;
    __shared__ __align__(16) short sbuf[324 * 48];
    short* hi_t = sbuf;
    short* lo_t = sbuf + 324 * 24;

    const int tid = threadIdx.x;
    const int b   = blockIdx.y;
    const int tx0 = (blockIdx.x % tiles_x) * 16;
    const int ty0 = (blockIdx.x / tiles_x) * 16;
    const long npx = (long)16 * H * W;

    const int lane = tid & 63;
    const int wv   = tid >> 6;
    const int h    = lane >> 5;
    const int n    = lane & 31;
    const int lx   = n & 15;
    const int ly0  = wv * 4 + (n >> 4);

    f32x16 acc[2][2];
    #pragma unroll
    for (int cg = 0; cg < 2; ++cg)
        #pragma unroll
        for (int pf = 0; pf < 2; ++pf)
            #pragma unroll
            for (int k = 0; k < 16; ++k) acc[cg][pf][k] = 0.f;

    const char* aph = (const char*)whi + h * 512 + n * 16;
    const char* apl = (const char*)wlo + h * 512 + n * 16;
    const long  cgstride = (long)NCHUNK * 9216;

    int4v rv[6];
    // ---- prologue: load chunk 0 into regs ----
    #pragma unroll
    for (int k = 0; k < 6; ++k) {
        const int i = tid + k * 256;
        rv[k] = (int4v){0, 0, 0, 0};
        if (i < 1296) {
            int p = i >> 2, q = i & 3;
            int hy = p / 18, hx = p - hy * 18;
            int gy = ty0 + hy - 1, gx = tx0 + hx - 1;
            if (gy >= 0 && gy < H && gx >= 0 && gx < W) {
                long pg = (long)(b * H + gy) * W + gx;
                rv[k] = *(const int4v*)(fhl + (0 * npx + pg) * 32 + q * 8);
            }
        }
    }

    for (int c = 0; c < NCHUNK; ++c) {
        __syncthreads();   // prior chunk's MFMA done reading LDS
        // ---- write prefetched regs -> LDS ----
        #pragma unroll
        for (int k = 0; k < 6; ++k) {
            const int i = tid + k * 256;
            if (i < 1296) {
                int p = i >> 2, q = i & 3;
                char* dst = (q < 2) ? (char*)hi_t + p * 48 + q * 16
                                    : (char*)lo_t + p * 48 + (q - 2) * 16;
                *(int4v*)dst = rv[k];
            }
        }
        __syncthreads();
        // ---- issue next chunk's loads (latency hides under MFMA below) ----
        if (c + 1 < NCHUNK) {
            #pragma unroll
            for (int k = 0; k < 6; ++k) {
                const int i = tid + k * 256;
                rv[k] = (int4v){0, 0, 0, 0};
                if (i < 1296) {
                    int p = i >> 2, q = i & 3;
                    int hy = p / 18, hx = p - hy * 18;
                    int gy = ty0 + hy - 1, gx = tx0 + hx - 1;
                    if (gy >= 0 && gy < H && gx >= 0 && gx < W) {
                        long pg = (long)(b * H + gy) * W + gx;
                        rv[k] = *(const int4v*)(fhl + ((long)(c + 1) * npx + pg) * 32 + q * 8);
                    }
                }
            }
        }

        const char* ahc = aph + (long)c * 9216;
        const char* alc = apl + (long)c * 9216;
        #pragma unroll
        for (int s = 0; s < 9; ++s) {
            const int dy = s / 3, dx = s % 3;
            const int p0 = (ly0 + dy) * 18 + (lx + dx);
            const int p1 = p0 + 36;
            short8v bh0 = *(const short8v*)((const char*)hi_t + p0 * 48 + h * 16);
            short8v bh1 = *(const short8v*)((const char*)hi_t + p1 * 48 + h * 16);
            short8v bl0 = *(const short8v*)((const char*)lo_t + p0 * 48 + h * 16);
            short8v bl1 = *(const short8v*)((const char*)lo_t + p1 * 48 + h * 16);
            #pragma unroll
            for (int cg = 0; cg < 2; ++cg) {
                short8v af = *(const short8v*)(ahc + cg * cgstride + s * 1024);
                short8v al = *(const short8v*)(alc + cg * cgstride + s * 1024);
                acc[cg][0] = __builtin_amdgcn_mfma_f32_32x32x16_bf16(af, bh0, acc[cg][0], 0, 0, 0);
                acc[cg][0] = __builtin_amdgcn_mfma_f32_32x32x16_bf16(af, bl0, acc[cg][0], 0, 0, 0);
                acc[cg][0] = __builtin_amdgcn_mfma_f32_32x32x16_bf16(al, bh0, acc[cg][0], 0, 0, 0);
                acc[cg][1] = __builtin_amdgcn_mfma_f32_32x32x16_bf16(af, bh1, acc[cg][1], 0, 0, 0);
                acc[cg][1] = __builtin_amdgcn_mfma_f32_32x32x16_bf16(af, bl1, acc[cg][1], 0, 0, 0);
                acc[cg][1] = __builtin_amdgcn_mfma_f32_32x32x16_bf16(al, bh1, acc[cg][1], 0, 0, 0);
            }
        }
    }
    __syncthreads();   // last MFMA done before sbuf reuse

    // ---- epilogue: LIF -> LDS transpose -> coalesced 16B stores ----
    for (int i = tid; i < 1280; i += 256)
        *(int4v*)((char*)sbuf + i * 16) = (int4v){0, 0, 0, 0};
    __syncthreads();

    #pragma unroll
    for (int cg = 0; cg < 2; ++cg) {
        #pragma unroll
        for (int r = 0; r < 16; ++r) {
            const int co = (cg << 5) + (r & 3) + ((r >> 2) << 3) + (h << 2);
            if (co < 36) {
                const float sc   = bn_s[co], sb = bn_b[co];
                const float beta = 1.f / (1.f + expf(-beta_raw[co]));
                const float t    = thr[co];
                #pragma unroll
                for (int pf = 0; pf < 2; ++pf) {
                    const int ly = ly0 + pf * 2;
                    float hv = acc[cg][pf][r] * sc + sb;
                    float m = 0.f, c2 = 0.f;
                    #pragma unroll
                    for (int s4 = 0; s4 < 4; ++s4) {
                        m = beta * m + hv;
                        if (m > t) { c2 += 1.f; m -= t; }
                    }
                    __hip_bfloat16 ov = __float2bfloat16(c2 * 0.25f);
                    sbuf[(ly * 16 + lx) * 40 + co] = *(short*)&ov;
                }
            }
        }
    }
    __syncthreads();

    const long tilebase = ((long)(b * H + ty0) * W + tx0) * 40;
    for (int i = tid; i < 1280; i += 256) {
        int px = i / 5, u = i - px * 5;
        int py2 = px >> 4, px2 = px & 15;
        *(int4v*)(avg + tilebase + ((long)py2 * W + px2) * 40 + u * 8) =
            *(const int4v*)(sbuf + px * 40 + u * 8);
    }
}

// ===========================================================================
// MFMA encoder, ci-split partial variant (enc5), same reg-prefetch pipeline.
// ===========================================================================
template<int CIN, int CIPER>
__global__ __launch_bounds__(256) void enc_mfma_p(
    const __hip_bfloat16* __restrict__ fhl,
    const __hip_bfloat16* __restrict__ whi,
    const __hip_bfloat16* __restrict__ wlo,
    float* __restrict__ partial,
    int H, int W, int tiles_x)
{
    const int NCH_TOT = CIN / 16;
    const int NCH_PER = CIPER / 16;
    __shared__ __align__(16) short sbuf[324 * 48];
    short* hi_t = sbuf;
    short* lo_t = sbuf + 324 * 24;

    const int tid = threadIdx.x;
    const int b   = blockIdx.y;
    const int cis = blockIdx.z;
    const int tx0 = (blockIdx.x % tiles_x) * 16;
    const int ty0 = (blockIdx.x / tiles_x) * 16;
    const long npx = (long)16 * H * W;

    const int lane = tid & 63;
    const int wv   = tid >> 6;
    const int h    = lane >> 5;
    const int n    = lane & 31;
    const int lx   = n & 15;
    const int ly0  = wv * 4 + (n >> 4);

    f32x16 acc[2][2];
    #pragma unroll
    for (int cg = 0; cg < 2; ++cg)
        #pragma unroll
        for (int pf = 0; pf < 2; ++pf)
            #pragma unroll
            for (int k = 0; k < 16; ++k) acc[cg][pf][k] = 0.f;

    const char* aph = (const char*)whi + h * 512 + n * 16;
    const char* apl = (const char*)wlo + h * 512 + n * 16;
    const long  cgstride = (long)NCH_TOT * 9216;

    int4v rv[6];
    #pragma unroll
    for (int k = 0; k < 6; ++k) {
        const int i = tid + k * 256;
        rv[k] = (int4v){0, 0, 0, 0};
        if (i < 1296) {
            int p = i >> 2, q = i & 3;
            int hy = p / 18, hx = p - hy * 18;
            int gy = ty0 + hy - 1, gx = tx0 + hx - 1;
            if (gy >= 0 && gy < H && gx >= 0 && gx < W) {
                long pg = (long)(b * H + gy) * W + gx;
                rv[k] = *(const int4v*)(fhl + ((long)(cis * NCH_PER) * npx + pg) * 32 + q * 8);
            }
        }
    }

    for (int c = 0; c < NCH_PER; ++c) {
        const int gc = cis * NCH_PER + c;
        __syncthreads();
        #pragma unroll
        for (int k = 0; k < 6; ++k) {
            const int i = tid + k * 256;
            if (i < 1296) {
                int p = i >> 2, q = i & 3;
                char* dst = (q < 2) ? (char*)hi_t + p * 48 + q * 16
                                    : (char*)lo_t + p * 48 + (q - 2) * 16;
                *(int4v*)dst = rv[k];
            }
        }
        __syncthreads();
        if (c + 1 < NCH_PER) {
            #pragma unroll
            for (int k = 0; k < 6; ++k) {
                const int i = tid + k * 256;
                rv[k] = (int4v){0, 0, 0, 0};
                if (i < 1296) {
                    int p = i >> 2, q = i & 3;
                    int hy = p / 18, hx = p - hy * 18;
                    int gy = ty0 + hy - 1, gx = tx0 + hx - 1;
                    if (gy >= 0 && gy < H && gx >= 0 && gx < W) {
                        long pg = (long)(b * H + gy) * W + gx;
                        rv[k] = *(const int4v*)(fhl + ((long)(gc + 1) * npx + pg) * 32 + q * 8);
                    }
                }
            }
        }

        const char* ahc = aph + (long)gc * 9216;
        const char* alc = apl + (long)gc * 9216;
        #pragma unroll
        for (int s = 0; s < 9; ++s) {
            const int dy = s / 3, dx = s % 3;
            const int p0 = (ly0 + dy) * 18 + (lx + dx);
            const int p1 = p0 + 36;
            short8v bh0 = *(const short8v*)((const char*)hi_t + p0 * 48 + h * 16);
            short8v bh1 = *(const short8v*)((const char*)hi_t + p1 * 48 + h * 16);
            short8v bl0 = *(const short8v*)((const char*)lo_t + p0 * 48 + h * 16);
            short8v bl1 = *(const short8v*)((const char*)lo_t + p1 * 48 + h * 16);
            #pragma unroll
            for (int cg = 0; cg < 2; ++cg) {
                short8v af = *(const short8v*)(ahc + cg * cgstride + s * 1024);
                short8v al = *(const short8v*)(alc + cg * cgstride + s * 1024);
                acc[cg][0] = __builtin_amdgcn_mfma_f32_32x32x16_bf16(af, bh0, acc[cg][0], 0, 0, 0);
                acc[cg][0] = __builtin_amdgcn_mfma_f32_32x32x16_bf16(af, bl0, acc[cg][0], 0, 0, 0);
                acc[cg][0] = __builtin_amdgcn_mfma_f32_32x32x16_bf16(al, bh0, acc[cg][0], 0, 0, 0);
                acc[cg][1] = __builtin_amdgcn_mfma_f32_32x32x16_bf16(af, bh1, acc[cg][1], 0, 0, 0);
                acc[cg][1] = __builtin_amdgcn_mfma_f32_32x32x16_bf16(af, bl1, acc[cg][1], 0, 0, 0);
                acc[cg][1] = __builtin_amdgcn_mfma_f32_32x32x16_bf16(al, bh1, acc[cg][1], 0, 0, 0);
            }
        }
    }

    const int HW = H * W;
    const long total = (long)16 * 36 * HW;
    #pragma unroll
    for (int cg = 0; cg < 2; ++cg) {
        #pragma unroll
        for (int r = 0; r < 16; ++r) {
            const int co = (cg << 5) + (r & 3) + ((r >> 2) << 3) + (h << 2);
            if (co < 36) {
                #pragma unroll
                for (int pf = 0; pf < 2; ++pf) {
                    const int gy = ty0 + ly0 + pf * 2, gx = tx0 + lx;
                    if (gy < H && gx < W)
                        partial[(long)cis * total + ((long)(b * 36 + co) * HW + gy * W + gx)]
                            = acc[cg][pf][r];
                }
            }
        }
    }
}

// ===========================================================================
// Original encoder (fallback path).
// ===========================================================================
template<int CIN, int CIPER, int CICHUNK, int COCHUNK, int TDIM, bool PARTIAL, bool CL>
__global__ __launch_bounds__(TDIM* TDIM) void enc_tiled(
    const float* __restrict__ feat,
    const float* __restrict__ w,
    const float* __restrict__ bn_s, const float* __restrict__ bn_b,
    const float* __restrict__ thr, const float* __restrict__ beta_raw,
    __hip_bfloat16* __restrict__ avg,
    float* __restrict__ partial,
    int H, int W, int tiles_x)
{
    const int TPB  = TDIM * TDIM;
    const int HALOD = TDIM + 2;
    const int NCO  = 36 / COCHUNK;
    __shared__ float fs[CICHUNK][HALOD][HALOD];

    const int tile = blockIdx.x;
    const int b    = blockIdx.y;
    const int coc  = blockIdx.z % NCO;
    const int cis  = blockIdx.z / NCO;
    const int co0  = coc * COCHUNK;
    const int tx0  = (tile % tiles_x) * TDIM;
    const int ty0  = (tile / tiles_x) * TDIM;

    const int tx = threadIdx.x % TDIM;
    const int ty = threadIdx.x / TDIM;
    const int ox = tx0 + tx, oy = ty0 + ty;

    float acc[COCHUNK];
    #pragma unroll
    for (int c = 0; c < COCHUNK; ++c) acc[c] = 0.f;

    const float* fb = feat + (long)b * CIN * H * W;
    const int ci_base = cis * CIPER;

    for (int cc = ci_base; cc < ci_base + CIPER; cc += CICHUNK) {
        for (int i = threadIdx.x; i < CICHUNK * HALOD * HALOD; i += TPB) {
            int ci = i / (HALOD * HALOD);
            int r  = i % (HALOD * HALOD);
            int hy = r / HALOD, hx = r % HALOD;
            int gy = ty0 + hy - 1, gx = tx0 + hx - 1;
            float v = 0.f;
            if (gy >= 0 && gy < H && gx >= 0 && gx < W)
                v = fb[((long)(cc + ci) * H + gy) * W + gx];
            fs[ci][hy][hx] = v;
        }
        __syncthreads();

        for (int ci = 0; ci < CICHUNK; ++ci) {
            float f0 = fs[ci][ty    ][tx], f1 = fs[ci][ty    ][tx+1], f2 = fs[ci][ty    ][tx+2];
            float f3 = fs[ci][ty + 1][tx], f4 = fs[ci][ty + 1][tx+1], f5 = fs[ci][ty + 1][tx+2];
            float f6 = fs[ci][ty + 2][tx], f7 = fs[ci][ty + 2][tx+1], f8 = fs[ci][ty + 2][tx+2];
            const float* wq = w + (long)(cc + ci) * 9;
            #pragma unroll
            for (int j = 0; j < COCHUNK; ++j) {
                const float* ww = wq + (long)(co0 + j) * CIN * 9;
                acc[j] += f0 * ww[0] + f1 * ww[1] + f2 * ww[2]
                        + f3 * ww[3] + f4 * ww[4] + f5 * ww[5]
                        + f6 * ww[6] + f7 * ww[7] + f8 * ww[8];
            }
        }
        __syncthreads();
    }

    if (ox < W && oy < H) {
        if (PARTIAL) {
            #pragma unroll
            for (int j = 0; j < COCHUNK; ++j)
                partial[((((long)cis * 16 + b) * 36 + (co0 + j)) * H + oy) * W + ox] = acc[j];
        } else {
            float cnt[COCHUNK];
            #pragma unroll
            for (int j = 0; j < COCHUNK; ++j) {
                int co = co0 + j;
                float hh   = acc[j] * bn_s[co] + bn_b[co];
                float beta = 1.f / (1.f + expf(-beta_raw[co]));
                float t    = thr[co];
                float m = 0.f, c2 = 0.f;
                #pragma unroll
                for (int s = 0; s < 4; ++s) {
                    m = beta * m + hh;
                    if (m > t) { c2 += 1.f; m -= t; }
                }
                cnt[j] = c2 * 0.25f;
            }
            if (CL) {
                unsigned* dp = (unsigned*)(avg + ((long)(b * H + oy) * W + ox) * 40 + co0);
                #pragma unroll
                for (int j2 = 0; j2 < COCHUNK / 2; ++j2) {
                    __hip_bfloat16 h0 = __float2bfloat16(cnt[2 * j2]);
                    __hip_bfloat16 h1 = __float2bfloat16(cnt[2 * j2 + 1]);
                    unsigned u0 = *(unsigned short*)&h0;
                    unsigned u1 = *(unsigned short*)&h1;
                    dp[j2] = u0 | (u1 << 16);
                }
            } else {
                #pragma unroll
                for (int j = 0; j < COCHUNK; ++j)
                    avg[(((long)b * 36 + (co0 + j)) * H + oy) * W + ox] = __float2bfloat16(cnt[j]);
            }
        }
    }
}

// ===========================================================================
// Combine ci-split partials + BN + LIF + mean -> bf16 avg (CL or NCHW).
// ===========================================================================
template<int SPLITS, bool CL>
__global__ __launch_bounds__(256) void combine_lif(
    const float* __restrict__ partial,
    const float* __restrict__ bn_s, const float* __restrict__ bn_b,
    const float* __restrict__ thr, const float* __restrict__ beta_raw,
    __hip_bfloat16* __restrict__ avg, int H, int W, int total)
{
    int idx = blockIdx.x * 256 + threadIdx.x;
    if (idx >= total) return;
    int HW = H * W;
    int co = (idx / HW) % 36;
    float hh = 0.f;
    #pragma unroll
    for (int s = 0; s < SPLITS; ++s) hh += partial[(long)s * total + idx];
    hh = hh * bn_s[co] + bn_b[co];
    float beta = 1.f / (1.f + expf(-beta_raw[co]));
    float t    = thr[co];
    float m = 0.f, cnt = 0.f;
    #pragma unroll
    for (int s = 0; s < 4; ++s) {
        m = beta * m + hh;
        if (m > t) { cnt += 1.f; m -= t; }
    }
    if (CL) {
        int b = idx / (36 * HW);
        int rem = idx % HW;
        int y = rem / W, x = rem % W;
        avg[((long)(b * H + y) * W + x) * 40 + co] = __float2bfloat16(cnt * 0.25f);
    } else {
        avg[idx] = __float2bfloat16(cnt * 0.25f);
    }
}

// ===========================================================================
// Weight prepack for MFMA decoder.
// ===========================================================================
__global__ __launch_bounds__(256) void pack_w(
    const float* __restrict__ w, __hip_bfloat16* __restrict__ ap, int total)
{
    int idx = blockIdx.x * 256 + threadIdx.x;
    if (idx >= total) return;
    int m  = idx & 31;
    int h  = (idx >> 5) & 1;
    int s  = (idx >> 6) % 23;
    int cg = idx / (23 * 64);
    int o  = 2 * s + h;
    int co = cg * 32 + m;
    unsigned short v[8];
    #pragma unroll
    for (int j = 0; j < 8; ++j) {
        float x = 0.f;
        if (o < 45) {
            int tap = o / 5, oct = o % 5, ci = oct * 8 + j;
            if (ci < 36) x = w[(long)co * 324 + ci * 9 + tap];
        }
        __hip_bfloat16 hv = __float2bfloat16(x);
        v[j] = *(unsigned short*)&hv;
    }
    *(int4v*)(ap + (long)idx * 8) = *(int4v*)v;
}

// ===========================================================================
// MFMA decoder: conv3x3(36->Cout) + BN + SiLU.
// ===========================================================================
template<int COG>
__global__ __launch_bounds__(256) void dec_mfma(
    const __hip_bfloat16* __restrict__ avg_cl,
    const __hip_bfloat16* __restrict__ apack,
    const float* __restrict__ bn_s, const float* __restrict__ bn_b,
    float* __restrict__ out, int Cout, int H, int W, int tiles_x)
{
    __shared__ __hip_bfloat16 tile[12960];

    const int tid    = threadIdx.x;
    const int b      = blockIdx.y;
    const int cgbase = blockIdx.z * COG;
    const int tx0 = (blockIdx.x % tiles_x) * 16;
    const int ty0 = (blockIdx.x / tiles_x) * 16;

    {
        const __hip_bfloat16* ab = avg_cl + (long)b * H * W * 40;
        for (int i = tid; i < 1620; i += 256) {
            int row = i / 90, u = i - row * 90;
            int px = u / 5, un = u - px * 5;
            int gy = ty0 + row - 1, gx = tx0 + px - 1;
            int4v v = {0, 0, 0, 0};
            if (gy >= 0 && gy < H && gx >= 0 && gx < W)
                v = *(const int4v*)(ab + ((long)gy * W + gx) * 40 + un * 8);
            *(int4v*)(tile + (row * 18 + px) * 40 + un * 8) = v;
        }
    }
    __syncthreads();

    const int lane = tid & 63;
    const int wv   = tid >> 6;
    const int h    = lane >> 5;
    const int n    = lane & 31;
    const int lx   = n & 15;
    const int ly0  = wv * 4 + (n >> 4);

    const char* tb  = (const char*)tile;
    const int   bb0 = ((ly0 + 1) * 18 + (lx + 1)) * 80;
    const int   bb1 = bb0 + 2 * 18 * 80;

    const char* ap = (const char*)apack + (long)cgbase * 23552 + h * 512 + n * 16;

    f32x16 acc[COG][2];
    #pragma unroll
    for (int cg = 0; cg < COG; ++cg)
        #pragma unroll
        for (int pf = 0; pf < 2; ++pf)
            #pragma unroll
            for (int k = 0; k < 16; ++k) acc[cg][pf][k] = 0.f;

    #pragma unroll
    for (int s = 0; s < 23; ++s) {
        int o0 = 2 * s;     if (o0 > 44) o0 = 44;
        int o1 = 2 * s + 1; if (o1 > 44) o1 = 44;
        const int C0 = ((o0 / 5) / 3 - 1) * 1440 + ((o0 / 5) % 3 - 1) * 80 + (o0 % 5) * 16;
        const int C1 = ((o1 / 5) / 3 - 1) * 1440 + ((o1 / 5) % 3 - 1) * 80 + (o1 % 5) * 16;
        const int offc = h ? C1 : C0;
        short8v bf0 = *(const short8v*)(tb + (bb0 + offc));
        short8v bf1 = *(const short8v*)(tb + (bb1 + offc));
        #pragma unroll
        for (int cg = 0; cg < COG; ++cg) {
            short8v af = *(const short8v*)(ap + cg * 23552 + s * 1024);
            acc[cg][0] = __builtin_amdgcn_mfma_f32_32x32x16_bf16(af, bf0, acc[cg][0], 0, 0, 0);
            acc[cg][1] = __builtin_amdgcn_mfma_f32_32x32x16_bf16(af, bf1, acc[cg][1], 0, 0, 0);
        }
    }

    #pragma unroll
    for (int cg = 0; cg < COG; ++cg) {
        #pragma unroll
        for (int r = 0; r < 16; ++r) {
            const int co = ((cgbase + cg) << 5) + (r & 3) + ((r >> 2) << 3) + (h << 2);
            const float sc = bn_s[co], bc = bn_b[co];
            #pragma unroll
            for (int pf = 0; pf < 2; ++pf) {
                const int ly = ly0 + pf * 2;
                const int gy = ty0 + ly, gx = tx0 + lx;
                float v = acc[cg][pf][r] * sc + bc;
                v = v / (1.f + __expf(-v));
                if (gy < H && gx < W)
                    out[(((long)b * Cout + co) * H + gy) * W + gx] = v;
            }
        }
    }
}

// ===========================================================================
// Fallback decoder (VALU, NCHW avg).
// ===========================================================================
template<int COCHUNK, int TDIM>
__global__ __launch_bounds__(TDIM* TDIM) void dec_tiled(
    const __hip_bfloat16* __restrict__ avg,
    const float* __restrict__ w,
    const float* __restrict__ bn_s, const float* __restrict__ bn_b,
    float* __restrict__ out,
    int Cout, int H, int W, int tiles_x)
{
    const int CIN = 36;
    const int TPB = TDIM * TDIM;
    const int HALOD = TDIM + 2;
    __shared__ float fs[CIN][HALOD][HALOD];

    const int tile = blockIdx.x;
    const int b    = blockIdx.y;
    const int co0  = blockIdx.z * COCHUNK;
    const int tx0  = (tile % tiles_x) * TDIM;
    const int ty0  = (tile / tiles_x) * TDIM;

    const int tx = threadIdx.x % TDIM;
    const int ty = threadIdx.x / TDIM;
    const int ox = tx0 + tx, oy = ty0 + ty;

    const __hip_bfloat16* ab = avg + (long)b * CIN * H * W;

    for (int i = threadIdx.x; i < CIN * HALOD * HALOD; i += TPB) {
        int ci = i / (HALOD * HALOD);
        int r  = i % (HALOD * HALOD);
        int hy = r / HALOD, hx = r % HALOD;
        int gy = ty0 + hy - 1, gx = tx0 + hx - 1;
        float v = 0.f;
        if (gy >= 0 && gy < H && gx >= 0 && gx < W)
            v = __bfloat162float(ab[((long)ci * H + gy) * W + gx]);
        fs[ci][hy][hx] = v;
    }
    __syncthreads();

    float acc[COCHUNK];
    #pragma unroll
    for (int j = 0; j < COCHUNK; ++j) acc[j] = 0.f;

    for (int ci = 0; ci < CIN; ++ci) {
        float f0 = fs[ci][ty    ][tx], f1 = fs[ci][ty    ][tx+1], f2 = fs[ci][ty    ][tx+2];
        float f3 = fs[ci][ty + 1][tx], f4 = fs[ci][ty + 1][tx+1], f5 = fs[ci][ty + 1][tx+2];
        float f6 = fs[ci][ty + 2][tx], f7 = fs[ci][ty + 2][tx+1], f8 = fs[ci][ty + 2][tx+2];
        #pragma unroll
        for (int j = 0; j < COCHUNK; ++j) {
            const float* ww = w + ((long)(co0 + j) * CIN + ci) * 9;
            acc[j] += f0 * ww[0] + f1 * ww[1] + f2 * ww[2]
                    + f3 * ww[3] + f4 * ww[4] + f5 * ww[5]
                    + f6 * ww[6] + f7 * ww[7] + f8 * ww[8];
        }
    }

    if (ox < W && oy < H) {
        #pragma unroll
        for (int j = 0; j < COCHUNK; ++j) {
            int co = co0 + j;
            float v = acc[j] * bn_s[co] + bn_b[co];
            out[(((long)b * Cout + co) * H + oy) * W + ox] = v / (1.f + expf(-v));
        }
    }
}

// ===========================================================================
extern "C" void kernel_launch(void* const* d_in, const int* in_sizes, int n_in,
                              void* d_out, int out_size, void* d_ws, size_t ws_size,
                              hipStream_t stream)
{
    const int B = 16;
    const int C[3] = {64, 128, 256};
    const int S[3] = {160, 80, 40};

    float* out = (float*)d_out;
    long out_off[3]; long off = 0;
    for (int l = 0; l < 3; ++l) { out_off[l] = off; off += (long)B * C[l] * S[l] * S[l]; }

    // ---- workspace layout (bytes) ----
    const long avgcl_bytes[3] = {32768000L, 8192000L, 2048000L};
    long avgcl_off[3]; long boff = 0;
    for (int l = 0; l < 3; ++l) { avgcl_off[l] = boff; boff += avgcl_bytes[l]; }
    const long avgcl_total = boff;
    const long ap_bytes[3] = {47104L, 94208L, 188416L};
    long ap_off[3];
    for (int l = 0; l < 3; ++l) { ap_off[l] = boff; boff += ap_bytes[l]; }
    const long we_bytes[3] = {73728L, 147456L, 294912L};
    long wehi_off[3], welo_off[3];
    for (int l = 0; l < 3; ++l) { wehi_off[l] = boff; boff += we_bytes[l];
                                  welo_off[l] = boff; boff += we_bytes[l]; }
    const long part5_off = boff;
    const long part5_bytes = 4L * B * 36 * 1600 * 4;
    boff += part5_bytes;
    const size_t need_full = (size_t)boff;
    const size_t need_min  = (size_t)part5_off;
    const long fhl_bytes[3] = {104857600L, 52428800L, 26214400L};
    long fhl_off[3];
    for (int l = 0; l < 2; ++l) { fhl_off[l] = boff; boff += fhl_bytes[l]; }
    const size_t need_cl = (size_t)boff;
    fhl_off[2] = boff; boff += fhl_bytes[2];
    const size_t need_cl5 = (size_t)boff;

    char* wsb = (char*)d_ws;

    if (ws_size >= need_min) {
        const bool split5  = ws_size >= need_full;
        const bool use_cl  = ws_size >= need_cl;
        const bool use_cl5 = ws_size >= need_cl5;
        hipMemsetAsync(wsb, 0, avgcl_total, stream);

        for (int l = 0; l < 3; ++l) {
            const float* dec_w = (const float*)d_in[9 * l + 6];
            int total = (C[l] / 32) * 23 * 2 * 32;
            pack_w<<<(total + 255) / 256, 256, 0, stream>>>(
                dec_w, (__hip_bfloat16*)(wsb + ap_off[l]), total);
        }
        {
            const float* enc_w3 = (const float*)d_in[1];
            int total = 2 * (64 / 16) * 9 * 2 * 32;
            pack_we<64><<<(total + 255) / 256, 256, 0, stream>>>(
                enc_w3, (__hip_bfloat16*)(wsb + wehi_off[0]),
                (__hip_bfloat16*)(wsb + welo_off[0]), total);
        }
        {
            const float* enc_w4 = (const float*)d_in[10];
            int total = 2 * (128 / 16) * 9 * 2 * 32;
            pack_we<128><<<(total + 255) / 256, 256, 0, stream>>>(
                enc_w4, (__hip_bfloat16*)(wsb + wehi_off[1]),
                (__hip_bfloat16*)(wsb + welo_off[1]), total);
        }
        if (use_cl5) {
            const float* enc_w5 = (const float*)d_in[19];
            int total = 2 * (256 / 16) * 9 * 2 * 32;
            pack_we<256><<<(total + 255) / 256, 256, 0, stream>>>(
                enc_w5, (__hip_bfloat16*)(wsb + wehi_off[2]),
                (__hip_bfloat16*)(wsb + welo_off[2]), total);
        }
        if (use_cl) {
            {
                int HW = 160 * 160, npx = B * HW;
                feat_hl<64, 64><<<(npx + 63) / 64, 256, 0, stream>>>(
                    (const float*)d_in[0], (__hip_bfloat16*)(wsb + fhl_off[0]), HW, npx);
            }
            {
                int HW = 80 * 80, npx = B * HW;
                feat_hl<128, 64><<<(npx + 63) / 64, 256, 0, stream>>>(
                    (const float*)d_in[9], (__hip_bfloat16*)(wsb + fhl_off[1]), HW, npx);
            }
        }
        if (use_cl5) {
            int HW = 40 * 40, npx = B * HW;
            feat_hl<256, 32><<<(npx + 31) / 32, 256, 0, stream>>>(
                (const float*)d_in[18], (__hip_bfloat16*)(wsb + fhl_off[2]), HW, npx);
        }

        for (int l = 0; l < 3; ++l) {
            const int base = 9 * l;
            const float* feat     = (const float*)d_in[base + 0];
            const float* enc_w    = (const float*)d_in[base + 1];
            const float* enc_bn_s = (const float*)d_in[base + 2];
            const float* enc_bn_b = (const float*)d_in[base + 3];
            const float* enc_thr  = (const float*)d_in[base + 4];
            const float* enc_beta = (const float*)d_in[base + 5];
            const float* dec_bn_s = (const float*)d_in[base + 7];
            const float* dec_bn_b = (const float*)d_in[base + 8];

            const int Hs = S[l], Wsz = S[l];
            __hip_bfloat16* avg_cl = (__hip_bfloat16*)(wsb + avgcl_off[l]);
            const __hip_bfloat16* ap = (const __hip_bfloat16*)(wsb + ap_off[l]);
            float* r = out + out_off[l];

            if (l == 0) {
                dim3 eg(100, B);
                if (use_cl)
                    enc_mfma_cl<64><<<eg, 256, 0, stream>>>(
                        (const __hip_bfloat16*)(wsb + fhl_off[0]),
                        (const __hip_bfloat16*)(wsb + wehi_off[0]),
                        (const __hip_bfloat16*)(wsb + welo_off[0]),
                        enc_bn_s, enc_bn_b, enc_thr, enc_beta, avg_cl, Hs, Wsz, 10);
                else
                    enc_tiled<64, 64, 16, 12, 16, false, true><<<dim3(100, B, 3), 256, 0, stream>>>(
                        feat, enc_w, enc_bn_s, enc_bn_b, enc_thr, enc_beta, avg_cl, nullptr, Hs, Wsz, 10);
                dim3 dg(100, B, 1);
                dec_mfma<2><<<dg, 256, 0, stream>>>(avg_cl, ap, dec_bn_s, dec_bn_b, r, 64, Hs, Wsz, 10);
            } else if (l == 1) {
                dim3 eg(25, B);
                if (use_cl)
                    enc_mfma_cl<128><<<eg, 256, 0, stream>>>(
                        (const __hip_bfloat16*)(wsb + fhl_off[1]),
                        (const __hip_bfloat16*)(wsb + wehi_off[1]),
                        (const __hip_bfloat16*)(wsb + welo_off[1]),
                        enc_bn_s, enc_bn_b, enc_thr, enc_beta, avg_cl, Hs, Wsz, 5);
                else
                    enc_tiled<128, 128, 16, 12, 16, false, true><<<dim3(25, B, 3), 256, 0, stream>>>(
                        feat, enc_w, enc_bn_s, enc_bn_b, enc_thr, enc_beta, avg_cl, nullptr, Hs, Wsz, 5);
                dim3 dg(25, B, 2);
                dec_mfma<2><<<dg, 256, 0, stream>>>(avg_cl, ap, dec_bn_s, dec_bn_b, r, 128, Hs, Wsz, 5);
            } else {
                if (use_cl5) {
                    float* partial5 = (float*)(wsb + part5_off);
                    dim3 eg(9, B, 4);
                    enc_mfma_p<256, 64><<<eg, 256, 0, stream>>>(
                        (const __hip_bfloat16*)(wsb + fhl_off[2]),
                        (const __hip_bfloat16*)(wsb + wehi_off[2]),
                        (const __hip_bfloat16*)(wsb + welo_off[2]),
                        partial5, Hs, Wsz, 3);
                    int total = B * 36 * Hs * Wsz;
                    combine_lif<4, true><<<(total + 255) / 256, 256, 0, stream>>>(
                        partial5, enc_bn_s, enc_bn_b, enc_thr, enc_beta, avg_cl, Hs, Wsz, total);
                } else if (split5) {
                    float* partial5 = (float*)(wsb + part5_off);
                    dim3 eg(25, B, 12);
                    enc_tiled<256, 64, 16, 12, 8, true, true><<<eg, 64, 0, stream>>>(
                        feat, enc_w, enc_bn_s, enc_bn_b, enc_thr, enc_beta, nullptr, partial5, Hs, Wsz, 5);
                    int total = B * 36 * Hs * Wsz;
                    combine_lif<4, true><<<(total + 255) / 256, 256, 0, stream>>>(
                        partial5, enc_bn_s, enc_bn_b, enc_thr, enc_beta, avg_cl, Hs, Wsz, total);
                } else {
                    dim3 eg(25, B, 3);
                    enc_tiled<256, 256, 16, 12, 8, false, true><<<eg, 64, 0, stream>>>(
                        feat, enc_w, enc_bn_s, enc_bn_b, enc_thr, enc_beta, avg_cl, nullptr, Hs, Wsz, 5);
                }
                dim3 dg(9, B, 4);
                dec_mfma<2><<<dg, 256, 0, stream>>>(avg_cl, ap, dec_bn_s, dec_bn_b, r, 256, Hs, Wsz, 3);
            }
        }
    } else {
        // ================= FALLBACK (NCHW, VALU decoder) =================
        __hip_bfloat16* ws = (__hip_bfloat16*)d_ws;
        long avg_off2[3]; long eoff = 0;
        for (int l = 0; l < 3; ++l) { avg_off2[l] = eoff; eoff += (long)B * 36 * S[l] * S[l]; }
        float* partial5 = (float*)(ws + ((eoff + 7) & ~7L));
        const long part5f = 4L * B * 36 * 40 * 40;
        const size_t old_need = (size_t)((eoff + 7) & ~7L) * 2 + part5f * 4;
        const bool split5 = ws_size >= old_need;

        for (int l = 0; l < 3; ++l) {
            const int base = 9 * l;
            const float* feat     = (const float*)d_in[base + 0];
            const float* enc_w    = (const float*)d_in[base + 1];
            const float* enc_bn_s = (const float*)d_in[base + 2];
            const float* enc_bn_b = (const float*)d_in[base + 3];
            const float* enc_thr  = (const float*)d_in[base + 4];
            const float* enc_beta = (const float*)d_in[base + 5];
            const float* dec_w    = (const float*)d_in[base + 6];
            const float* dec_bn_s = (const float*)d_in[base + 7];
            const float* dec_bn_b = (const float*)d_in[base + 8];

            const int Hs = S[l], Wsz = S[l], Cl = C[l];
            __hip_bfloat16* avg = ws + avg_off2[l];
            float* r = out + out_off[l];

            if (l == 0) {
                dim3 eg(100, B, 3);
                enc_tiled<64, 64, 16, 12, 16, false, false><<<eg, 256, 0, stream>>>(
                    feat, enc_w, enc_bn_s, enc_bn_b, enc_thr, enc_beta, avg, nullptr, Hs, Wsz, 10);
                dim3 dg(100, B, 2);
                dec_tiled<32, 16><<<dg, 256, 0, stream>>>(avg, dec_w, dec_bn_s, dec_bn_b, r, Cl, Hs, Wsz, 10);
            } else if (l == 1) {
                dim3 eg(25, B, 3);
                enc_tiled<128, 128, 16, 12, 16, false, false><<<eg, 256, 0, stream>>>(
                    feat, enc_w, enc_bn_s, enc_bn_b, enc_thr, enc_beta, avg, nullptr, Hs, Wsz, 5);
                dim3 dg(25, B, 4);
                dec_tiled<32, 16><<<dg, 256, 0, stream>>>(avg, dec_w, dec_bn_s, dec_bn_b, r, Cl, Hs, Wsz, 5);
            } else {
                if (split5) {
                    dim3 eg(25, B, 12);
                    enc_tiled<256, 64, 16, 12, 8, true, false><<<eg, 64, 0, stream>>>(
                        feat, enc_w, enc_bn_s, enc_bn_b, enc_thr, enc_beta, nullptr, partial5, Hs, Wsz, 5);
                    int total = B * 36 * Hs * Wsz;
                    combine_lif<4, false><<<(total + 255) / 256, 256, 0, stream>>>(
                        partial5, enc_bn_s, enc_bn_b, enc_thr, enc_beta, avg, Hs, Wsz, total);
                } else {
                    dim3 eg(25, B, 3);
                    enc_tiled<256, 256, 16, 12, 8, false, false><<<eg, 64, 0, stream>>>(
                        feat, enc_w, enc_bn_s, enc_bn_b, enc_thr, enc_beta, avg, nullptr, Hs, Wsz, 5);
                }
                dim3 dg(25, B, 16);
                dec_tiled<16, 8><<<dg, 64, 0, stream>>>(avg, dec_w, dec_bn_s, dec_bn_b, r, Cl, Hs, Wsz, 5);
            }
        }
    }
}